// Round 1
// baseline (7549.619 us; speedup 1.0000x reference)
//
#include <hip/hip_runtime.h>
#include <math.h>

// Problem constants
// B=8, S=1024, D=768, H=12, DH=64, L=3, I=3072, W1S=128, nc=8, MLP=512, NCLS=3

__device__ __forceinline__ float gelu_exact(float x) {
    return 0.5f * x * (1.f + erff(x * 0.70710678118654752440f));
}

// ---------------------------------------------------------------------------
// Embed: gather patchified row (192), GEMM 192x768, +pos+tok, LayerNorm.
// grid = 8192 blocks (one per token), 256 threads.
// ---------------------------------------------------------------------------
__global__ __launch_bounds__(256) void embed_kernel(
    const float* __restrict__ x, const float* __restrict__ proj_w,
    const float* __restrict__ proj_b, const float* __restrict__ pos_emb,
    const float* __restrict__ tok_emb, const float* __restrict__ ln_s,
    const float* __restrict__ ln_b, float* __restrict__ h)
{
    int tok = blockIdx.x;           // 0..8191
    int b = tok >> 10;
    int s = tok & 1023;
    int tci = s >> 6, sci = (s >> 3) & 7, scj = s & 7;
    __shared__ float xrow[192];
    __shared__ float red[8];
    int tid = threadIdx.x;
    if (tid < 192) {
        int ch  = tid % 3;
        int crc = tid / 3;
        int cr1 = crc >> 4, cr2 = (crc >> 2) & 3, cr3 = crc & 3;
        xrow[tid] = x[(((b * 3 + ch) * 64) + cr1 * 16 + tci) * 1024 +
                      (cr2 * 8 + sci) * 32 + cr3 * 8 + scj];
    }
    __syncthreads();
    int d0 = tid, d1 = tid + 256, d2 = tid + 512;
    float a0 = proj_b[d0] + pos_emb[s * 768 + d0] + tok_emb[d0];
    float a1 = proj_b[d1] + pos_emb[s * 768 + d1] + tok_emb[d1];
    float a2 = proj_b[d2] + pos_emb[s * 768 + d2] + tok_emb[d2];
    for (int k = 0; k < 192; k++) {
        float xk = xrow[k];
        const float* wrow = &proj_w[k * 768];
        a0 += xk * wrow[d0];
        a1 += xk * wrow[d1];
        a2 += xk * wrow[d2];
    }
    float sum = a0 + a1 + a2;
    float sumsq = a0 * a0 + a1 * a1 + a2 * a2;
    #pragma unroll
    for (int off = 32; off; off >>= 1) {
        sum   += __shfl_down(sum, off, 64);
        sumsq += __shfl_down(sumsq, off, 64);
    }
    if ((tid & 63) == 0) { red[tid >> 6] = sum; red[4 + (tid >> 6)] = sumsq; }
    __syncthreads();
    sum   = red[0] + red[1] + red[2] + red[3];
    sumsq = red[4] + red[5] + red[6] + red[7];
    float mean = sum * (1.f / 768.f);
    float var  = sumsq * (1.f / 768.f) - mean * mean;
    float rs   = rsqrtf(var + 1e-12f);
    float* hrow = &h[(long)tok * 768];
    hrow[d0] = (a0 - mean) * rs * ln_s[d0] + ln_b[d0];
    hrow[d1] = (a1 - mean) * rs * ln_s[d1] + ln_b[d1];
    hrow[d2] = (a2 - mean) * rs * ln_s[d2] + ln_b[d2];
}

// ---------------------------------------------------------------------------
// Generic fp32 GEMM: C[M,N] = A[M,K] @ W[K,N] + bias, optional exact-GELU.
// 64x64 tile, 256 threads, 4x4 microtile, K-tile 16.
// Requires M%64==0, N%64==0, K%16==0 (all shapes here satisfy this).
// ---------------------------------------------------------------------------
__global__ __launch_bounds__(256) void gemm_kernel(
    const float* __restrict__ A, const float* __restrict__ Wm,
    const float* __restrict__ bias, float* __restrict__ C,
    int M, int N, int K, int act)
{
    __shared__ float As[16][64];
    __shared__ float Bs[16][64];
    int tid = threadIdx.x;
    int tx = tid & 15, ty = tid >> 4;
    int bx = blockIdx.x, by = blockIdx.y;
    int col0 = bx * 64 + tx * 4;
    int row0 = by * 64 + ty * 4;
    float acc[4][4] = {};
    int la_row = tid >> 2;            // 0..63
    int la_k   = (tid & 3) * 4;       // 0,4,8,12
    int lb_k   = tid >> 4;            // 0..15
    int lb_n   = (tid & 15) * 4;      // 0..60

    for (int kt = 0; kt < K; kt += 16) {
        float4 av = *(const float4*)&A[(long)(by * 64 + la_row) * K + kt + la_k];
        float4 bv = *(const float4*)&Wm[(long)(kt + lb_k) * N + bx * 64 + lb_n];
        As[la_k + 0][la_row] = av.x;
        As[la_k + 1][la_row] = av.y;
        As[la_k + 2][la_row] = av.z;
        As[la_k + 3][la_row] = av.w;
        *(float4*)&Bs[lb_k][lb_n] = bv;
        __syncthreads();
        #pragma unroll
        for (int kk = 0; kk < 16; kk++) {
            float4 a = *(const float4*)&As[kk][ty * 4];
            float4 b = *(const float4*)&Bs[kk][tx * 4];
            acc[0][0] += a.x * b.x; acc[0][1] += a.x * b.y; acc[0][2] += a.x * b.z; acc[0][3] += a.x * b.w;
            acc[1][0] += a.y * b.x; acc[1][1] += a.y * b.y; acc[1][2] += a.y * b.z; acc[1][3] += a.y * b.w;
            acc[2][0] += a.z * b.x; acc[2][1] += a.z * b.y; acc[2][2] += a.z * b.z; acc[2][3] += a.z * b.w;
            acc[3][0] += a.w * b.x; acc[3][1] += a.w * b.y; acc[3][2] += a.w * b.z; acc[3][3] += a.w * b.w;
        }
        __syncthreads();
    }
    float4 bb = *(const float4*)&bias[col0];
    #pragma unroll
    for (int i = 0; i < 4; i++) {
        float4 o;
        o.x = acc[i][0] + bb.x;
        o.y = acc[i][1] + bb.y;
        o.z = acc[i][2] + bb.z;
        o.w = acc[i][3] + bb.w;
        if (act == 1) {
            o.x = gelu_exact(o.x); o.y = gelu_exact(o.y);
            o.z = gelu_exact(o.z); o.w = gelu_exact(o.w);
        }
        *(float4*)&C[(long)(row0 + i) * N + col0] = o;
    }
}

// ---------------------------------------------------------------------------
// Band attention, flash-style. grid = B*H*nc = 768 blocks, 128 threads
// (one thread per query row). K/V tiled 64 keys at a time through LDS.
// Q/K/V layout: [token(8192)][d(768)] with d = head*64 + dh.
// ---------------------------------------------------------------------------
__global__ __launch_bounds__(128) void attn_kernel(
    const float* __restrict__ Qb, const float* __restrict__ Kb,
    const float* __restrict__ Vb, float* __restrict__ Ob)
{
    int blk = blockIdx.x;
    int ci = blk & 7;
    int hh = (blk >> 3) % 12;
    int b  = blk / 96;
    int r  = threadIdx.x;            // query row within chunk, 0..127
    int qpos = ci * 128 + r;

    const float* qptr = &Qb[((long)(b * 1024 + qpos)) * 768 + hh * 64];
    float4 q[16];
    #pragma unroll
    for (int i = 0; i < 16; i++) q[i] = *(const float4*)&qptr[i * 4];
    float4 acc[16] = {};
    float m = -1e30f, l = 0.f;

    __shared__ float Ks[64][64];
    __shared__ float Vs[64][64];

    for (int t = 0; t < 6; t++) {
        int j0 = t * 64;
        __syncthreads();
        // stage 64 keys x 64 dims of K and V (zeros outside sequence)
        for (int e = threadIdx.x; e < 64 * 16; e += 128) {
            int jj = e >> 4;
            int dd = (e & 15) * 4;
            int kpos = ci * 128 + j0 + jj - 128;
            float4 kv = make_float4(0.f, 0.f, 0.f, 0.f);
            float4 vv = make_float4(0.f, 0.f, 0.f, 0.f);
            if (kpos >= 0 && kpos < 1024) {
                long base = ((long)(b * 1024 + kpos)) * 768 + hh * 64 + dd;
                kv = *(const float4*)&Kb[base];
                vv = *(const float4*)&Vb[base];
            }
            *(float4*)&Ks[jj][dd] = kv;
            *(float4*)&Vs[jj][dd] = vv;
        }
        __syncthreads();

        float sc[64];
        float tmax = -1e30f;
        #pragma unroll
        for (int jj = 0; jj < 64; jj++) {
            int j = j0 + jj;
            int kpos = ci * 128 + j - 128;
            bool valid = (j >= r) && (j <= r + 256) && (kpos >= 0) && (kpos < 1024);
            float dot = 0.f;
            #pragma unroll
            for (int i2 = 0; i2 < 16; i2++) {
                float4 kv4 = *(const float4*)&Ks[jj][i2 * 4];
                dot += q[i2].x * kv4.x + q[i2].y * kv4.y +
                       q[i2].z * kv4.z + q[i2].w * kv4.w;
            }
            sc[jj] = valid ? dot * 0.125f : -1e30f;
            tmax = fmaxf(tmax, sc[jj]);
        }
        if (tmax > -1e29f) {           // at least one valid key in this tile
            float mnew  = fmaxf(m, tmax);
            float alpha = expf(m - mnew);   // m==-1e30 -> 0
            l *= alpha;
            #pragma unroll
            for (int i2 = 0; i2 < 16; i2++) {
                acc[i2].x *= alpha; acc[i2].y *= alpha;
                acc[i2].z *= alpha; acc[i2].w *= alpha;
            }
            #pragma unroll
            for (int jj = 0; jj < 64; jj++) {
                float p = expf(sc[jj] - mnew);  // invalid: exp(-huge)=0
                l += p;
                #pragma unroll
                for (int i2 = 0; i2 < 16; i2++) {
                    float4 vv = *(const float4*)&Vs[jj][i2 * 4];
                    acc[i2].x += p * vv.x; acc[i2].y += p * vv.y;
                    acc[i2].z += p * vv.z; acc[i2].w += p * vv.w;
                }
            }
            m = mnew;
        }
    }
    float rl = 1.f / l;
    float* optr = &Ob[((long)(b * 1024 + qpos)) * 768 + hh * 64];
    #pragma unroll
    for (int i2 = 0; i2 < 16; i2++) {
        float4 o;
        o.x = acc[i2].x * rl; o.y = acc[i2].y * rl;
        o.z = acc[i2].z * rl; o.w = acc[i2].w * rl;
        *(float4*)&optr[i2 * 4] = o;
    }
}

// ---------------------------------------------------------------------------
// h = LayerNorm(h + t) in place. grid = 8192, 256 threads.
// ---------------------------------------------------------------------------
__global__ __launch_bounds__(256) void add_ln_kernel(
    float* __restrict__ h, const float* __restrict__ t,
    const float* __restrict__ ln_s, const float* __restrict__ ln_b)
{
    int tok = blockIdx.x;
    int tid = threadIdx.x;
    __shared__ float red[8];
    float* hrow = &h[(long)tok * 768];
    const float* trow = &t[(long)tok * 768];
    int d0 = tid, d1 = tid + 256, d2 = tid + 512;
    float a0 = hrow[d0] + trow[d0];
    float a1 = hrow[d1] + trow[d1];
    float a2 = hrow[d2] + trow[d2];
    float sum = a0 + a1 + a2;
    float sumsq = a0 * a0 + a1 * a1 + a2 * a2;
    #pragma unroll
    for (int off = 32; off; off >>= 1) {
        sum   += __shfl_down(sum, off, 64);
        sumsq += __shfl_down(sumsq, off, 64);
    }
    if ((tid & 63) == 0) { red[tid >> 6] = sum; red[4 + (tid >> 6)] = sumsq; }
    __syncthreads();
    sum   = red[0] + red[1] + red[2] + red[3];
    sumsq = red[4] + red[5] + red[6] + red[7];
    float mean = sum * (1.f / 768.f);
    float var  = sumsq * (1.f / 768.f) - mean * mean;
    float rs   = rsqrtf(var + 1e-12f);
    hrow[d0] = (a0 - mean) * rs * ln_s[d0] + ln_b[d0];
    hrow[d1] = (a1 - mean) * rs * ln_s[d1] + ln_b[d1];
    hrow[d2] = (a2 - mean) * rs * ln_s[d2] + ln_b[d2];
}

// ---------------------------------------------------------------------------
// Head: pooled = tanh(h[:,0] @ pool_w + pool_b); LN; gelu(@w1+b1); @w2+b2.
// grid = 8 blocks (one per batch), 256 threads.
// ---------------------------------------------------------------------------
__global__ __launch_bounds__(256) void head_kernel(
    const float* __restrict__ h, const float* __restrict__ pool_w,
    const float* __restrict__ pool_b, const float* __restrict__ hln_s,
    const float* __restrict__ hln_b, const float* __restrict__ w1,
    const float* __restrict__ b1, const float* __restrict__ w2,
    const float* __restrict__ b2, float* __restrict__ out)
{
    int b = blockIdx.x;
    int tid = threadIdx.x;
    __shared__ float row[768];
    __shared__ float z[768];
    __shared__ float z1[512];
    __shared__ float red[8];
    #pragma unroll
    for (int j = 0; j < 3; j++)
        row[tid + j * 256] = h[((long)b * 1024) * 768 + tid + j * 256];
    __syncthreads();
    float pv[3];
    float sum = 0.f, sumsq = 0.f;
    #pragma unroll
    for (int j = 0; j < 3; j++) {
        int d = tid + j * 256;
        float acc = pool_b[d];
        for (int k = 0; k < 768; k++) acc += row[k] * pool_w[k * 768 + d];
        acc = tanhf(acc);
        pv[j] = acc;
        sum += acc; sumsq += acc * acc;
    }
    #pragma unroll
    for (int off = 32; off; off >>= 1) {
        sum   += __shfl_down(sum, off, 64);
        sumsq += __shfl_down(sumsq, off, 64);
    }
    if ((tid & 63) == 0) { red[tid >> 6] = sum; red[4 + (tid >> 6)] = sumsq; }
    __syncthreads();
    sum   = red[0] + red[1] + red[2] + red[3];
    sumsq = red[4] + red[5] + red[6] + red[7];
    float mean = sum * (1.f / 768.f);
    float var  = sumsq * (1.f / 768.f) - mean * mean;
    float rs   = rsqrtf(var + 1e-12f);
    #pragma unroll
    for (int j = 0; j < 3; j++) {
        int d = tid + j * 256;
        z[d] = (pv[j] - mean) * rs * hln_s[d] + hln_b[d];
    }
    __syncthreads();
    #pragma unroll
    for (int j = 0; j < 2; j++) {
        int d = tid + j * 256;   // 0..511
        float acc = b1[d];
        for (int k = 0; k < 768; k++) acc += z[k] * w1[k * 512 + d];
        z1[d] = gelu_exact(acc);
    }
    __syncthreads();
    if (tid < 3) {
        float acc = b2[tid];
        for (int k = 0; k < 512; k++) acc += z1[k] * w2[k * 3 + tid];
        out[b * 3 + tid] = acc;
    }
}

// ---------------------------------------------------------------------------
extern "C" void kernel_launch(void* const* d_in, const int* in_sizes, int n_in,
                              void* d_out, int out_size, void* d_ws, size_t ws_size,
                              hipStream_t stream) {
    const float* x       = (const float*)d_in[0];
    // d_in[1] = position_ids (unused by reference forward)
    const float* proj_w  = (const float*)d_in[2];
    const float* proj_b  = (const float*)d_in[3];
    const float* pos_emb = (const float*)d_in[4];
    const float* tok_emb = (const float*)d_in[5];
    const float* eln_s   = (const float*)d_in[6];
    const float* eln_b   = (const float*)d_in[7];
    const float* wq      = (const float*)d_in[8];
    const float* bq      = (const float*)d_in[9];
    const float* wk      = (const float*)d_in[10];
    const float* bk      = (const float*)d_in[11];
    const float* wv      = (const float*)d_in[12];
    const float* bv      = (const float*)d_in[13];
    const float* wo      = (const float*)d_in[14];
    const float* bo      = (const float*)d_in[15];
    const float* ln1_s   = (const float*)d_in[16];
    const float* ln1_b   = (const float*)d_in[17];
    const float* wi      = (const float*)d_in[18];
    const float* bi      = (const float*)d_in[19];
    const float* wo2     = (const float*)d_in[20];
    const float* bo2     = (const float*)d_in[21];
    const float* ln2_s   = (const float*)d_in[22];
    const float* ln2_b   = (const float*)d_in[23];
    const float* pool_w  = (const float*)d_in[24];
    const float* pool_b  = (const float*)d_in[25];
    const float* hln_s   = (const float*)d_in[26];
    const float* hln_b   = (const float*)d_in[27];
    const float* hw1     = (const float*)d_in[28];
    const float* hb1     = (const float*)d_in[29];
    const float* hw2     = (const float*)d_in[30];
    const float* hb2     = (const float*)d_in[31];

    const long NTOK = 8192;                 // B*S
    const long HSZ  = NTOK * 768;           // 6291456 floats
    float* ws  = (float*)d_ws;
    float* h   = ws;
    float* q   = h + HSZ;
    float* k   = q + HSZ;
    float* v   = k + HSZ;
    float* a   = v + HSZ;
    float* mlp = a + HSZ;                   // NTOK*3072 floats

    embed_kernel<<<8192, 256, 0, stream>>>(x, proj_w, proj_b, pos_emb, tok_emb,
                                           eln_s, eln_b, h);

    dim3 g768(768 / 64, 8192 / 64);         // (12,128)
    dim3 g3072(3072 / 64, 8192 / 64);       // (48,128)
    for (int l = 0; l < 3; l++) {
        const float* wq_l  = wq  + (long)l * 768 * 768;
        const float* wk_l  = wk  + (long)l * 768 * 768;
        const float* wv_l  = wv  + (long)l * 768 * 768;
        const float* wo_l  = wo  + (long)l * 768 * 768;
        const float* wi_l  = wi  + (long)l * 768 * 3072;
        const float* wo2_l = wo2 + (long)l * 3072 * 768;
        const float* bq_l  = bq  + l * 768;
        const float* bk_l  = bk  + l * 768;
        const float* bv_l  = bv  + l * 768;
        const float* bo_l  = bo  + l * 768;
        const float* bi_l  = bi  + l * 3072;
        const float* bo2_l = bo2 + l * 768;

        gemm_kernel<<<g768, 256, 0, stream>>>(h, wq_l, bq_l, q, 8192, 768, 768, 0);
        gemm_kernel<<<g768, 256, 0, stream>>>(h, wk_l, bk_l, k, 8192, 768, 768, 0);
        gemm_kernel<<<g768, 256, 0, stream>>>(h, wv_l, bv_l, v, 8192, 768, 768, 0);
        attn_kernel<<<768, 128, 0, stream>>>(q, k, v, a);
        gemm_kernel<<<g768, 256, 0, stream>>>(a, wo_l, bo_l, q, 8192, 768, 768, 0);
        add_ln_kernel<<<8192, 256, 0, stream>>>(h, q, ln1_s + l * 768, ln1_b + l * 768);
        gemm_kernel<<<g3072, 256, 0, stream>>>(h, wi_l, bi_l, mlp, 8192, 3072, 768, 1);
        gemm_kernel<<<g768, 256, 0, stream>>>(mlp, wo2_l, bo2_l, q, 8192, 768, 3072, 0);
        add_ln_kernel<<<8192, 256, 0, stream>>>(h, q, ln2_s + l * 768, ln2_b + l * 768);
    }

    head_kernel<<<8, 256, 0, stream>>>(h, pool_w, pool_b, hln_s, hln_b,
                                       hw1, hb1, hw2, hb2, (float*)d_out);
}

// Round 2
// 2895.083 us; speedup vs baseline: 2.6077x; 2.6077x over previous
//
#include <hip/hip_runtime.h>
#include <hip/hip_bf16.h>
#include <math.h>

// B=8, S=1024, D=768, H=12, DH=64, L=3, I=3072, W1S=128, nc=8, MLP=512, NCLS=3

typedef __attribute__((ext_vector_type(8))) short short8;   // 8 bf16 (4 VGPRs)
typedef __attribute__((ext_vector_type(4))) float floatx4;  // MFMA C/D

__device__ __forceinline__ float gelu_exact(float x) {
    return 0.5f * x * (1.f + erff(x * 0.70710678118654752440f));
}

#define GLOAD_LDS16(g, l) __builtin_amdgcn_global_load_lds( \
    (const __attribute__((address_space(1))) void*)(g),     \
    (__attribute__((address_space(3))) void*)(l), 16, 0, 0)

// ---------------------------------------------------------------------------
// Weight convert+transpose: W[K,N] fp32 -> Wt[N,K] bf16. blockIdx.z = layer.
// ---------------------------------------------------------------------------
__global__ __launch_bounds__(256) void transpose_bf16(
    const float* __restrict__ W, __hip_bfloat16* __restrict__ Wt,
    int K, int N, long inLS, long outLS)
{
    __shared__ float tile[32][33];
    int l = blockIdx.z;
    const float* Wl = W + (long)l * inLS;
    __hip_bfloat16* Wtl = Wt + (long)l * outLS;
    int lx = threadIdx.x & 31, ly = threadIdx.x >> 5;
    int kb = blockIdx.y * 32, nb = blockIdx.x * 32;
    #pragma unroll
    for (int r = 0; r < 32; r += 8)
        tile[ly + r][lx] = Wl[(long)(kb + ly + r) * N + nb + lx];
    __syncthreads();
    #pragma unroll
    for (int r = 0; r < 32; r += 8)
        Wtl[(long)(nb + ly + r) * K + kb + lx] = __float2bfloat16(tile[lx][ly + r]);
}

__global__ void pack_qkv_bias(const float* __restrict__ bq,
                              const float* __restrict__ bk,
                              const float* __restrict__ bv,
                              float* __restrict__ out)
{
    int l = blockIdx.x, tid = threadIdx.x;   // 768 threads
    out[l * 2304 + tid]        = bq[l * 768 + tid];
    out[l * 2304 + 768 + tid]  = bk[l * 768 + tid];
    out[l * 2304 + 1536 + tid] = bv[l * 768 + tid];
}

// ---------------------------------------------------------------------------
// bf16 MFMA GEMM: C[M,N] = A[M,K](bf16) @ Bt[N,K](bf16)^T + bias.
// 128x128 tile, BK=32, 256 thr = 4 waves, each wave 64x64 via 4x4 of
// mfma_f32_16x16x32_bf16. Staging via global_load_lds width=16 (m97 recipe).
// ACT: 0 = none (fp32 out), 1 = exact gelu (bf16 out).
// Requires M%128==0, N%128==0, K%32==0.
// ---------------------------------------------------------------------------
template<int ACT, typename OT>
__global__ __launch_bounds__(256) void mfma_gemm(
    const __hip_bfloat16* __restrict__ A, const __hip_bfloat16* __restrict__ Bt,
    const float* __restrict__ bias, OT* __restrict__ C, int M, int N, int K)
{
    __shared__ __hip_bfloat16 As[128 * 32];   // row-major [row][k], 8 KB
    __shared__ __hip_bfloat16 Bs[128 * 32];
    int tid  = threadIdx.x;
    int wave = tid >> 6, lane = tid & 63;
    long m0 = (long)blockIdx.y * 128, n0 = (long)blockIdx.x * 128;
    int wr = wave >> 1, wc = wave & 1;        // wave quadrant (64x64)
    floatx4 acc[4][4] = {};

    // staging: slot sigma = wave*128 + t*64 + lane; row = sigma>>2, chunk = sigma&3
    int srow = (wave * 128 + lane) >> 2;      // t=0 row (t=1 adds 16)
    int sch  = lane & 3;
    const __hip_bfloat16* Ag = A  + (m0 + srow) * K + sch * 8;
    const __hip_bfloat16* Bg = Bt + (n0 + srow) * K + sch * 8;
    __hip_bfloat16* AsW = &As[wave * 128 * 8];    // wave-uniform LDS base, t=0
    __hip_bfloat16* BsW = &Bs[wave * 128 * 8];
    int lm = lane & 15, lk8 = (lane >> 4) * 8;

    for (int k0 = 0; k0 < K; k0 += 32) {
        GLOAD_LDS16(Ag + k0,          AsW);
        GLOAD_LDS16(Ag + 16 * K + k0, AsW + 64 * 8);
        GLOAD_LDS16(Bg + k0,          BsW);
        GLOAD_LDS16(Bg + 16 * K + k0, BsW + 64 * 8);
        __syncthreads();
        short8 af[4], bf[4];
        #pragma unroll
        for (int mi = 0; mi < 4; mi++)
            af[mi] = *(const short8*)&As[(wr * 64 + mi * 16 + lm) * 32 + lk8];
        #pragma unroll
        for (int ni = 0; ni < 4; ni++)
            bf[ni] = *(const short8*)&Bs[(wc * 64 + ni * 16 + lm) * 32 + lk8];
        #pragma unroll
        for (int mi = 0; mi < 4; mi++)
            #pragma unroll
            for (int ni = 0; ni < 4; ni++)
                acc[mi][ni] = __builtin_amdgcn_mfma_f32_16x16x32_bf16(
                    af[mi], bf[ni], acc[mi][ni], 0, 0, 0);
        __syncthreads();
    }

    // epilogue: D col = lane&15, row = (lane>>4)*4 + reg (m89/m91-verified)
    int colb = (int)n0 + wc * 64 + lm;
    int rowb = (int)m0 + wr * 64 + (lane >> 4) * 4;
    #pragma unroll
    for (int ni = 0; ni < 4; ni++) {
        int col = colb + ni * 16;
        float bv = bias[col];
        #pragma unroll
        for (int mi = 0; mi < 4; mi++) {
            #pragma unroll
            for (int j = 0; j < 4; j++) {
                float o = acc[mi][ni][j] + bv;
                if (ACT == 1) o = gelu_exact(o);
                long idx = (long)(rowb + mi * 16 + j) * N + col;
                if constexpr (sizeof(OT) == 2) C[idx] = __float2bfloat16(o);
                else                           C[idx] = o;
            }
        }
    }
}

// ---------------------------------------------------------------------------
// Embed: gather patchified row (192), GEMM 192x768, +pos+tok, LayerNorm.
// Writes fp32 h and bf16 mirror. grid = 8192, 256 threads.
// ---------------------------------------------------------------------------
__global__ __launch_bounds__(256) void embed_kernel(
    const float* __restrict__ x, const float* __restrict__ proj_w,
    const float* __restrict__ proj_b, const float* __restrict__ pos_emb,
    const float* __restrict__ tok_emb, const float* __restrict__ ln_s,
    const float* __restrict__ ln_b, float* __restrict__ h,
    __hip_bfloat16* __restrict__ hbf)
{
    int tok = blockIdx.x;
    int b = tok >> 10;
    int s = tok & 1023;
    int tci = s >> 6, sci = (s >> 3) & 7, scj = s & 7;
    __shared__ float xrow[192];
    __shared__ float red[8];
    int tid = threadIdx.x;
    if (tid < 192) {
        int ch  = tid % 3;
        int crc = tid / 3;
        int cr1 = crc >> 4, cr2 = (crc >> 2) & 3, cr3 = crc & 3;
        xrow[tid] = x[(((b * 3 + ch) * 64) + cr1 * 16 + tci) * 1024 +
                      (cr2 * 8 + sci) * 32 + cr3 * 8 + scj];
    }
    __syncthreads();
    int d0 = tid, d1 = tid + 256, d2 = tid + 512;
    float a0 = proj_b[d0] + pos_emb[s * 768 + d0] + tok_emb[d0];
    float a1 = proj_b[d1] + pos_emb[s * 768 + d1] + tok_emb[d1];
    float a2 = proj_b[d2] + pos_emb[s * 768 + d2] + tok_emb[d2];
    for (int k = 0; k < 192; k++) {
        float xk = xrow[k];
        const float* wrow = &proj_w[k * 768];
        a0 += xk * wrow[d0];
        a1 += xk * wrow[d1];
        a2 += xk * wrow[d2];
    }
    float sum = a0 + a1 + a2;
    float sumsq = a0 * a0 + a1 * a1 + a2 * a2;
    #pragma unroll
    for (int off = 32; off; off >>= 1) {
        sum   += __shfl_down(sum, off, 64);
        sumsq += __shfl_down(sumsq, off, 64);
    }
    if ((tid & 63) == 0) { red[tid >> 6] = sum; red[4 + (tid >> 6)] = sumsq; }
    __syncthreads();
    sum   = red[0] + red[1] + red[2] + red[3];
    sumsq = red[4] + red[5] + red[6] + red[7];
    float mean = sum * (1.f / 768.f);
    float var  = sumsq * (1.f / 768.f) - mean * mean;
    float rs   = rsqrtf(var + 1e-12f);
    float* hrow = &h[(long)tok * 768];
    __hip_bfloat16* brow = &hbf[(long)tok * 768];
    float o0 = (a0 - mean) * rs * ln_s[d0] + ln_b[d0];
    float o1 = (a1 - mean) * rs * ln_s[d1] + ln_b[d1];
    float o2 = (a2 - mean) * rs * ln_s[d2] + ln_b[d2];
    hrow[d0] = o0; hrow[d1] = o1; hrow[d2] = o2;
    brow[d0] = __float2bfloat16(o0);
    brow[d1] = __float2bfloat16(o1);
    brow[d2] = __float2bfloat16(o2);
}

// ---------------------------------------------------------------------------
// Band attention, flash-style fp32. Reads packed QKV [8192,2304]
// (q|k|v, each head*64+dh within its 768 slice). Writes bf16 output.
// grid = 768 blocks (b,h,chunk), 128 threads (one per query row).
// ---------------------------------------------------------------------------
__global__ __launch_bounds__(128) void attn_kernel(
    const float* __restrict__ QKV, __hip_bfloat16* __restrict__ Ob)
{
    int blk = blockIdx.x;
    int ci = blk & 7;
    int hh = (blk >> 3) % 12;
    int b  = blk / 96;
    int r  = threadIdx.x;
    int qpos = ci * 128 + r;

    const float* qptr = &QKV[((long)(b * 1024 + qpos)) * 2304 + hh * 64];
    float4 q[16];
    #pragma unroll
    for (int i = 0; i < 16; i++) q[i] = *(const float4*)&qptr[i * 4];
    float4 acc[16] = {};
    float m = -1e30f, l = 0.f;

    __shared__ float Ks[64][64];
    __shared__ float Vs[64][64];

    for (int t = 0; t < 6; t++) {
        int j0 = t * 64;
        __syncthreads();
        for (int e = threadIdx.x; e < 64 * 16; e += 128) {
            int jj = e >> 4;
            int dd = (e & 15) * 4;
            int kpos = ci * 128 + j0 + jj - 128;
            float4 kv = make_float4(0.f, 0.f, 0.f, 0.f);
            float4 vv = make_float4(0.f, 0.f, 0.f, 0.f);
            if (kpos >= 0 && kpos < 1024) {
                long base = ((long)(b * 1024 + kpos)) * 2304 + hh * 64 + dd;
                kv = *(const float4*)&QKV[base + 768];
                vv = *(const float4*)&QKV[base + 1536];
            }
            *(float4*)&Ks[jj][dd] = kv;
            *(float4*)&Vs[jj][dd] = vv;
        }
        __syncthreads();

        float sc[64];
        float tmax = -1e30f;
        #pragma unroll
        for (int jj = 0; jj < 64; jj++) {
            int j = j0 + jj;
            int kpos = ci * 128 + j - 128;
            bool valid = (j >= r) && (j <= r + 256) && (kpos >= 0) && (kpos < 1024);
            float dot = 0.f;
            #pragma unroll
            for (int i2 = 0; i2 < 16; i2++) {
                float4 kv4 = *(const float4*)&Ks[jj][i2 * 4];
                dot += q[i2].x * kv4.x + q[i2].y * kv4.y +
                       q[i2].z * kv4.z + q[i2].w * kv4.w;
            }
            sc[jj] = valid ? dot * 0.125f : -1e30f;
            tmax = fmaxf(tmax, sc[jj]);
        }
        if (tmax > -1e29f) {
            float mnew  = fmaxf(m, tmax);
            float alpha = expf(m - mnew);
            l *= alpha;
            #pragma unroll
            for (int i2 = 0; i2 < 16; i2++) {
                acc[i2].x *= alpha; acc[i2].y *= alpha;
                acc[i2].z *= alpha; acc[i2].w *= alpha;
            }
            #pragma unroll
            for (int jj = 0; jj < 64; jj++) {
                float p = expf(sc[jj] - mnew);
                l += p;
                #pragma unroll
                for (int i2 = 0; i2 < 16; i2++) {
                    float4 vv = *(const float4*)&Vs[jj][i2 * 4];
                    acc[i2].x += p * vv.x; acc[i2].y += p * vv.y;
                    acc[i2].z += p * vv.z; acc[i2].w += p * vv.w;
                }
            }
            m = mnew;
        }
    }
    float rl = 1.f / l;
    __hip_bfloat16* optr = &Ob[((long)(b * 1024 + qpos)) * 768 + hh * 64];
    #pragma unroll
    for (int i2 = 0; i2 < 16; i2++) {
        optr[i2 * 4 + 0] = __float2bfloat16(acc[i2].x * rl);
        optr[i2 * 4 + 1] = __float2bfloat16(acc[i2].y * rl);
        optr[i2 * 4 + 2] = __float2bfloat16(acc[i2].z * rl);
        optr[i2 * 4 + 3] = __float2bfloat16(acc[i2].w * rl);
    }
}

// ---------------------------------------------------------------------------
// h = LayerNorm(h + t) in place; also writes bf16 mirror. grid = 8192, 256 thr.
// ---------------------------------------------------------------------------
__global__ __launch_bounds__(256) void add_ln_kernel(
    float* __restrict__ h, const float* __restrict__ t,
    const float* __restrict__ ln_s, const float* __restrict__ ln_b,
    __hip_bfloat16* __restrict__ hbf)
{
    int tok = blockIdx.x;
    int tid = threadIdx.x;
    __shared__ float red[8];
    float* hrow = &h[(long)tok * 768];
    const float* trow = &t[(long)tok * 768];
    int d0 = tid, d1 = tid + 256, d2 = tid + 512;
    float a0 = hrow[d0] + trow[d0];
    float a1 = hrow[d1] + trow[d1];
    float a2 = hrow[d2] + trow[d2];
    float sum = a0 + a1 + a2;
    float sumsq = a0 * a0 + a1 * a1 + a2 * a2;
    #pragma unroll
    for (int off = 32; off; off >>= 1) {
        sum   += __shfl_down(sum, off, 64);
        sumsq += __shfl_down(sumsq, off, 64);
    }
    if ((tid & 63) == 0) { red[tid >> 6] = sum; red[4 + (tid >> 6)] = sumsq; }
    __syncthreads();
    sum   = red[0] + red[1] + red[2] + red[3];
    sumsq = red[4] + red[5] + red[6] + red[7];
    float mean = sum * (1.f / 768.f);
    float var  = sumsq * (1.f / 768.f) - mean * mean;
    float rs   = rsqrtf(var + 1e-12f);
    __hip_bfloat16* brow = &hbf[(long)tok * 768];
    float o0 = (a0 - mean) * rs * ln_s[d0] + ln_b[d0];
    float o1 = (a1 - mean) * rs * ln_s[d1] + ln_b[d1];
    float o2 = (a2 - mean) * rs * ln_s[d2] + ln_b[d2];
    hrow[d0] = o0; hrow[d1] = o1; hrow[d2] = o2;
    brow[d0] = __float2bfloat16(o0);
    brow[d1] = __float2bfloat16(o1);
    brow[d2] = __float2bfloat16(o2);
}

// ---------------------------------------------------------------------------
// Head: pooled = tanh(h[:,0] @ pool_w + pool_b); LN; gelu(@w1+b1); @w2+b2.
// ---------------------------------------------------------------------------
__global__ __launch_bounds__(256) void head_kernel(
    const float* __restrict__ h, const float* __restrict__ pool_w,
    const float* __restrict__ pool_b, const float* __restrict__ hln_s,
    const float* __restrict__ hln_b, const float* __restrict__ w1,
    const float* __restrict__ b1, const float* __restrict__ w2,
    const float* __restrict__ b2, float* __restrict__ out)
{
    int b = blockIdx.x;
    int tid = threadIdx.x;
    __shared__ float row[768];
    __shared__ float z[768];
    __shared__ float z1[512];
    __shared__ float red[8];
    #pragma unroll
    for (int j = 0; j < 3; j++)
        row[tid + j * 256] = h[((long)b * 1024) * 768 + tid + j * 256];
    __syncthreads();
    float pv[3];
    float sum = 0.f, sumsq = 0.f;
    #pragma unroll
    for (int j = 0; j < 3; j++) {
        int d = tid + j * 256;
        float acc = pool_b[d];
        for (int k = 0; k < 768; k++) acc += row[k] * pool_w[k * 768 + d];
        acc = tanhf(acc);
        pv[j] = acc;
        sum += acc; sumsq += acc * acc;
    }
    #pragma unroll
    for (int off = 32; off; off >>= 1) {
        sum   += __shfl_down(sum, off, 64);
        sumsq += __shfl_down(sumsq, off, 64);
    }
    if ((tid & 63) == 0) { red[tid >> 6] = sum; red[4 + (tid >> 6)] = sumsq; }
    __syncthreads();
    sum   = red[0] + red[1] + red[2] + red[3];
    sumsq = red[4] + red[5] + red[6] + red[7];
    float mean = sum * (1.f / 768.f);
    float var  = sumsq * (1.f / 768.f) - mean * mean;
    float rs   = rsqrtf(var + 1e-12f);
    #pragma unroll
    for (int j = 0; j < 3; j++) {
        int d = tid + j * 256;
        z[d] = (pv[j] - mean) * rs * hln_s[d] + hln_b[d];
    }
    __syncthreads();
    #pragma unroll
    for (int j = 0; j < 2; j++) {
        int d = tid + j * 256;
        float acc = b1[d];
        for (int k = 0; k < 768; k++) acc += z[k] * w1[k * 512 + d];
        z1[d] = gelu_exact(acc);
    }
    __syncthreads();
    if (tid < 3) {
        float acc = b2[tid];
        for (int k = 0; k < 512; k++) acc += z1[k] * w2[k * 3 + tid];
        out[b * 3 + tid] = acc;
    }
}

// ---------------------------------------------------------------------------
extern "C" void kernel_launch(void* const* d_in, const int* in_sizes, int n_in,
                              void* d_out, int out_size, void* d_ws, size_t ws_size,
                              hipStream_t stream) {
    const float* x       = (const float*)d_in[0];
    const float* proj_w  = (const float*)d_in[2];
    const float* proj_b  = (const float*)d_in[3];
    const float* pos_emb = (const float*)d_in[4];
    const float* tok_emb = (const float*)d_in[5];
    const float* eln_s   = (const float*)d_in[6];
    const float* eln_b   = (const float*)d_in[7];
    const float* wq      = (const float*)d_in[8];
    const float* bq      = (const float*)d_in[9];
    const float* wk      = (const float*)d_in[10];
    const float* bk      = (const float*)d_in[11];
    const float* wv      = (const float*)d_in[12];
    const float* bv      = (const float*)d_in[13];
    const float* wo      = (const float*)d_in[14];
    const float* bo      = (const float*)d_in[15];
    const float* ln1_s   = (const float*)d_in[16];
    const float* ln1_b   = (const float*)d_in[17];
    const float* wi      = (const float*)d_in[18];
    const float* bi      = (const float*)d_in[19];
    const float* wo2     = (const float*)d_in[20];
    const float* bo2     = (const float*)d_in[21];
    const float* ln2_s   = (const float*)d_in[22];
    const float* ln2_b   = (const float*)d_in[23];
    const float* pool_w  = (const float*)d_in[24];
    const float* pool_b  = (const float*)d_in[25];
    const float* hln_s   = (const float*)d_in[26];
    const float* hln_b   = (const float*)d_in[27];
    const float* hw1     = (const float*)d_in[28];
    const float* hb1     = (const float*)d_in[29];
    const float* hw2     = (const float*)d_in[30];
    const float* hb2     = (const float*)d_in[31];

    // workspace layout (256-B aligned chunks), ~168 MB total
    char* wp = (char*)d_ws;
    auto alloc = [&](size_t bytes) {
        char* p = wp; wp += (bytes + 255) & ~(size_t)255; return p;
    };
    float*          h      = (float*)alloc(8192ll * 768 * 4);
    float*          qkv    = (float*)alloc(8192ll * 2304 * 4);   // also aliased below
    __hip_bfloat16* h_bf   = (__hip_bfloat16*)alloc(8192ll * 768 * 2);
    __hip_bfloat16* a_bf   = (__hip_bfloat16*)alloc(8192ll * 768 * 2);
    __hip_bfloat16* qkvw_t = (__hip_bfloat16*)alloc(3ll * 2304 * 768 * 2);
    __hip_bfloat16* wo_t   = (__hip_bfloat16*)alloc(3ll * 768 * 768 * 2);
    __hip_bfloat16* wi_t   = (__hip_bfloat16*)alloc(3ll * 3072 * 768 * 2);
    __hip_bfloat16* wo2_t  = (__hip_bfloat16*)alloc(3ll * 768 * 3072 * 2);
    float*          qkv_b  = (float*)alloc(3ll * 2304 * 4);
    // aliases into the dead qkv region (qkv is consumed by attn before these):
    float*          t      = qkv;                                          // 25.2 MB
    __hip_bfloat16* mlp_bf = (__hip_bfloat16*)((char*)qkv + 8192ll * 768 * 4); // 50.3 MB

    // ---- weight conversion (every call; graph-safe) ----
    transpose_bf16<<<dim3(24, 24, 3), 256, 0, stream>>>(wq, qkvw_t,               768, 768,  768ll * 768,  2304ll * 768);
    transpose_bf16<<<dim3(24, 24, 3), 256, 0, stream>>>(wk, qkvw_t + 768 * 768,   768, 768,  768ll * 768,  2304ll * 768);
    transpose_bf16<<<dim3(24, 24, 3), 256, 0, stream>>>(wv, qkvw_t + 1536 * 768,  768, 768,  768ll * 768,  2304ll * 768);
    transpose_bf16<<<dim3(24, 24, 3), 256, 0, stream>>>(wo, wo_t,                 768, 768,  768ll * 768,  768ll * 768);
    transpose_bf16<<<dim3(96, 24, 3), 256, 0, stream>>>(wi, wi_t,                 768, 3072, 768ll * 3072, 3072ll * 768);
    transpose_bf16<<<dim3(24, 96, 3), 256, 0, stream>>>(wo2, wo2_t,               3072, 768, 3072ll * 768, 768ll * 3072);
    pack_qkv_bias<<<3, 768, 0, stream>>>(bq, bk, bv, qkv_b);

    embed_kernel<<<8192, 256, 0, stream>>>(x, proj_w, proj_b, pos_emb, tok_emb,
                                           eln_s, eln_b, h, h_bf);

    for (int l = 0; l < 3; l++) {
        // fused QKV: [8192,768] @ [768,2304] -> qkv [8192,2304]
        mfma_gemm<0, float><<<dim3(18, 64), 256, 0, stream>>>(
            h_bf, qkvw_t + (long)l * 2304 * 768, qkv_b + l * 2304, qkv,
            8192, 2304, 768);
        attn_kernel<<<768, 128, 0, stream>>>(qkv, a_bf);
        // out-proj -> t (aliases qkv region; qkv is dead after attn)
        mfma_gemm<0, float><<<dim3(6, 64), 256, 0, stream>>>(
            a_bf, wo_t + (long)l * 768 * 768, bo + l * 768, t,
            8192, 768, 768);
        add_ln_kernel<<<8192, 256, 0, stream>>>(h, t, ln1_s + l * 768, ln1_b + l * 768, h_bf);
        // MLP up + gelu -> bf16
        mfma_gemm<1, __hip_bfloat16><<<dim3(24, 64), 256, 0, stream>>>(
            h_bf, wi_t + (long)l * 3072 * 768, bi + l * 3072, mlp_bf,
            8192, 3072, 768);
        // MLP down -> t
        mfma_gemm<0, float><<<dim3(6, 64), 256, 0, stream>>>(
            mlp_bf, wo2_t + (long)l * 768 * 3072, bo2 + l * 768, t,
            8192, 768, 3072);
        add_ln_kernel<<<8192, 256, 0, stream>>>(h, t, ln2_s + l * 768, ln2_b + l * 768, h_bf);
    }

    head_kernel<<<8, 256, 0, stream>>>(h, pool_w, pool_b, hln_s, hln_b,
                                       hw1, hb1, hw2, hb2, (float*)d_out);
}

// Round 4
// 1585.783 us; speedup vs baseline: 4.7608x; 1.8256x over previous
//
#include <hip/hip_runtime.h>
#include <hip/hip_bf16.h>
#include <math.h>

// B=8, S=1024, D=768, H=12, DH=64, L=3, I=3072, W1S=128, nc=8, MLP=512, NCLS=3

typedef __attribute__((ext_vector_type(8))) short short8;   // 8 bf16 (4 VGPRs)
typedef __attribute__((ext_vector_type(4))) short short4v;  // 4 bf16 (8 B)
typedef __attribute__((ext_vector_type(4))) float floatx4;  // MFMA C/D

__device__ __forceinline__ float gelu_exact(float x) {
    return 0.5f * x * (1.f + erff(x * 0.70710678118654752440f));
}

__device__ __forceinline__ short bfs(float x) {
    __hip_bfloat16 h = __float2bfloat16(x);
    short s;
    __builtin_memcpy(&s, &h, 2);
    return s;
}

#define GLOAD_LDS16(g, l) __builtin_amdgcn_global_load_lds( \
    (const __attribute__((address_space(1))) void*)(g),     \
    (__attribute__((address_space(3))) void*)(l), 16, 0, 0)

// ---------------------------------------------------------------------------
// Weight convert+transpose: W[K,N] fp32 -> Wt[N,K] bf16. blockIdx.z = layer.
// ---------------------------------------------------------------------------
__global__ __launch_bounds__(256) void transpose_bf16(
    const float* __restrict__ W, __hip_bfloat16* __restrict__ Wt,
    int K, int N, long inLS, long outLS)
{
    __shared__ float tile[32][33];
    int l = blockIdx.z;
    const float* Wl = W + (long)l * inLS;
    __hip_bfloat16* Wtl = Wt + (long)l * outLS;
    int lx = threadIdx.x & 31, ly = threadIdx.x >> 5;
    int kb = blockIdx.y * 32, nb = blockIdx.x * 32;
    #pragma unroll
    for (int r = 0; r < 32; r += 8)
        tile[ly + r][lx] = Wl[(long)(kb + ly + r) * N + nb + lx];
    __syncthreads();
    #pragma unroll
    for (int r = 0; r < 32; r += 8)
        Wtl[(long)(nb + ly + r) * K + kb + lx] = __float2bfloat16(tile[lx][ly + r]);
}

__global__ void pack_qkv_bias(const float* __restrict__ bq,
                              const float* __restrict__ bk,
                              const float* __restrict__ bv,
                              float* __restrict__ out)
{
    int l = blockIdx.x, tid = threadIdx.x;   // 768 threads
    out[l * 2304 + tid]        = bq[l * 768 + tid];
    out[l * 2304 + 768 + tid]  = bk[l * 768 + tid];
    out[l * 2304 + 1536 + tid] = bv[l * 768 + tid];
}

// ---------------------------------------------------------------------------
// bf16 MFMA GEMM: C[M,N] = A[M,K](bf16) @ Bt[N,K](bf16)^T + bias.
// 128x128 tile, BK=32, 256 thr = 4 waves, each wave 64x64 via 4x4 of
// mfma_f32_16x16x32_bf16. Staging via global_load_lds width=16 (m97 recipe).
// ---------------------------------------------------------------------------
template<int ACT, typename OT>
__global__ __launch_bounds__(256) void mfma_gemm(
    const __hip_bfloat16* __restrict__ A, const __hip_bfloat16* __restrict__ Bt,
    const float* __restrict__ bias, OT* __restrict__ C, int M, int N, int K)
{
    __shared__ __hip_bfloat16 As[128 * 32];
    __shared__ __hip_bfloat16 Bs[128 * 32];
    int tid  = threadIdx.x;
    int wave = tid >> 6, lane = tid & 63;
    long m0 = (long)blockIdx.y * 128, n0 = (long)blockIdx.x * 128;
    int wr = wave >> 1, wc = wave & 1;
    floatx4 acc[4][4] = {};

    int srow = (wave * 128 + lane) >> 2;
    int sch  = lane & 3;
    const __hip_bfloat16* Ag = A  + (m0 + srow) * K + sch * 8;
    const __hip_bfloat16* Bg = Bt + (n0 + srow) * K + sch * 8;
    __hip_bfloat16* AsW = &As[wave * 128 * 8];
    __hip_bfloat16* BsW = &Bs[wave * 128 * 8];
    int lm = lane & 15, lk8 = (lane >> 4) * 8;

    for (int k0 = 0; k0 < K; k0 += 32) {
        GLOAD_LDS16(Ag + k0,          AsW);
        GLOAD_LDS16(Ag + 16 * K + k0, AsW + 64 * 8);
        GLOAD_LDS16(Bg + k0,          BsW);
        GLOAD_LDS16(Bg + 16 * K + k0, BsW + 64 * 8);
        __syncthreads();
        short8 af[4], bf[4];
        #pragma unroll
        for (int mi = 0; mi < 4; mi++)
            af[mi] = *(const short8*)&As[(wr * 64 + mi * 16 + lm) * 32 + lk8];
        #pragma unroll
        for (int ni = 0; ni < 4; ni++)
            bf[ni] = *(const short8*)&Bs[(wc * 64 + ni * 16 + lm) * 32 + lk8];
        #pragma unroll
        for (int mi = 0; mi < 4; mi++)
            #pragma unroll
            for (int ni = 0; ni < 4; ni++)
                acc[mi][ni] = __builtin_amdgcn_mfma_f32_16x16x32_bf16(
                    af[mi], bf[ni], acc[mi][ni], 0, 0, 0);
        __syncthreads();
    }

    int colb = (int)n0 + wc * 64 + lm;
    int rowb = (int)m0 + wr * 64 + (lane >> 4) * 4;
    #pragma unroll
    for (int ni = 0; ni < 4; ni++) {
        int col = colb + ni * 16;
        float bv = bias[col];
        #pragma unroll
        for (int mi = 0; mi < 4; mi++) {
            #pragma unroll
            for (int j = 0; j < 4; j++) {
                float o = acc[mi][ni][j] + bv;
                if (ACT == 1) o = gelu_exact(o);
                long idx = (long)(rowb + mi * 16 + j) * N + col;
                if constexpr (sizeof(OT) == 2) C[idx] = __float2bfloat16(o);
                else                           C[idx] = o;
            }
        }
    }
}

// ---------------------------------------------------------------------------
// Embed (unchanged)
// ---------------------------------------------------------------------------
__global__ __launch_bounds__(256) void embed_kernel(
    const float* __restrict__ x, const float* __restrict__ proj_w,
    const float* __restrict__ proj_b, const float* __restrict__ pos_emb,
    const float* __restrict__ tok_emb, const float* __restrict__ ln_s,
    const float* __restrict__ ln_b, float* __restrict__ h,
    __hip_bfloat16* __restrict__ hbf)
{
    int tok = blockIdx.x;
    int b = tok >> 10;
    int s = tok & 1023;
    int tci = s >> 6, sci = (s >> 3) & 7, scj = s & 7;
    __shared__ float xrow[192];
    __shared__ float red[8];
    int tid = threadIdx.x;
    if (tid < 192) {
        int ch  = tid % 3;
        int crc = tid / 3;
        int cr1 = crc >> 4, cr2 = (crc >> 2) & 3, cr3 = crc & 3;
        xrow[tid] = x[(((b * 3 + ch) * 64) + cr1 * 16 + tci) * 1024 +
                      (cr2 * 8 + sci) * 32 + cr3 * 8 + scj];
    }
    __syncthreads();
    int d0 = tid, d1 = tid + 256, d2 = tid + 512;
    float a0 = proj_b[d0] + pos_emb[s * 768 + d0] + tok_emb[d0];
    float a1 = proj_b[d1] + pos_emb[s * 768 + d1] + tok_emb[d1];
    float a2 = proj_b[d2] + pos_emb[s * 768 + d2] + tok_emb[d2];
    for (int k = 0; k < 192; k++) {
        float xk = xrow[k];
        const float* wrow = &proj_w[k * 768];
        a0 += xk * wrow[d0];
        a1 += xk * wrow[d1];
        a2 += xk * wrow[d2];
    }
    float sum = a0 + a1 + a2;
    float sumsq = a0 * a0 + a1 * a1 + a2 * a2;
    #pragma unroll
    for (int off = 32; off; off >>= 1) {
        sum   += __shfl_down(sum, off, 64);
        sumsq += __shfl_down(sumsq, off, 64);
    }
    if ((tid & 63) == 0) { red[tid >> 6] = sum; red[4 + (tid >> 6)] = sumsq; }
    __syncthreads();
    sum   = red[0] + red[1] + red[2] + red[3];
    sumsq = red[4] + red[5] + red[6] + red[7];
    float mean = sum * (1.f / 768.f);
    float var  = sumsq * (1.f / 768.f) - mean * mean;
    float rs   = rsqrtf(var + 1e-12f);
    float* hrow = &h[(long)tok * 768];
    __hip_bfloat16* brow = &hbf[(long)tok * 768];
    float o0 = (a0 - mean) * rs * ln_s[d0] + ln_b[d0];
    float o1 = (a1 - mean) * rs * ln_s[d1] + ln_b[d1];
    float o2 = (a2 - mean) * rs * ln_s[d2] + ln_b[d2];
    hrow[d0] = o0; hrow[d1] = o1; hrow[d2] = o2;
    brow[d0] = __float2bfloat16(o0);
    brow[d1] = __float2bfloat16(o1);
    brow[d2] = __float2bfloat16(o2);
}

// ---------------------------------------------------------------------------
// MFMA band attention. One block per (b, head, chunk): 128 queries x 384-key
// window. 256 thr = 4 waves; wave w owns query rows w*32..w*32+31.
// Per 128-key tile: S^T = K@Q^T (C-layout: row=key, col=query), mask, online
// softmax (2-shuffle per-query reduce), P packed to LDS in A-layout, then
// O += P@V with V^T staged in LDS (shares buffer with K; 2-phase, 4 barriers).
// ---------------------------------------------------------------------------
__global__ __launch_bounds__(256) void attn_kernel(
    const float* __restrict__ QKV, __hip_bfloat16* __restrict__ Ob)
{
    __shared__ __hip_bfloat16 KV[128 * 72];       // Ks[128][72]  /  Vt[64][136]
    __shared__ __hip_bfloat16 Pl[4][32 * 136];    // per-wave P[query][key]
    __shared__ float alpha_s[4][32];
    __shared__ float l_s[4][32];

    int blk = blockIdx.x;
    int ci = blk & 7, hh = (blk >> 3) % 12, b = blk / 96;
    int tid = threadIdx.x, w = tid >> 6, lane = tid & 63;
    int lm = lane & 15, lg = lane >> 4;
    __hip_bfloat16* Pw = &Pl[w][0];

    // Q fragments (B-operand of S^T): qf[nt][ks], query = w*32+nt*16+lm
    short8 qf[2][2];
    #pragma unroll
    for (int nt = 0; nt < 2; nt++) {
        int q = ci * 128 + w * 32 + nt * 16 + lm;
        const float* qp = &QKV[((long)(b * 1024 + q)) * 2304 + hh * 64];
        #pragma unroll
        for (int ks = 0; ks < 2; ks++) {
            float4 f0 = *(const float4*)(qp + ks * 32 + lg * 8);
            float4 f1 = *(const float4*)(qp + ks * 32 + lg * 8 + 4);
            short8 v;
            v[0] = bfs(f0.x); v[1] = bfs(f0.y); v[2] = bfs(f0.z); v[3] = bfs(f0.w);
            v[4] = bfs(f1.x); v[5] = bfs(f1.y); v[6] = bfs(f1.z); v[7] = bfs(f1.w);
            qf[nt][ks] = v;
        }
    }

    floatx4 accO[2][4] = {};
    float m_run[2] = {-1e30f, -1e30f};
    float l_run[2] = {0.f, 0.f};

    for (int tt = 0; tt < 3; tt++) {
        __syncthreads();
        // ---- stage K tile: Ks[key][72] bf16, coalesced float4 reads ----
        #pragma unroll
        for (int i = 0; i < 8; i++) {
            int e = tid + i * 256;
            int jj = e >> 4, dd = (e & 15) * 4;
            int kpos = ci * 128 + tt * 128 + jj - 128;
            float4 kv = make_float4(0.f, 0.f, 0.f, 0.f);
            if (kpos >= 0 && kpos < 1024)
                kv = *(const float4*)&QKV[((long)(b * 1024 + kpos)) * 2304 + 768 + hh * 64 + dd];
            short4v kp;
            kp[0] = bfs(kv.x); kp[1] = bfs(kv.y); kp[2] = bfs(kv.z); kp[3] = bfs(kv.w);
            *(short4v*)&KV[jj * 72 + dd] = kp;
        }
        __syncthreads();

        // ---- S^T = K @ Q^T : m=key(128, 8 tiles), n=query(32, 2), k=dh(64) ----
        floatx4 accS[8][2] = {};
        #pragma unroll
        for (int ks = 0; ks < 2; ks++)
            #pragma unroll
            for (int mt = 0; mt < 8; mt++) {
                short8 kf = *(const short8*)&KV[(mt * 16 + lm) * 72 + ks * 32 + lg * 8];
                accS[mt][0] = __builtin_amdgcn_mfma_f32_16x16x32_bf16(kf, qf[0][ks], accS[mt][0], 0, 0, 0);
                accS[mt][1] = __builtin_amdgcn_mfma_f32_16x16x32_bf16(kf, qf[1][ks], accS[mt][1], 0, 0, 0);
            }

        // ---- mask + scale in place; per-query tile max ----
        float tmax[2] = {-1e30f, -1e30f};
        #pragma unroll
        for (int nt = 0; nt < 2; nt++) {
            int r = w * 32 + nt * 16 + lm;
            #pragma unroll
            for (int mt = 0; mt < 8; mt++)
                #pragma unroll
                for (int j = 0; j < 4; j++) {
                    int jrel = tt * 128 + mt * 16 + lg * 4 + j;
                    int kpos = ci * 128 + jrel - 128;
                    bool valid = (jrel >= r) && (jrel <= r + 256) &&
                                 (kpos >= 0) && (kpos < 1024);
                    float s = valid ? accS[mt][nt][j] * 0.125f : -1e9f;
                    accS[mt][nt][j] = s;
                    tmax[nt] = fmaxf(tmax[nt], s);
                }
            tmax[nt] = fmaxf(tmax[nt], __shfl_xor(tmax[nt], 16));
            tmax[nt] = fmaxf(tmax[nt], __shfl_xor(tmax[nt], 32));
        }

        // ---- online softmax: p=exp(s-mnew), pack to P (A-layout), l update ----
        float al[2];
        #pragma unroll
        for (int nt = 0; nt < 2; nt++) {
            float mnew = fmaxf(m_run[nt], tmax[nt]);
            al[nt] = __expf(m_run[nt] - mnew);
            m_run[nt] = mnew;
            float ts = 0.f;
            #pragma unroll
            for (int mt = 0; mt < 8; mt++) {
                short4v pp;
                #pragma unroll
                for (int j = 0; j < 4; j++) {
                    float p = __expf(accS[mt][nt][j] - mnew);
                    ts += p;
                    pp[j] = bfs(p);
                }
                *(short4v*)&Pw[(nt * 16 + lm) * 136 + mt * 16 + lg * 4] = pp;
            }
            ts += __shfl_xor(ts, 16);
            ts += __shfl_xor(ts, 32);
            l_run[nt] = l_run[nt] * al[nt] + ts;
        }
        if (lg < 2) alpha_s[w][lg * 16 + lm] = al[lg];

        __syncthreads();
        // ---- stage V tile transposed: Vt[dh][136] (overwrites Ks) ----
        #pragma unroll
        for (int i = 0; i < 8; i++) {
            int e = tid + i * 256;
            int jj = e >> 4, dd = (e & 15) * 4;
            int kpos = ci * 128 + tt * 128 + jj - 128;
            float4 vv = make_float4(0.f, 0.f, 0.f, 0.f);
            if (kpos >= 0 && kpos < 1024)
                vv = *(const float4*)&QKV[((long)(b * 1024 + kpos)) * 2304 + 1536 + hh * 64 + dd];
            KV[(dd + 0) * 136 + jj] = __float2bfloat16(vv.x);
            KV[(dd + 1) * 136 + jj] = __float2bfloat16(vv.y);
            KV[(dd + 2) * 136 + jj] = __float2bfloat16(vv.z);
            KV[(dd + 3) * 136 + jj] = __float2bfloat16(vv.w);
        }
        __syncthreads();

        // ---- rescale accO by alpha (per query row in C-layout) ----
        #pragma unroll
        for (int mo = 0; mo < 2; mo++)
            #pragma unroll
            for (int j = 0; j < 4; j++) {
                float a = alpha_s[w][mo * 16 + lg * 4 + j];
                #pragma unroll
                for (int nd = 0; nd < 4; nd++)
                    accO[mo][nd][j] *= a;
            }

        // ---- O += P @ V : m=query(32, 2), n=dh(64, 4), k=key(128, 4 steps) ----
        #pragma unroll
        for (int kk = 0; kk < 4; kk++) {
            short8 pf[2], vf[4];
            #pragma unroll
            for (int mo = 0; mo < 2; mo++)
                pf[mo] = *(const short8*)&Pw[(mo * 16 + lm) * 136 + kk * 32 + lg * 8];
            #pragma unroll
            for (int nd = 0; nd < 4; nd++)
                vf[nd] = *(const short8*)&KV[(nd * 16 + lm) * 136 + kk * 32 + lg * 8];
            #pragma unroll
            for (int mo = 0; mo < 2; mo++)
                #pragma unroll
                for (int nd = 0; nd < 4; nd++)
                    accO[mo][nd] = __builtin_amdgcn_mfma_f32_16x16x32_bf16(
                        pf[mo], vf[nd], accO[mo][nd], 0, 0, 0);
        }
    }

    // ---- epilogue: divide by l, store bf16 ----
    // BUGFIX (R3->R4): l_s index must be the WITHIN-WAVE row qr (0..31),
    // not the chunk-level row w*32+qr — waves 1..3 read wrong/OOB l before.
    if (lg < 2) l_s[w][lg * 16 + lm] = l_run[lg];
    #pragma unroll
    for (int mo = 0; mo < 2; mo++)
        #pragma unroll
        for (int j = 0; j < 4; j++) {
            int qr = mo * 16 + lg * 4 + j;       // within-wave row, 0..31
            float rl = 1.f / l_s[w][qr];
            int q  = w * 32 + qr;                // row within chunk
            long base = ((long)(b * 1024 + ci * 128 + q)) * 768 + hh * 64;
            #pragma unroll
            for (int nd = 0; nd < 4; nd++)
                Ob[base + nd * 16 + lm] = __float2bfloat16(accO[mo][nd][j] * rl);
        }
}

// ---------------------------------------------------------------------------
// h = LayerNorm(h + t) in place; also writes bf16 mirror.
// ---------------------------------------------------------------------------
__global__ __launch_bounds__(256) void add_ln_kernel(
    float* __restrict__ h, const float* __restrict__ t,
    const float* __restrict__ ln_s, const float* __restrict__ ln_b,
    __hip_bfloat16* __restrict__ hbf)
{
    int tok = blockIdx.x;
    int tid = threadIdx.x;
    __shared__ float red[8];
    float* hrow = &h[(long)tok * 768];
    const float* trow = &t[(long)tok * 768];
    int d0 = tid, d1 = tid + 256, d2 = tid + 512;
    float a0 = hrow[d0] + trow[d0];
    float a1 = hrow[d1] + trow[d1];
    float a2 = hrow[d2] + trow[d2];
    float sum = a0 + a1 + a2;
    float sumsq = a0 * a0 + a1 * a1 + a2 * a2;
    #pragma unroll
    for (int off = 32; off; off >>= 1) {
        sum   += __shfl_down(sum, off, 64);
        sumsq += __shfl_down(sumsq, off, 64);
    }
    if ((tid & 63) == 0) { red[tid >> 6] = sum; red[4 + (tid >> 6)] = sumsq; }
    __syncthreads();
    sum   = red[0] + red[1] + red[2] + red[3];
    sumsq = red[4] + red[5] + red[6] + red[7];
    float mean = sum * (1.f / 768.f);
    float var  = sumsq * (1.f / 768.f) - mean * mean;
    float rs   = rsqrtf(var + 1e-12f);
    __hip_bfloat16* brow = &hbf[(long)tok * 768];
    float o0 = (a0 - mean) * rs * ln_s[d0] + ln_b[d0];
    float o1 = (a1 - mean) * rs * ln_s[d1] + ln_b[d1];
    float o2 = (a2 - mean) * rs * ln_s[d2] + ln_b[d2];
    hrow[d0] = o0; hrow[d1] = o1; hrow[d2] = o2;
    brow[d0] = __float2bfloat16(o0);
    brow[d1] = __float2bfloat16(o1);
    brow[d2] = __float2bfloat16(o2);
}

// ---------------------------------------------------------------------------
// Head (unchanged)
// ---------------------------------------------------------------------------
__global__ __launch_bounds__(256) void head_kernel(
    const float* __restrict__ h, const float* __restrict__ pool_w,
    const float* __restrict__ pool_b, const float* __restrict__ hln_s,
    const float* __restrict__ hln_b, const float* __restrict__ w1,
    const float* __restrict__ b1, const float* __restrict__ w2,
    const float* __restrict__ b2, float* __restrict__ out)
{
    int b = blockIdx.x;
    int tid = threadIdx.x;
    __shared__ float row[768];
    __shared__ float z[768];
    __shared__ float z1[512];
    __shared__ float red[8];
    #pragma unroll
    for (int j = 0; j < 3; j++)
        row[tid + j * 256] = h[((long)b * 1024) * 768 + tid + j * 256];
    __syncthreads();
    float pv[3];
    float sum = 0.f, sumsq = 0.f;
    #pragma unroll
    for (int j = 0; j < 3; j++) {
        int d = tid + j * 256;
        float acc = pool_b[d];
        for (int k = 0; k < 768; k++) acc += row[k] * pool_w[k * 768 + d];
        acc = tanhf(acc);
        pv[j] = acc;
        sum += acc; sumsq += acc * acc;
    }
    #pragma unroll
    for (int off = 32; off; off >>= 1) {
        sum   += __shfl_down(sum, off, 64);
        sumsq += __shfl_down(sumsq, off, 64);
    }
    if ((tid & 63) == 0) { red[tid >> 6] = sum; red[4 + (tid >> 6)] = sumsq; }
    __syncthreads();
    sum   = red[0] + red[1] + red[2] + red[3];
    sumsq = red[4] + red[5] + red[6] + red[7];
    float mean = sum * (1.f / 768.f);
    float var  = sumsq * (1.f / 768.f) - mean * mean;
    float rs   = rsqrtf(var + 1e-12f);
    #pragma unroll
    for (int j = 0; j < 3; j++) {
        int d = tid + j * 256;
        z[d] = (pv[j] - mean) * rs * hln_s[d] + hln_b[d];
    }
    __syncthreads();
    #pragma unroll
    for (int j = 0; j < 2; j++) {
        int d = tid + j * 256;
        float acc = b1[d];
        for (int k = 0; k < 768; k++) acc += z[k] * w1[k * 512 + d];
        z1[d] = gelu_exact(acc);
    }
    __syncthreads();
    if (tid < 3) {
        float acc = b2[tid];
        for (int k = 0; k < 512; k++) acc += z1[k] * w2[k * 3 + tid];
        out[b * 3 + tid] = acc;
    }
}

// ---------------------------------------------------------------------------
extern "C" void kernel_launch(void* const* d_in, const int* in_sizes, int n_in,
                              void* d_out, int out_size, void* d_ws, size_t ws_size,
                              hipStream_t stream) {
    const float* x       = (const float*)d_in[0];
    const float* proj_w  = (const float*)d_in[2];
    const float* proj_b  = (const float*)d_in[3];
    const float* pos_emb = (const float*)d_in[4];
    const float* tok_emb = (const float*)d_in[5];
    const float* eln_s   = (const float*)d_in[6];
    const float* eln_b   = (const float*)d_in[7];
    const float* wq      = (const float*)d_in[8];
    const float* bq      = (const float*)d_in[9];
    const float* wk      = (const float*)d_in[10];
    const float* bk      = (const float*)d_in[11];
    const float* wv      = (const float*)d_in[12];
    const float* bv      = (const float*)d_in[13];
    const float* wo      = (const float*)d_in[14];
    const float* bo      = (const float*)d_in[15];
    const float* ln1_s   = (const float*)d_in[16];
    const float* ln1_b   = (const float*)d_in[17];
    const float* wi      = (const float*)d_in[18];
    const float* bi      = (const float*)d_in[19];
    const float* wo2     = (const float*)d_in[20];
    const float* bo2     = (const float*)d_in[21];
    const float* ln2_s   = (const float*)d_in[22];
    const float* ln2_b   = (const float*)d_in[23];
    const float* pool_w  = (const float*)d_in[24];
    const float* pool_b  = (const float*)d_in[25];
    const float* hln_s   = (const float*)d_in[26];
    const float* hln_b   = (const float*)d_in[27];
    const float* hw1     = (const float*)d_in[28];
    const float* hb1     = (const float*)d_in[29];
    const float* hw2     = (const float*)d_in[30];
    const float* hb2     = (const float*)d_in[31];

    char* wp = (char*)d_ws;
    auto alloc = [&](size_t bytes) {
        char* p = wp; wp += (bytes + 255) & ~(size_t)255; return p;
    };
    float*          h      = (float*)alloc(8192ll * 768 * 4);
    float*          qkv    = (float*)alloc(8192ll * 2304 * 4);
    __hip_bfloat16* h_bf   = (__hip_bfloat16*)alloc(8192ll * 768 * 2);
    __hip_bfloat16* a_bf   = (__hip_bfloat16*)alloc(8192ll * 768 * 2);
    __hip_bfloat16* qkvw_t = (__hip_bfloat16*)alloc(3ll * 2304 * 768 * 2);
    __hip_bfloat16* wo_t   = (__hip_bfloat16*)alloc(3ll * 768 * 768 * 2);
    __hip_bfloat16* wi_t   = (__hip_bfloat16*)alloc(3ll * 3072 * 768 * 2);
    __hip_bfloat16* wo2_t  = (__hip_bfloat16*)alloc(3ll * 768 * 3072 * 2);
    float*          qkv_b  = (float*)alloc(3ll * 2304 * 4);
    float*          t      = qkv;                                          // alias
    __hip_bfloat16* mlp_bf = (__hip_bfloat16*)((char*)qkv + 8192ll * 768 * 4);

    transpose_bf16<<<dim3(24, 24, 3), 256, 0, stream>>>(wq, qkvw_t,               768, 768,  768ll * 768,  2304ll * 768);
    transpose_bf16<<<dim3(24, 24, 3), 256, 0, stream>>>(wk, qkvw_t + 768 * 768,   768, 768,  768ll * 768,  2304ll * 768);
    transpose_bf16<<<dim3(24, 24, 3), 256, 0, stream>>>(wv, qkvw_t + 1536 * 768,  768, 768,  768ll * 768,  2304ll * 768);
    transpose_bf16<<<dim3(24, 24, 3), 256, 0, stream>>>(wo, wo_t,                 768, 768,  768ll * 768,  768ll * 768);
    transpose_bf16<<<dim3(96, 24, 3), 256, 0, stream>>>(wi, wi_t,                 768, 3072, 768ll * 3072, 3072ll * 768);
    transpose_bf16<<<dim3(24, 96, 3), 256, 0, stream>>>(wo2, wo2_t,               3072, 768, 3072ll * 768, 768ll * 3072);
    pack_qkv_bias<<<3, 768, 0, stream>>>(bq, bk, bv, qkv_b);

    embed_kernel<<<8192, 256, 0, stream>>>(x, proj_w, proj_b, pos_emb, tok_emb,
                                           eln_s, eln_b, h, h_bf);

    for (int l = 0; l < 3; l++) {
        mfma_gemm<0, float><<<dim3(18, 64), 256, 0, stream>>>(
            h_bf, qkvw_t + (long)l * 2304 * 768, qkv_b + l * 2304, qkv,
            8192, 2304, 768);
        attn_kernel<<<768, 256, 0, stream>>>(qkv, a_bf);
        mfma_gemm<0, float><<<dim3(6, 64), 256, 0, stream>>>(
            a_bf, wo_t + (long)l * 768 * 768, bo + l * 768, t,
            8192, 768, 768);
        add_ln_kernel<<<8192, 256, 0, stream>>>(h, t, ln1_s + l * 768, ln1_b + l * 768, h_bf);
        mfma_gemm<1, __hip_bfloat16><<<dim3(24, 64), 256, 0, stream>>>(
            h_bf, wi_t + (long)l * 3072 * 768, bi + l * 3072, mlp_bf,
            8192, 3072, 768);
        mfma_gemm<0, float><<<dim3(6, 64), 256, 0, stream>>>(
            mlp_bf, wo2_t + (long)l * 768 * 3072, bo2 + l * 768, t,
            8192, 768, 3072);
        add_ln_kernel<<<8192, 256, 0, stream>>>(h, t, ln2_s + l * 768, ln2_b + l * 768, h_bf);
    }

    head_kernel<<<8, 256, 0, stream>>>(h, pool_w, pool_b, hln_s, hln_b,
                                       hw1, hb1, hw2, hb2, (float*)d_out);
}

// Round 5
// 1478.112 us; speedup vs baseline: 5.1076x; 1.0728x over previous
//
#include <hip/hip_runtime.h>
#include <hip/hip_bf16.h>
#include <math.h>

// B=8, S=1024, D=768, H=12, DH=64, L=3, I=3072, W1S=128, nc=8, MLP=512, NCLS=3

typedef __attribute__((ext_vector_type(8))) short short8;   // 8 bf16 (4 VGPRs)
typedef __attribute__((ext_vector_type(4))) short short4v;  // 4 bf16 (8 B)
typedef __attribute__((ext_vector_type(4))) float floatx4;  // MFMA C/D

__device__ __forceinline__ float gelu_exact(float x) {
    return 0.5f * x * (1.f + erff(x * 0.70710678118654752440f));
}

__device__ __forceinline__ short bfs(float x) {
    __hip_bfloat16 h = __float2bfloat16(x);
    short s;
    __builtin_memcpy(&s, &h, 2);
    return s;
}

#define GLOAD_LDS16(g, l) __builtin_amdgcn_global_load_lds( \
    (const __attribute__((address_space(1))) void*)(g),     \
    (__attribute__((address_space(3))) void*)(l), 16, 0, 0)

// ---------------------------------------------------------------------------
// Weight convert+transpose: W[K,N] fp32 -> Wt[N,K] bf16. blockIdx.z = layer.
// ---------------------------------------------------------------------------
__global__ __launch_bounds__(256) void transpose_bf16(
    const float* __restrict__ W, __hip_bfloat16* __restrict__ Wt,
    int K, int N, long inLS, long outLS)
{
    __shared__ float tile[32][33];
    int l = blockIdx.z;
    const float* Wl = W + (long)l * inLS;
    __hip_bfloat16* Wtl = Wt + (long)l * outLS;
    int lx = threadIdx.x & 31, ly = threadIdx.x >> 5;
    int kb = blockIdx.y * 32, nb = blockIdx.x * 32;
    #pragma unroll
    for (int r = 0; r < 32; r += 8)
        tile[ly + r][lx] = Wl[(long)(kb + ly + r) * N + nb + lx];
    __syncthreads();
    #pragma unroll
    for (int r = 0; r < 32; r += 8)
        Wtl[(long)(nb + ly + r) * K + kb + lx] = __float2bfloat16(tile[lx][ly + r]);
}

__global__ void pack_qkv_bias(const float* __restrict__ bq,
                              const float* __restrict__ bk,
                              const float* __restrict__ bv,
                              float* __restrict__ out)
{
    int l = blockIdx.x, tid = threadIdx.x;   // 768 threads
    out[l * 2304 + tid]        = bq[l * 768 + tid];
    out[l * 2304 + 768 + tid]  = bk[l * 768 + tid];
    out[l * 2304 + 1536 + tid] = bv[l * 768 + tid];
}

// ---------------------------------------------------------------------------
// Patchify gather: x (8,3,64,32,32) fp32 -> xr_bf [8192 tokens][192] bf16.
// ---------------------------------------------------------------------------
__global__ __launch_bounds__(192) void gather_x(
    const float* __restrict__ x, __hip_bfloat16* __restrict__ xr)
{
    int tok = blockIdx.x;           // 0..8191
    int b = tok >> 10, s = tok & 1023;
    int tci = s >> 6, sci = (s >> 3) & 7, scj = s & 7;
    int f = threadIdx.x;            // 0..191
    int ch  = f % 3;
    int crc = f / 3;
    int cr1 = crc >> 4, cr2 = (crc >> 2) & 3, cr3 = crc & 3;
    float v = x[(((b * 3 + ch) * 64) + cr1 * 16 + tci) * 1024 +
                (cr2 * 8 + sci) * 32 + cr3 * 8 + scj];
    xr[(long)tok * 192 + f] = __float2bfloat16(v);
}

// ---------------------------------------------------------------------------
// bf16 MFMA GEMM: C[M,N] = A[M,K](bf16) @ Bt[N,K](bf16)^T + bias.
// 128x128 tile, BK=32, 256 thr = 4 waves, each wave 64x64 via 4x4 of
// mfma_f32_16x16x32_bf16. Staging via global_load_lds width=16 (m97 recipe).
// ---------------------------------------------------------------------------
template<int ACT, typename OT>
__global__ __launch_bounds__(256) void mfma_gemm(
    const __hip_bfloat16* __restrict__ A, const __hip_bfloat16* __restrict__ Bt,
    const float* __restrict__ bias, OT* __restrict__ C, int M, int N, int K)
{
    __shared__ __hip_bfloat16 As[128 * 32];
    __shared__ __hip_bfloat16 Bs[128 * 32];
    int tid  = threadIdx.x;
    int wave = tid >> 6, lane = tid & 63;
    long m0 = (long)blockIdx.y * 128, n0 = (long)blockIdx.x * 128;
    int wr = wave >> 1, wc = wave & 1;
    floatx4 acc[4][4] = {};

    int srow = (wave * 128 + lane) >> 2;
    int sch  = lane & 3;
    const __hip_bfloat16* Ag = A  + (m0 + srow) * K + sch * 8;
    const __hip_bfloat16* Bg = Bt + (n0 + srow) * K + sch * 8;
    __hip_bfloat16* AsW = &As[wave * 128 * 8];
    __hip_bfloat16* BsW = &Bs[wave * 128 * 8];
    int lm = lane & 15, lk8 = (lane >> 4) * 8;

    for (int k0 = 0; k0 < K; k0 += 32) {
        GLOAD_LDS16(Ag + k0,          AsW);
        GLOAD_LDS16(Ag + 16 * K + k0, AsW + 64 * 8);
        GLOAD_LDS16(Bg + k0,          BsW);
        GLOAD_LDS16(Bg + 16 * K + k0, BsW + 64 * 8);
        __syncthreads();
        short8 af[4], bf[4];
        #pragma unroll
        for (int mi = 0; mi < 4; mi++)
            af[mi] = *(const short8*)&As[(wr * 64 + mi * 16 + lm) * 32 + lk8];
        #pragma unroll
        for (int ni = 0; ni < 4; ni++)
            bf[ni] = *(const short8*)&Bs[(wc * 64 + ni * 16 + lm) * 32 + lk8];
        #pragma unroll
        for (int mi = 0; mi < 4; mi++)
            #pragma unroll
            for (int ni = 0; ni < 4; ni++)
                acc[mi][ni] = __builtin_amdgcn_mfma_f32_16x16x32_bf16(
                    af[mi], bf[ni], acc[mi][ni], 0, 0, 0);
        __syncthreads();
    }

    int colb = (int)n0 + wc * 64 + lm;
    int rowb = (int)m0 + wr * 64 + (lane >> 4) * 4;
    #pragma unroll
    for (int ni = 0; ni < 4; ni++) {
        int col = colb + ni * 16;
        float bv = bias[col];
        #pragma unroll
        for (int mi = 0; mi < 4; mi++) {
            #pragma unroll
            for (int j = 0; j < 4; j++) {
                float o = acc[mi][ni][j] + bv;
                if (ACT == 1) o = gelu_exact(o);
                long idx = (long)(rowb + mi * 16 + j) * N + col;
                if constexpr (sizeof(OT) == 2) C[idx] = __float2bfloat16(o);
                else                           C[idx] = o;
            }
        }
    }
}

// ---------------------------------------------------------------------------
// h = LayerNorm(t + pos_emb[s] + tok_emb); writes fp32 h + bf16 mirror.
// ---------------------------------------------------------------------------
__global__ __launch_bounds__(256) void pos_ln_kernel(
    const float* __restrict__ t, const float* __restrict__ pos_emb,
    const float* __restrict__ tok_emb, const float* __restrict__ ln_s,
    const float* __restrict__ ln_b, float* __restrict__ h,
    __hip_bfloat16* __restrict__ hbf)
{
    int tok = blockIdx.x;
    int s = tok & 1023;
    int tid = threadIdx.x;
    __shared__ float red[8];
    const float* trow = &t[(long)tok * 768];
    int d0 = tid, d1 = tid + 256, d2 = tid + 512;
    float a0 = trow[d0] + pos_emb[s * 768 + d0] + tok_emb[d0];
    float a1 = trow[d1] + pos_emb[s * 768 + d1] + tok_emb[d1];
    float a2 = trow[d2] + pos_emb[s * 768 + d2] + tok_emb[d2];
    float sum = a0 + a1 + a2;
    float sumsq = a0 * a0 + a1 * a1 + a2 * a2;
    #pragma unroll
    for (int off = 32; off; off >>= 1) {
        sum   += __shfl_down(sum, off, 64);
        sumsq += __shfl_down(sumsq, off, 64);
    }
    if ((tid & 63) == 0) { red[tid >> 6] = sum; red[4 + (tid >> 6)] = sumsq; }
    __syncthreads();
    sum   = red[0] + red[1] + red[2] + red[3];
    sumsq = red[4] + red[5] + red[6] + red[7];
    float mean = sum * (1.f / 768.f);
    float var  = sumsq * (1.f / 768.f) - mean * mean;
    float rs   = rsqrtf(var + 1e-12f);
    float* hrow = &h[(long)tok * 768];
    __hip_bfloat16* brow = &hbf[(long)tok * 768];
    float o0 = (a0 - mean) * rs * ln_s[d0] + ln_b[d0];
    float o1 = (a1 - mean) * rs * ln_s[d1] + ln_b[d1];
    float o2 = (a2 - mean) * rs * ln_s[d2] + ln_b[d2];
    hrow[d0] = o0; hrow[d1] = o1; hrow[d2] = o2;
    brow[d0] = __float2bfloat16(o0);
    brow[d1] = __float2bfloat16(o1);
    brow[d2] = __float2bfloat16(o2);
}

// ---------------------------------------------------------------------------
// MFMA band attention (unchanged from R4, incl. epilogue bugfix).
// ---------------------------------------------------------------------------
__global__ __launch_bounds__(256) void attn_kernel(
    const float* __restrict__ QKV, __hip_bfloat16* __restrict__ Ob)
{
    __shared__ __hip_bfloat16 KV[128 * 72];       // Ks[128][72]  /  Vt[64][136]
    __shared__ __hip_bfloat16 Pl[4][32 * 136];    // per-wave P[query][key]
    __shared__ float alpha_s[4][32];
    __shared__ float l_s[4][32];

    int blk = blockIdx.x;
    int ci = blk & 7, hh = (blk >> 3) % 12, b = blk / 96;
    int tid = threadIdx.x, w = tid >> 6, lane = tid & 63;
    int lm = lane & 15, lg = lane >> 4;
    __hip_bfloat16* Pw = &Pl[w][0];

    short8 qf[2][2];
    #pragma unroll
    for (int nt = 0; nt < 2; nt++) {
        int q = ci * 128 + w * 32 + nt * 16 + lm;
        const float* qp = &QKV[((long)(b * 1024 + q)) * 2304 + hh * 64];
        #pragma unroll
        for (int ks = 0; ks < 2; ks++) {
            float4 f0 = *(const float4*)(qp + ks * 32 + lg * 8);
            float4 f1 = *(const float4*)(qp + ks * 32 + lg * 8 + 4);
            short8 v;
            v[0] = bfs(f0.x); v[1] = bfs(f0.y); v[2] = bfs(f0.z); v[3] = bfs(f0.w);
            v[4] = bfs(f1.x); v[5] = bfs(f1.y); v[6] = bfs(f1.z); v[7] = bfs(f1.w);
            qf[nt][ks] = v;
        }
    }

    floatx4 accO[2][4] = {};
    float m_run[2] = {-1e30f, -1e30f};
    float l_run[2] = {0.f, 0.f};

    for (int tt = 0; tt < 3; tt++) {
        __syncthreads();
        #pragma unroll
        for (int i = 0; i < 8; i++) {
            int e = tid + i * 256;
            int jj = e >> 4, dd = (e & 15) * 4;
            int kpos = ci * 128 + tt * 128 + jj - 128;
            float4 kv = make_float4(0.f, 0.f, 0.f, 0.f);
            if (kpos >= 0 && kpos < 1024)
                kv = *(const float4*)&QKV[((long)(b * 1024 + kpos)) * 2304 + 768 + hh * 64 + dd];
            short4v kp;
            kp[0] = bfs(kv.x); kp[1] = bfs(kv.y); kp[2] = bfs(kv.z); kp[3] = bfs(kv.w);
            *(short4v*)&KV[jj * 72 + dd] = kp;
        }
        __syncthreads();

        floatx4 accS[8][2] = {};
        #pragma unroll
        for (int ks = 0; ks < 2; ks++)
            #pragma unroll
            for (int mt = 0; mt < 8; mt++) {
                short8 kf = *(const short8*)&KV[(mt * 16 + lm) * 72 + ks * 32 + lg * 8];
                accS[mt][0] = __builtin_amdgcn_mfma_f32_16x16x32_bf16(kf, qf[0][ks], accS[mt][0], 0, 0, 0);
                accS[mt][1] = __builtin_amdgcn_mfma_f32_16x16x32_bf16(kf, qf[1][ks], accS[mt][1], 0, 0, 0);
            }

        float tmax[2] = {-1e30f, -1e30f};
        #pragma unroll
        for (int nt = 0; nt < 2; nt++) {
            int r = w * 32 + nt * 16 + lm;
            #pragma unroll
            for (int mt = 0; mt < 8; mt++)
                #pragma unroll
                for (int j = 0; j < 4; j++) {
                    int jrel = tt * 128 + mt * 16 + lg * 4 + j;
                    int kpos = ci * 128 + jrel - 128;
                    bool valid = (jrel >= r) && (jrel <= r + 256) &&
                                 (kpos >= 0) && (kpos < 1024);
                    float s = valid ? accS[mt][nt][j] * 0.125f : -1e9f;
                    accS[mt][nt][j] = s;
                    tmax[nt] = fmaxf(tmax[nt], s);
                }
            tmax[nt] = fmaxf(tmax[nt], __shfl_xor(tmax[nt], 16));
            tmax[nt] = fmaxf(tmax[nt], __shfl_xor(tmax[nt], 32));
        }

        float al[2];
        #pragma unroll
        for (int nt = 0; nt < 2; nt++) {
            float mnew = fmaxf(m_run[nt], tmax[nt]);
            al[nt] = __expf(m_run[nt] - mnew);
            m_run[nt] = mnew;
            float ts = 0.f;
            #pragma unroll
            for (int mt = 0; mt < 8; mt++) {
                short4v pp;
                #pragma unroll
                for (int j = 0; j < 4; j++) {
                    float p = __expf(accS[mt][nt][j] - mnew);
                    ts += p;
                    pp[j] = bfs(p);
                }
                *(short4v*)&Pw[(nt * 16 + lm) * 136 + mt * 16 + lg * 4] = pp;
            }
            ts += __shfl_xor(ts, 16);
            ts += __shfl_xor(ts, 32);
            l_run[nt] = l_run[nt] * al[nt] + ts;
        }
        if (lg < 2) alpha_s[w][lg * 16 + lm] = al[lg];

        __syncthreads();
        #pragma unroll
        for (int i = 0; i < 8; i++) {
            int e = tid + i * 256;
            int jj = e >> 4, dd = (e & 15) * 4;
            int kpos = ci * 128 + tt * 128 + jj - 128;
            float4 vv = make_float4(0.f, 0.f, 0.f, 0.f);
            if (kpos >= 0 && kpos < 1024)
                vv = *(const float4*)&QKV[((long)(b * 1024 + kpos)) * 2304 + 1536 + hh * 64 + dd];
            KV[(dd + 0) * 136 + jj] = __float2bfloat16(vv.x);
            KV[(dd + 1) * 136 + jj] = __float2bfloat16(vv.y);
            KV[(dd + 2) * 136 + jj] = __float2bfloat16(vv.z);
            KV[(dd + 3) * 136 + jj] = __float2bfloat16(vv.w);
        }
        __syncthreads();

        #pragma unroll
        for (int mo = 0; mo < 2; mo++)
            #pragma unroll
            for (int j = 0; j < 4; j++) {
                float a = alpha_s[w][mo * 16 + lg * 4 + j];
                #pragma unroll
                for (int nd = 0; nd < 4; nd++)
                    accO[mo][nd][j] *= a;
            }

        #pragma unroll
        for (int kk = 0; kk < 4; kk++) {
            short8 pf[2], vf[4];
            #pragma unroll
            for (int mo = 0; mo < 2; mo++)
                pf[mo] = *(const short8*)&Pw[(mo * 16 + lm) * 136 + kk * 32 + lg * 8];
            #pragma unroll
            for (int nd = 0; nd < 4; nd++)
                vf[nd] = *(const short8*)&KV[(nd * 16 + lm) * 136 + kk * 32 + lg * 8];
            #pragma unroll
            for (int mo = 0; mo < 2; mo++)
                #pragma unroll
                for (int nd = 0; nd < 4; nd++)
                    accO[mo][nd] = __builtin_amdgcn_mfma_f32_16x16x32_bf16(
                        pf[mo], vf[nd], accO[mo][nd], 0, 0, 0);
        }
    }

    if (lg < 2) l_s[w][lg * 16 + lm] = l_run[lg];
    #pragma unroll
    for (int mo = 0; mo < 2; mo++)
        #pragma unroll
        for (int j = 0; j < 4; j++) {
            int qr = mo * 16 + lg * 4 + j;       // within-wave row, 0..31
            float rl = 1.f / l_s[w][qr];
            int q  = w * 32 + qr;
            long base = ((long)(b * 1024 + ci * 128 + q)) * 768 + hh * 64;
            #pragma unroll
            for (int nd = 0; nd < 4; nd++)
                Ob[base + nd * 16 + lm] = __float2bfloat16(accO[mo][nd][j] * rl);
        }
}

// ---------------------------------------------------------------------------
// h = LayerNorm(h + t) in place; also writes bf16 mirror.
// ---------------------------------------------------------------------------
__global__ __launch_bounds__(256) void add_ln_kernel(
    float* __restrict__ h, const float* __restrict__ t,
    const float* __restrict__ ln_s, const float* __restrict__ ln_b,
    __hip_bfloat16* __restrict__ hbf)
{
    int tok = blockIdx.x;
    int tid = threadIdx.x;
    __shared__ float red[8];
    float* hrow = &h[(long)tok * 768];
    const float* trow = &t[(long)tok * 768];
    int d0 = tid, d1 = tid + 256, d2 = tid + 512;
    float a0 = hrow[d0] + trow[d0];
    float a1 = hrow[d1] + trow[d1];
    float a2 = hrow[d2] + trow[d2];
    float sum = a0 + a1 + a2;
    float sumsq = a0 * a0 + a1 * a1 + a2 * a2;
    #pragma unroll
    for (int off = 32; off; off >>= 1) {
        sum   += __shfl_down(sum, off, 64);
        sumsq += __shfl_down(sumsq, off, 64);
    }
    if ((tid & 63) == 0) { red[tid >> 6] = sum; red[4 + (tid >> 6)] = sumsq; }
    __syncthreads();
    sum   = red[0] + red[1] + red[2] + red[3];
    sumsq = red[4] + red[5] + red[6] + red[7];
    float mean = sum * (1.f / 768.f);
    float var  = sumsq * (1.f / 768.f) - mean * mean;
    float rs   = rsqrtf(var + 1e-12f);
    __hip_bfloat16* brow = &hbf[(long)tok * 768];
    float o0 = (a0 - mean) * rs * ln_s[d0] + ln_b[d0];
    float o1 = (a1 - mean) * rs * ln_s[d1] + ln_b[d1];
    float o2 = (a2 - mean) * rs * ln_s[d2] + ln_b[d2];
    hrow[d0] = o0; hrow[d1] = o1; hrow[d2] = o2;
    brow[d0] = __float2bfloat16(o0);
    brow[d1] = __float2bfloat16(o1);
    brow[d2] = __float2bfloat16(o2);
}

// ---------------------------------------------------------------------------
// Head, stage 1: pooled[b,d] = tanh(h[b,0,:] @ pool_w[:,d] + pool_b[d]).
// grid = 24 blocks; block c covers dims c*32..c*32+31 for all 8 batches.
// ---------------------------------------------------------------------------
__global__ __launch_bounds__(256) void pool_kernel(
    const float* __restrict__ h, const float* __restrict__ pool_w,
    const float* __restrict__ pool_b, float* __restrict__ pooled)
{
    __shared__ float h0[8][768];
    int tid = threadIdx.x;
    for (int i = tid; i < 8 * 768; i += 256)
        h0[i / 768][i % 768] = h[((long)(i / 768) * 1024) * 768 + (i % 768)];
    __syncthreads();
    int d = blockIdx.x * 32 + (tid & 31);
    int b = tid >> 5;
    float acc = pool_b[d];
    const float* hr = h0[b];
    #pragma unroll 4
    for (int k = 0; k < 768; k++)
        acc += hr[k] * pool_w[k * 768 + d];
    pooled[b * 768 + d] = tanhf(acc);
}

// ---------------------------------------------------------------------------
// Head, stage 2: z = LN(pooled[b]); z1[b, d] = gelu(z @ w1[:,d] + b1[d]).
// grid = (2, 8): block (c, b) computes dims c*256..c*256+255.
// ---------------------------------------------------------------------------
__global__ __launch_bounds__(256) void head_mlp_kernel(
    const float* __restrict__ pooled, const float* __restrict__ hln_s,
    const float* __restrict__ hln_b, const float* __restrict__ w1,
    const float* __restrict__ b1, float* __restrict__ z1)
{
    int b = blockIdx.y, c = blockIdx.x, tid = threadIdx.x;
    __shared__ float z[768];
    __shared__ float red[8];
    const float* pr = &pooled[b * 768];
    float p0 = pr[tid], p1 = pr[tid + 256], p2 = pr[tid + 512];
    float sum = p0 + p1 + p2;
    float sumsq = p0 * p0 + p1 * p1 + p2 * p2;
    #pragma unroll
    for (int off = 32; off; off >>= 1) {
        sum   += __shfl_down(sum, off, 64);
        sumsq += __shfl_down(sumsq, off, 64);
    }
    if ((tid & 63) == 0) { red[tid >> 6] = sum; red[4 + (tid >> 6)] = sumsq; }
    __syncthreads();
    sum   = red[0] + red[1] + red[2] + red[3];
    sumsq = red[4] + red[5] + red[6] + red[7];
    float mean = sum * (1.f / 768.f);
    float var  = sumsq * (1.f / 768.f) - mean * mean;
    float rs   = rsqrtf(var + 1e-12f);
    z[tid]       = (p0 - mean) * rs * hln_s[tid]       + hln_b[tid];
    z[tid + 256] = (p1 - mean) * rs * hln_s[tid + 256] + hln_b[tid + 256];
    z[tid + 512] = (p2 - mean) * rs * hln_s[tid + 512] + hln_b[tid + 512];
    __syncthreads();
    int d = c * 256 + tid;
    float acc = b1[d];
    #pragma unroll 4
    for (int k = 0; k < 768; k++)
        acc += z[k] * w1[k * 512 + d];
    z1[b * 512 + d] = gelu_exact(acc);
}

// ---------------------------------------------------------------------------
// Head, stage 3: out[b,o] = z1[b] @ w2[:,o] + b2[o]. 1 block, 256 threads.
// 24 outputs x 8 lanes each.
// ---------------------------------------------------------------------------
__global__ __launch_bounds__(256) void head_final_kernel(
    const float* __restrict__ z1, const float* __restrict__ w2,
    const float* __restrict__ b2, float* __restrict__ out)
{
    int tid = threadIdx.x;
    int g = tid >> 3, t8 = tid & 7;
    if (g < 24) {
        int b = g / 3, o = g % 3;
        float acc = 0.f;
        for (int k = t8; k < 512; k += 8)
            acc += z1[b * 512 + k] * w2[k * 3 + o];
        acc += __shfl_down(acc, 4, 64);
        acc += __shfl_down(acc, 2, 64);
        acc += __shfl_down(acc, 1, 64);
        if (t8 == 0) out[b * 3 + o] = acc + b2[o];
    }
}

// ---------------------------------------------------------------------------
extern "C" void kernel_launch(void* const* d_in, const int* in_sizes, int n_in,
                              void* d_out, int out_size, void* d_ws, size_t ws_size,
                              hipStream_t stream) {
    const float* x       = (const float*)d_in[0];
    const float* proj_w  = (const float*)d_in[2];
    const float* proj_b  = (const float*)d_in[3];
    const float* pos_emb = (const float*)d_in[4];
    const float* tok_emb = (const float*)d_in[5];
    const float* eln_s   = (const float*)d_in[6];
    const float* eln_b   = (const float*)d_in[7];
    const float* wq      = (const float*)d_in[8];
    const float* bq      = (const float*)d_in[9];
    const float* wk      = (const float*)d_in[10];
    const float* bk      = (const float*)d_in[11];
    const float* wv      = (const float*)d_in[12];
    const float* bv      = (const float*)d_in[13];
    const float* wo      = (const float*)d_in[14];
    const float* bo      = (const float*)d_in[15];
    const float* ln1_s   = (const float*)d_in[16];
    const float* ln1_b   = (const float*)d_in[17];
    const float* wi      = (const float*)d_in[18];
    const float* bi      = (const float*)d_in[19];
    const float* wo2     = (const float*)d_in[20];
    const float* bo2     = (const float*)d_in[21];
    const float* ln2_s   = (const float*)d_in[22];
    const float* ln2_b   = (const float*)d_in[23];
    const float* pool_w  = (const float*)d_in[24];
    const float* pool_b  = (const float*)d_in[25];
    const float* hln_s   = (const float*)d_in[26];
    const float* hln_b   = (const float*)d_in[27];
    const float* hw1     = (const float*)d_in[28];
    const float* hb1     = (const float*)d_in[29];
    const float* hw2     = (const float*)d_in[30];
    const float* hb2     = (const float*)d_in[31];

    char* wp = (char*)d_ws;
    auto alloc = [&](size_t bytes) {
        char* p = wp; wp += (bytes + 255) & ~(size_t)255; return p;
    };
    float*          h      = (float*)alloc(8192ll * 768 * 4);
    float*          qkv    = (float*)alloc(8192ll * 2304 * 4);
    __hip_bfloat16* h_bf   = (__hip_bfloat16*)alloc(8192ll * 768 * 2);
    __hip_bfloat16* a_bf   = (__hip_bfloat16*)alloc(8192ll * 768 * 2);
    __hip_bfloat16* qkvw_t = (__hip_bfloat16*)alloc(3ll * 2304 * 768 * 2);
    __hip_bfloat16* wo_t   = (__hip_bfloat16*)alloc(3ll * 768 * 768 * 2);
    __hip_bfloat16* wi_t   = (__hip_bfloat16*)alloc(3ll * 3072 * 768 * 2);
    __hip_bfloat16* wo2_t  = (__hip_bfloat16*)alloc(3ll * 768 * 3072 * 2);
    float*          qkv_b  = (float*)alloc(3ll * 2304 * 4);
    __hip_bfloat16* xr_bf  = (__hip_bfloat16*)alloc(8192ll * 192 * 2);
    __hip_bfloat16* projw_t= (__hip_bfloat16*)alloc(768ll * 192 * 2);
    float*          pooled = (float*)alloc(8ll * 768 * 4);
    float*          z1     = (float*)alloc(8ll * 512 * 4);
    float*          t      = qkv;                                          // alias
    __hip_bfloat16* mlp_bf = (__hip_bfloat16*)((char*)qkv + 8192ll * 768 * 4);

    // ---- weight conversion (every call; graph-safe) ----
    transpose_bf16<<<dim3(24, 24, 3), 256, 0, stream>>>(wq, qkvw_t,               768, 768,  768ll * 768,  2304ll * 768);
    transpose_bf16<<<dim3(24, 24, 3), 256, 0, stream>>>(wk, qkvw_t + 768 * 768,   768, 768,  768ll * 768,  2304ll * 768);
    transpose_bf16<<<dim3(24, 24, 3), 256, 0, stream>>>(wv, qkvw_t + 1536 * 768,  768, 768,  768ll * 768,  2304ll * 768);
    transpose_bf16<<<dim3(24, 24, 3), 256, 0, stream>>>(wo, wo_t,                 768, 768,  768ll * 768,  768ll * 768);
    transpose_bf16<<<dim3(96, 24, 3), 256, 0, stream>>>(wi, wi_t,                 768, 3072, 768ll * 3072, 3072ll * 768);
    transpose_bf16<<<dim3(24, 96, 3), 256, 0, stream>>>(wo2, wo2_t,               3072, 768, 3072ll * 768, 768ll * 3072);
    transpose_bf16<<<dim3(24, 6, 1),  256, 0, stream>>>(proj_w, projw_t,          192, 768,  0, 0);
    pack_qkv_bias<<<3, 768, 0, stream>>>(bq, bk, bv, qkv_b);

    // ---- embed as MFMA GEMM ----
    gather_x<<<8192, 192, 0, stream>>>(x, xr_bf);
    mfma_gemm<0, float><<<dim3(6, 64), 256, 0, stream>>>(
        xr_bf, projw_t, proj_b, t, 8192, 768, 192);
    pos_ln_kernel<<<8192, 256, 0, stream>>>(t, pos_emb, tok_emb, eln_s, eln_b, h, h_bf);

    for (int l = 0; l < 3; l++) {
        mfma_gemm<0, float><<<dim3(18, 64), 256, 0, stream>>>(
            h_bf, qkvw_t + (long)l * 2304 * 768, qkv_b + l * 2304, qkv,
            8192, 2304, 768);
        attn_kernel<<<768, 256, 0, stream>>>(qkv, a_bf);
        mfma_gemm<0, float><<<dim3(6, 64), 256, 0, stream>>>(
            a_bf, wo_t + (long)l * 768 * 768, bo + l * 768, t,
            8192, 768, 768);
        add_ln_kernel<<<8192, 256, 0, stream>>>(h, t, ln1_s + l * 768, ln1_b + l * 768, h_bf);
        mfma_gemm<1, __hip_bfloat16><<<dim3(24, 64), 256, 0, stream>>>(
            h_bf, wi_t + (long)l * 3072 * 768, bi + l * 3072, mlp_bf,
            8192, 3072, 768);
        mfma_gemm<0, float><<<dim3(6, 64), 256, 0, stream>>>(
            mlp_bf, wo2_t + (long)l * 768 * 3072, bo2 + l * 768, t,
            8192, 768, 3072);
        add_ln_kernel<<<8192, 256, 0, stream>>>(h, t, ln2_s + l * 768, ln2_b + l * 768, h_bf);
    }

    // ---- head: pool -> LN+MLP -> final ----
    pool_kernel<<<24, 256, 0, stream>>>(h, pool_w, pool_b, pooled);
    head_mlp_kernel<<<dim3(2, 8), 256, 0, stream>>>(pooled, hln_s, hln_b,
                                                    hw1, hb1, z1);
    head_final_kernel<<<1, 256, 0, stream>>>(z1, hw2, hb2, (float*)d_out);
}

// Round 6
// 1224.893 us; speedup vs baseline: 6.1635x; 1.2067x over previous
//
#include <hip/hip_runtime.h>
#include <hip/hip_bf16.h>
#include <math.h>

// B=8, S=1024, D=768, H=12, DH=64, L=3, I=3072, W1S=128, nc=8, MLP=512, NCLS=3

typedef __attribute__((ext_vector_type(8))) short short8;   // 8 bf16 (4 VGPRs)
typedef __attribute__((ext_vector_type(4))) short short4v;  // 4 bf16 (8 B)
typedef __attribute__((ext_vector_type(4))) float floatx4;  // MFMA C/D

__device__ __forceinline__ float gelu_exact(float x) {
    return 0.5f * x * (1.f + erff(x * 0.70710678118654752440f));
}

__device__ __forceinline__ short bfs(float x) {
    __hip_bfloat16 h = __float2bfloat16(x);
    short s;
    __builtin_memcpy(&s, &h, 2);
    return s;
}

__device__ __forceinline__ float bf2f(short s) {
    unsigned u = ((unsigned)(unsigned short)s) << 16;
    float f;
    __builtin_memcpy(&f, &u, 4);
    return f;
}

#define GLOAD_LDS16(g, l) __builtin_amdgcn_global_load_lds( \
    (const __attribute__((address_space(1))) void*)(g),     \
    (__attribute__((address_space(3))) void*)(l), 16, 0, 0)

// ---------------------------------------------------------------------------
// Weight convert+transpose: W[K,N] fp32 -> Wt[N,K] bf16. blockIdx.z = layer.
// ---------------------------------------------------------------------------
__global__ __launch_bounds__(256) void transpose_bf16(
    const float* __restrict__ W, __hip_bfloat16* __restrict__ Wt,
    int K, int N, long inLS, long outLS)
{
    __shared__ float tile[32][33];
    int l = blockIdx.z;
    const float* Wl = W + (long)l * inLS;
    __hip_bfloat16* Wtl = Wt + (long)l * outLS;
    int lx = threadIdx.x & 31, ly = threadIdx.x >> 5;
    int kb = blockIdx.y * 32, nb = blockIdx.x * 32;
    #pragma unroll
    for (int r = 0; r < 32; r += 8)
        tile[ly + r][lx] = Wl[(long)(kb + ly + r) * N + nb + lx];
    __syncthreads();
    #pragma unroll
    for (int r = 0; r < 32; r += 8)
        Wtl[(long)(nb + ly + r) * K + kb + lx] = __float2bfloat16(tile[lx][ly + r]);
}

__global__ void pack_qkv_bias(const float* __restrict__ bq,
                              const float* __restrict__ bk,
                              const float* __restrict__ bv,
                              float* __restrict__ out)
{
    int l = blockIdx.x, tid = threadIdx.x;   // 768 threads
    out[l * 2304 + tid]        = bq[l * 768 + tid];
    out[l * 2304 + 768 + tid]  = bk[l * 768 + tid];
    out[l * 2304 + 1536 + tid] = bv[l * 768 + tid];
}

// ---------------------------------------------------------------------------
// Patchify gather: x (8,3,64,32,32) fp32 -> xr_bf [8192 tokens][192] bf16.
// ---------------------------------------------------------------------------
__global__ __launch_bounds__(192) void gather_x(
    const float* __restrict__ x, __hip_bfloat16* __restrict__ xr)
{
    int tok = blockIdx.x;           // 0..8191
    int b = tok >> 10, s = tok & 1023;
    int tci = s >> 6, sci = (s >> 3) & 7, scj = s & 7;
    int f = threadIdx.x;            // 0..191
    int ch  = f % 3;
    int crc = f / 3;
    int cr1 = crc >> 4, cr2 = (crc >> 2) & 3, cr3 = crc & 3;
    float v = x[(((b * 3 + ch) * 64) + cr1 * 16 + tci) * 1024 +
                (cr2 * 8 + sci) * 32 + cr3 * 8 + scj];
    xr[(long)tok * 192 + f] = __float2bfloat16(v);
}

// ---------------------------------------------------------------------------
// bf16 MFMA GEMM: C[M,N] = A[M,K](bf16) @ Bt[N,K](bf16)^T + bias.
// 128x128 tile, BK=32, 256 thr = 4 waves, each wave 64x64 via 4x4 of
// mfma_f32_16x16x32_bf16. Staging via global_load_lds width=16 (m97 recipe).
// ---------------------------------------------------------------------------
template<int ACT, typename OT>
__global__ __launch_bounds__(256) void mfma_gemm(
    const __hip_bfloat16* __restrict__ A, const __hip_bfloat16* __restrict__ Bt,
    const float* __restrict__ bias, OT* __restrict__ C, int M, int N, int K)
{
    __shared__ __hip_bfloat16 As[128 * 32];
    __shared__ __hip_bfloat16 Bs[128 * 32];
    int tid  = threadIdx.x;
    int wave = tid >> 6, lane = tid & 63;
    long m0 = (long)blockIdx.y * 128, n0 = (long)blockIdx.x * 128;
    int wr = wave >> 1, wc = wave & 1;
    floatx4 acc[4][4] = {};

    int srow = (wave * 128 + lane) >> 2;
    int sch  = lane & 3;
    const __hip_bfloat16* Ag = A  + (m0 + srow) * K + sch * 8;
    const __hip_bfloat16* Bg = Bt + (n0 + srow) * K + sch * 8;
    __hip_bfloat16* AsW = &As[wave * 128 * 8];
    __hip_bfloat16* BsW = &Bs[wave * 128 * 8];
    int lm = lane & 15, lk8 = (lane >> 4) * 8;

    for (int k0 = 0; k0 < K; k0 += 32) {
        GLOAD_LDS16(Ag + k0,          AsW);
        GLOAD_LDS16(Ag + 16 * K + k0, AsW + 64 * 8);
        GLOAD_LDS16(Bg + k0,          BsW);
        GLOAD_LDS16(Bg + 16 * K + k0, BsW + 64 * 8);
        __syncthreads();
        short8 af[4], bf[4];
        #pragma unroll
        for (int mi = 0; mi < 4; mi++)
            af[mi] = *(const short8*)&As[(wr * 64 + mi * 16 + lm) * 32 + lk8];
        #pragma unroll
        for (int ni = 0; ni < 4; ni++)
            bf[ni] = *(const short8*)&Bs[(wc * 64 + ni * 16 + lm) * 32 + lk8];
        #pragma unroll
        for (int mi = 0; mi < 4; mi++)
            #pragma unroll
            for (int ni = 0; ni < 4; ni++)
                acc[mi][ni] = __builtin_amdgcn_mfma_f32_16x16x32_bf16(
                    af[mi], bf[ni], acc[mi][ni], 0, 0, 0);
        __syncthreads();
    }

    int colb = (int)n0 + wc * 64 + lm;
    int rowb = (int)m0 + wr * 64 + (lane >> 4) * 4;
    #pragma unroll
    for (int ni = 0; ni < 4; ni++) {
        int col = colb + ni * 16;
        float bv = bias[col];
        #pragma unroll
        for (int mi = 0; mi < 4; mi++) {
            #pragma unroll
            for (int j = 0; j < 4; j++) {
                float o = acc[mi][ni][j] + bv;
                if (ACT == 1) o = gelu_exact(o);
                long idx = (long)(rowb + mi * 16 + j) * N + col;
                if constexpr (sizeof(OT) == 2) C[idx] = __float2bfloat16(o);
                else                           C[idx] = o;
            }
        }
    }
}

// ---------------------------------------------------------------------------
// h = LayerNorm(t + pos_emb[s] + tok_emb); writes fp32 h + bf16 mirror.
// ---------------------------------------------------------------------------
__global__ __launch_bounds__(256) void pos_ln_kernel(
    const float* __restrict__ t, const float* __restrict__ pos_emb,
    const float* __restrict__ tok_emb, const float* __restrict__ ln_s,
    const float* __restrict__ ln_b, float* __restrict__ h,
    __hip_bfloat16* __restrict__ hbf)
{
    int tok = blockIdx.x;
    int s = tok & 1023;
    int tid = threadIdx.x;
    __shared__ float red[8];
    const float* trow = &t[(long)tok * 768];
    int d0 = tid, d1 = tid + 256, d2 = tid + 512;
    float a0 = trow[d0] + pos_emb[s * 768 + d0] + tok_emb[d0];
    float a1 = trow[d1] + pos_emb[s * 768 + d1] + tok_emb[d1];
    float a2 = trow[d2] + pos_emb[s * 768 + d2] + tok_emb[d2];
    float sum = a0 + a1 + a2;
    float sumsq = a0 * a0 + a1 * a1 + a2 * a2;
    #pragma unroll
    for (int off = 32; off; off >>= 1) {
        sum   += __shfl_down(sum, off, 64);
        sumsq += __shfl_down(sumsq, off, 64);
    }
    if ((tid & 63) == 0) { red[tid >> 6] = sum; red[4 + (tid >> 6)] = sumsq; }
    __syncthreads();
    sum   = red[0] + red[1] + red[2] + red[3];
    sumsq = red[4] + red[5] + red[6] + red[7];
    float mean = sum * (1.f / 768.f);
    float var  = sumsq * (1.f / 768.f) - mean * mean;
    float rs   = rsqrtf(var + 1e-12f);
    float* hrow = &h[(long)tok * 768];
    __hip_bfloat16* brow = &hbf[(long)tok * 768];
    float o0 = (a0 - mean) * rs * ln_s[d0] + ln_b[d0];
    float o1 = (a1 - mean) * rs * ln_s[d1] + ln_b[d1];
    float o2 = (a2 - mean) * rs * ln_s[d2] + ln_b[d2];
    hrow[d0] = o0; hrow[d1] = o1; hrow[d2] = o2;
    brow[d0] = __float2bfloat16(o0);
    brow[d1] = __float2bfloat16(o1);
    brow[d2] = __float2bfloat16(o2);
}

// ---------------------------------------------------------------------------
// MFMA band attention; QKV is bf16 [8192, 2304] (q|k|v packed per token).
// One block per (b, head, chunk). 256 thr = 4 waves; wave w owns 32 queries.
// ---------------------------------------------------------------------------
__global__ __launch_bounds__(256) void attn_kernel(
    const __hip_bfloat16* __restrict__ QKV, __hip_bfloat16* __restrict__ Ob)
{
    __shared__ __hip_bfloat16 KV[128 * 72];       // Ks[128][72]  /  Vt[64][136]
    __shared__ __hip_bfloat16 Pl[4][32 * 136];    // per-wave P[query][key]
    __shared__ float alpha_s[4][32];
    __shared__ float l_s[4][32];

    int blk = blockIdx.x;
    int ci = blk & 7, hh = (blk >> 3) % 12, b = blk / 96;
    int tid = threadIdx.x, w = tid >> 6, lane = tid & 63;
    int lm = lane & 15, lg = lane >> 4;
    __hip_bfloat16* Pw = &Pl[w][0];

    // Q fragments: direct bf16 loads (16-B aligned)
    short8 qf[2][2];
    #pragma unroll
    for (int nt = 0; nt < 2; nt++) {
        int q = ci * 128 + w * 32 + nt * 16 + lm;
        const __hip_bfloat16* qp = &QKV[((long)(b * 1024 + q)) * 2304 + hh * 64];
        #pragma unroll
        for (int ks = 0; ks < 2; ks++)
            qf[nt][ks] = *(const short8*)(qp + ks * 32 + lg * 8);
    }

    floatx4 accO[2][4] = {};
    float m_run[2] = {-1e30f, -1e30f};
    float l_run[2] = {0.f, 0.f};

    for (int tt = 0; tt < 3; tt++) {
        __syncthreads();
        // ---- stage K tile: Ks[key][72], short8 copies (16-B aligned) ----
        #pragma unroll
        for (int i = 0; i < 4; i++) {
            int e = tid + i * 256;          // 0..1023
            int jj = e >> 3, dd = (e & 7) * 8;
            int kpos = ci * 128 + tt * 128 + jj - 128;
            short8 kv = {};
            if (kpos >= 0 && kpos < 1024)
                kv = *(const short8*)&QKV[((long)(b * 1024 + kpos)) * 2304 + 768 + hh * 64 + dd];
            *(short8*)&KV[jj * 72 + dd] = kv;
        }
        __syncthreads();

        // ---- S^T = K @ Q^T : m=key(128, 8 tiles), n=query(32, 2), k=dh(64) ----
        floatx4 accS[8][2] = {};
        #pragma unroll
        for (int ks = 0; ks < 2; ks++)
            #pragma unroll
            for (int mt = 0; mt < 8; mt++) {
                short8 kf = *(const short8*)&KV[(mt * 16 + lm) * 72 + ks * 32 + lg * 8];
                accS[mt][0] = __builtin_amdgcn_mfma_f32_16x16x32_bf16(kf, qf[0][ks], accS[mt][0], 0, 0, 0);
                accS[mt][1] = __builtin_amdgcn_mfma_f32_16x16x32_bf16(kf, qf[1][ks], accS[mt][1], 0, 0, 0);
            }

        float tmax[2] = {-1e30f, -1e30f};
        #pragma unroll
        for (int nt = 0; nt < 2; nt++) {
            int r = w * 32 + nt * 16 + lm;
            #pragma unroll
            for (int mt = 0; mt < 8; mt++)
                #pragma unroll
                for (int j = 0; j < 4; j++) {
                    int jrel = tt * 128 + mt * 16 + lg * 4 + j;
                    int kpos = ci * 128 + jrel - 128;
                    bool valid = (jrel >= r) && (jrel <= r + 256) &&
                                 (kpos >= 0) && (kpos < 1024);
                    float s = valid ? accS[mt][nt][j] * 0.125f : -1e9f;
                    accS[mt][nt][j] = s;
                    tmax[nt] = fmaxf(tmax[nt], s);
                }
            tmax[nt] = fmaxf(tmax[nt], __shfl_xor(tmax[nt], 16));
            tmax[nt] = fmaxf(tmax[nt], __shfl_xor(tmax[nt], 32));
        }

        float al[2];
        #pragma unroll
        for (int nt = 0; nt < 2; nt++) {
            float mnew = fmaxf(m_run[nt], tmax[nt]);
            al[nt] = __expf(m_run[nt] - mnew);
            m_run[nt] = mnew;
            float ts = 0.f;
            #pragma unroll
            for (int mt = 0; mt < 8; mt++) {
                short4v pp;
                #pragma unroll
                for (int j = 0; j < 4; j++) {
                    float p = __expf(accS[mt][nt][j] - mnew);
                    ts += p;
                    pp[j] = bfs(p);
                }
                *(short4v*)&Pw[(nt * 16 + lm) * 136 + mt * 16 + lg * 4] = pp;
            }
            ts += __shfl_xor(ts, 16);
            ts += __shfl_xor(ts, 32);
            l_run[nt] = l_run[nt] * al[nt] + ts;
        }
        if (lg < 2) alpha_s[w][lg * 16 + lm] = al[lg];

        __syncthreads();
        // ---- stage V tile transposed: Vt[dh][136] (overwrites Ks) ----
        #pragma unroll
        for (int i = 0; i < 4; i++) {
            int e = tid + i * 256;          // 0..1023
            int jj = e >> 3, dd = (e & 7) * 8;
            int kpos = ci * 128 + tt * 128 + jj - 128;
            short8 vv = {};
            if (kpos >= 0 && kpos < 1024)
                vv = *(const short8*)&QKV[((long)(b * 1024 + kpos)) * 2304 + 1536 + hh * 64 + dd];
            short* kvs = (short*)KV;
            #pragma unroll
            for (int m2 = 0; m2 < 8; m2++)
                kvs[(dd + m2) * 136 + jj] = vv[m2];
        }
        __syncthreads();

        #pragma unroll
        for (int mo = 0; mo < 2; mo++)
            #pragma unroll
            for (int j = 0; j < 4; j++) {
                float a = alpha_s[w][mo * 16 + lg * 4 + j];
                #pragma unroll
                for (int nd = 0; nd < 4; nd++)
                    accO[mo][nd][j] *= a;
            }

        #pragma unroll
        for (int kk = 0; kk < 4; kk++) {
            short8 pf[2], vf[4];
            #pragma unroll
            for (int mo = 0; mo < 2; mo++)
                pf[mo] = *(const short8*)&Pw[(mo * 16 + lm) * 136 + kk * 32 + lg * 8];
            #pragma unroll
            for (int nd = 0; nd < 4; nd++)
                vf[nd] = *(const short8*)&KV[(nd * 16 + lm) * 136 + kk * 32 + lg * 8];
            #pragma unroll
            for (int mo = 0; mo < 2; mo++)
                #pragma unroll
                for (int nd = 0; nd < 4; nd++)
                    accO[mo][nd] = __builtin_amdgcn_mfma_f32_16x16x32_bf16(
                        pf[mo], vf[nd], accO[mo][nd], 0, 0, 0);
        }
    }

    if (lg < 2) l_s[w][lg * 16 + lm] = l_run[lg];
    #pragma unroll
    for (int mo = 0; mo < 2; mo++)
        #pragma unroll
        for (int j = 0; j < 4; j++) {
            int qr = mo * 16 + lg * 4 + j;       // within-wave row, 0..31
            float rl = 1.f / l_s[w][qr];
            int q  = w * 32 + qr;
            long base = ((long)(b * 1024 + ci * 128 + q)) * 768 + hh * 64;
            #pragma unroll
            for (int nd = 0; nd < 4; nd++)
                Ob[base + nd * 16 + lm] = __float2bfloat16(accO[mo][nd][j] * rl);
        }
}

// ---------------------------------------------------------------------------
// h = LayerNorm(h + t) in place; also writes bf16 mirror.
// ---------------------------------------------------------------------------
__global__ __launch_bounds__(256) void add_ln_kernel(
    float* __restrict__ h, const float* __restrict__ t,
    const float* __restrict__ ln_s, const float* __restrict__ ln_b,
    __hip_bfloat16* __restrict__ hbf)
{
    int tok = blockIdx.x;
    int tid = threadIdx.x;
    __shared__ float red[8];
    float* hrow = &h[(long)tok * 768];
    const float* trow = &t[(long)tok * 768];
    int d0 = tid, d1 = tid + 256, d2 = tid + 512;
    float a0 = hrow[d0] + trow[d0];
    float a1 = hrow[d1] + trow[d1];
    float a2 = hrow[d2] + trow[d2];
    float sum = a0 + a1 + a2;
    float sumsq = a0 * a0 + a1 * a1 + a2 * a2;
    #pragma unroll
    for (int off = 32; off; off >>= 1) {
        sum   += __shfl_down(sum, off, 64);
        sumsq += __shfl_down(sumsq, off, 64);
    }
    if ((tid & 63) == 0) { red[tid >> 6] = sum; red[4 + (tid >> 6)] = sumsq; }
    __syncthreads();
    sum   = red[0] + red[1] + red[2] + red[3];
    sumsq = red[4] + red[5] + red[6] + red[7];
    float mean = sum * (1.f / 768.f);
    float var  = sumsq * (1.f / 768.f) - mean * mean;
    float rs   = rsqrtf(var + 1e-12f);
    __hip_bfloat16* brow = &hbf[(long)tok * 768];
    float o0 = (a0 - mean) * rs * ln_s[d0] + ln_b[d0];
    float o1 = (a1 - mean) * rs * ln_s[d1] + ln_b[d1];
    float o2 = (a2 - mean) * rs * ln_s[d2] + ln_b[d2];
    hrow[d0] = o0; hrow[d1] = o1; hrow[d2] = o2;
    brow[d0] = __float2bfloat16(o0);
    brow[d1] = __float2bfloat16(o1);
    brow[d2] = __float2bfloat16(o2);
}

// ---------------------------------------------------------------------------
// Head stage 1: pooled[b,d] = tanh(h_bf[b,0,:] . pool_wt[d,:] + pool_b[d]).
// Split-K over 8 lanes per output. 6144 outputs -> 192 blocks x 256 thr.
// ---------------------------------------------------------------------------
__global__ __launch_bounds__(256) void pool_split(
    const __hip_bfloat16* __restrict__ hbf, const __hip_bfloat16* __restrict__ pool_wt,
    const float* __restrict__ pool_b, float* __restrict__ pooled)
{
    int g = blockIdx.x * 256 + threadIdx.x;
    int out = g >> 3, t8 = g & 7;
    int b = out / 768, d = out - b * 768;
    const __hip_bfloat16* hr = hbf + (long)b * 1024 * 768;   // token 0 of batch b
    const __hip_bfloat16* wr = pool_wt + (long)d * 768;
    float acc = 0.f;
    #pragma unroll
    for (int kk = 0; kk < 96; kk += 8) {
        int k = t8 * 96 + kk;
        short8 hv = *(const short8*)&hr[k];
        short8 wv = *(const short8*)&wr[k];
        #pragma unroll
        for (int j = 0; j < 8; j++) acc += bf2f(hv[j]) * bf2f(wv[j]);
    }
    acc += __shfl_down(acc, 4, 64);
    acc += __shfl_down(acc, 2, 64);
    acc += __shfl_down(acc, 1, 64);
    if (t8 == 0) pooled[out] = tanhf(acc + pool_b[d]);
}

// ---------------------------------------------------------------------------
// Head stage 2: z_bf[b] = bf16(LN(pooled[b])). 8 blocks x 256 thr.
// ---------------------------------------------------------------------------
__global__ __launch_bounds__(256) void ln_z_kernel(
    const float* __restrict__ pooled, const float* __restrict__ hln_s,
    const float* __restrict__ hln_b, __hip_bfloat16* __restrict__ zbf)
{
    int b = blockIdx.x, tid = threadIdx.x;
    __shared__ float red[8];
    const float* pr = &pooled[b * 768];
    float p0 = pr[tid], p1 = pr[tid + 256], p2 = pr[tid + 512];
    float sum = p0 + p1 + p2;
    float sumsq = p0 * p0 + p1 * p1 + p2 * p2;
    #pragma unroll
    for (int off = 32; off; off >>= 1) {
        sum   += __shfl_down(sum, off, 64);
        sumsq += __shfl_down(sumsq, off, 64);
    }
    if ((tid & 63) == 0) { red[tid >> 6] = sum; red[4 + (tid >> 6)] = sumsq; }
    __syncthreads();
    sum   = red[0] + red[1] + red[2] + red[3];
    sumsq = red[4] + red[5] + red[6] + red[7];
    float mean = sum * (1.f / 768.f);
    float var  = sumsq * (1.f / 768.f) - mean * mean;
    float rs   = rsqrtf(var + 1e-12f);
    zbf[b * 768 + tid]       = __float2bfloat16((p0 - mean) * rs * hln_s[tid]       + hln_b[tid]);
    zbf[b * 768 + tid + 256] = __float2bfloat16((p1 - mean) * rs * hln_s[tid + 256] + hln_b[tid + 256]);
    zbf[b * 768 + tid + 512] = __float2bfloat16((p2 - mean) * rs * hln_s[tid + 512] + hln_b[tid + 512]);
}

// ---------------------------------------------------------------------------
// Head stage 3: z1[b,d] = gelu(z_bf[b] . w1t[d,:] + b1[d]).
// 4096 outputs x 8 lanes -> 128 blocks x 256 thr.
// ---------------------------------------------------------------------------
__global__ __launch_bounds__(256) void mlp_split(
    const __hip_bfloat16* __restrict__ zbf, const __hip_bfloat16* __restrict__ w1t,
    const float* __restrict__ b1, float* __restrict__ z1)
{
    int g = blockIdx.x * 256 + threadIdx.x;
    int out = g >> 3, t8 = g & 7;
    int b = out >> 9, d = out & 511;
    const __hip_bfloat16* zr = zbf + b * 768;
    const __hip_bfloat16* wr = w1t + (long)d * 768;
    float acc = 0.f;
    #pragma unroll
    for (int kk = 0; kk < 96; kk += 8) {
        int k = t8 * 96 + kk;
        short8 zv = *(const short8*)&zr[k];
        short8 wv = *(const short8*)&wr[k];
        #pragma unroll
        for (int j = 0; j < 8; j++) acc += bf2f(zv[j]) * bf2f(wv[j]);
    }
    acc += __shfl_down(acc, 4, 64);
    acc += __shfl_down(acc, 2, 64);
    acc += __shfl_down(acc, 1, 64);
    if (t8 == 0) z1[out] = gelu_exact(acc + b1[d]);
}

// ---------------------------------------------------------------------------
// Head stage 4: out[b,o] = z1[b] @ w2[:,o] + b2[o]. 1 block, 256 threads.
// ---------------------------------------------------------------------------
__global__ __launch_bounds__(256) void head_final_kernel(
    const float* __restrict__ z1, const float* __restrict__ w2,
    const float* __restrict__ b2, float* __restrict__ out)
{
    int tid = threadIdx.x;
    int g = tid >> 3, t8 = tid & 7;
    if (g < 24) {
        int b = g / 3, o = g % 3;
        float acc = 0.f;
        for (int k = t8; k < 512; k += 8)
            acc += z1[b * 512 + k] * w2[k * 3 + o];
        acc += __shfl_down(acc, 4, 64);
        acc += __shfl_down(acc, 2, 64);
        acc += __shfl_down(acc, 1, 64);
        if (t8 == 0) out[b * 3 + o] = acc + b2[o];
    }
}

// ---------------------------------------------------------------------------
extern "C" void kernel_launch(void* const* d_in, const int* in_sizes, int n_in,
                              void* d_out, int out_size, void* d_ws, size_t ws_size,
                              hipStream_t stream) {
    const float* x       = (const float*)d_in[0];
    const float* proj_w  = (const float*)d_in[2];
    const float* proj_b  = (const float*)d_in[3];
    const float* pos_emb = (const float*)d_in[4];
    const float* tok_emb = (const float*)d_in[5];
    const float* eln_s   = (const float*)d_in[6];
    const float* eln_b   = (const float*)d_in[7];
    const float* wq      = (const float*)d_in[8];
    const float* bq      = (const float*)d_in[9];
    const float* wk      = (const float*)d_in[10];
    const float* bk      = (const float*)d_in[11];
    const float* wv      = (const float*)d_in[12];
    const float* bv      = (const float*)d_in[13];
    const float* wo      = (const float*)d_in[14];
    const float* bo      = (const float*)d_in[15];
    const float* ln1_s   = (const float*)d_in[16];
    const float* ln1_b   = (const float*)d_in[17];
    const float* wi      = (const float*)d_in[18];
    const float* bi      = (const float*)d_in[19];
    const float* wo2     = (const float*)d_in[20];
    const float* bo2     = (const float*)d_in[21];
    const float* ln2_s   = (const float*)d_in[22];
    const float* ln2_b   = (const float*)d_in[23];
    const float* pool_w  = (const float*)d_in[24];
    const float* pool_b  = (const float*)d_in[25];
    const float* hln_s   = (const float*)d_in[26];
    const float* hln_b   = (const float*)d_in[27];
    const float* hw1     = (const float*)d_in[28];
    const float* hb1     = (const float*)d_in[29];
    const float* hw2     = (const float*)d_in[30];
    const float* hb2     = (const float*)d_in[31];

    char* wp = (char*)d_ws;
    auto alloc = [&](size_t bytes) {
        char* p = wp; wp += (bytes + 255) & ~(size_t)255; return p;
    };
    float*          h       = (float*)alloc(8192ll * 768 * 4);
    __hip_bfloat16* qkv_bf  = (__hip_bfloat16*)alloc(8192ll * 2304 * 2);
    float*          t       = (float*)alloc(8192ll * 768 * 4);
    __hip_bfloat16* mlp_bf  = (__hip_bfloat16*)alloc(8192ll * 3072 * 2);
    __hip_bfloat16* h_bf    = (__hip_bfloat16*)alloc(8192ll * 768 * 2);
    __hip_bfloat16* a_bf    = (__hip_bfloat16*)alloc(8192ll * 768 * 2);
    __hip_bfloat16* qkvw_t  = (__hip_bfloat16*)alloc(3ll * 2304 * 768 * 2);
    __hip_bfloat16* wo_t    = (__hip_bfloat16*)alloc(3ll * 768 * 768 * 2);
    __hip_bfloat16* wi_t    = (__hip_bfloat16*)alloc(3ll * 3072 * 768 * 2);
    __hip_bfloat16* wo2_t   = (__hip_bfloat16*)alloc(3ll * 768 * 3072 * 2);
    float*          qkv_b   = (float*)alloc(3ll * 2304 * 4);
    __hip_bfloat16* xr_bf   = (__hip_bfloat16*)alloc(8192ll * 192 * 2);
    __hip_bfloat16* projw_t = (__hip_bfloat16*)alloc(768ll * 192 * 2);
    __hip_bfloat16* poolw_t = (__hip_bfloat16*)alloc(768ll * 768 * 2);
    __hip_bfloat16* w1_t    = (__hip_bfloat16*)alloc(512ll * 768 * 2);
    float*          pooled  = (float*)alloc(8ll * 768 * 4);
    __hip_bfloat16* z_bf    = (__hip_bfloat16*)alloc(8ll * 768 * 2);
    float*          z1      = (float*)alloc(8ll * 512 * 4);

    // ---- weight conversion (every call; graph-safe) ----
    transpose_bf16<<<dim3(24, 24, 3), 256, 0, stream>>>(wq, qkvw_t,               768, 768,  768ll * 768,  2304ll * 768);
    transpose_bf16<<<dim3(24, 24, 3), 256, 0, stream>>>(wk, qkvw_t + 768 * 768,   768, 768,  768ll * 768,  2304ll * 768);
    transpose_bf16<<<dim3(24, 24, 3), 256, 0, stream>>>(wv, qkvw_t + 1536 * 768,  768, 768,  768ll * 768,  2304ll * 768);
    transpose_bf16<<<dim3(24, 24, 3), 256, 0, stream>>>(wo, wo_t,                 768, 768,  768ll * 768,  768ll * 768);
    transpose_bf16<<<dim3(96, 24, 3), 256, 0, stream>>>(wi, wi_t,                 768, 3072, 768ll * 3072, 3072ll * 768);
    transpose_bf16<<<dim3(24, 96, 3), 256, 0, stream>>>(wo2, wo2_t,               3072, 768, 3072ll * 768, 768ll * 3072);
    transpose_bf16<<<dim3(24, 6, 1),  256, 0, stream>>>(proj_w, projw_t,          192, 768,  0, 0);
    transpose_bf16<<<dim3(24, 24, 1), 256, 0, stream>>>(pool_w, poolw_t,          768, 768,  0, 0);
    transpose_bf16<<<dim3(16, 24, 1), 256, 0, stream>>>(hw1, w1_t,                768, 512,  0, 0);
    pack_qkv_bias<<<3, 768, 0, stream>>>(bq, bk, bv, qkv_b);

    // ---- embed as MFMA GEMM ----
    gather_x<<<8192, 192, 0, stream>>>(x, xr_bf);
    mfma_gemm<0, float><<<dim3(6, 64), 256, 0, stream>>>(
        xr_bf, projw_t, proj_b, t, 8192, 768, 192);
    pos_ln_kernel<<<8192, 256, 0, stream>>>(t, pos_emb, tok_emb, eln_s, eln_b, h, h_bf);

    for (int l = 0; l < 3; l++) {
        mfma_gemm<0, __hip_bfloat16><<<dim3(18, 64), 256, 0, stream>>>(
            h_bf, qkvw_t + (long)l * 2304 * 768, qkv_b + l * 2304, qkv_bf,
            8192, 2304, 768);
        attn_kernel<<<768, 256, 0, stream>>>(qkv_bf, a_bf);
        mfma_gemm<0, float><<<dim3(6, 64), 256, 0, stream>>>(
            a_bf, wo_t + (long)l * 768 * 768, bo + l * 768, t,
            8192, 768, 768);
        add_ln_kernel<<<8192, 256, 0, stream>>>(h, t, ln1_s + l * 768, ln1_b + l * 768, h_bf);
        mfma_gemm<1, __hip_bfloat16><<<dim3(24, 64), 256, 0, stream>>>(
            h_bf, wi_t + (long)l * 3072 * 768, bi + l * 3072, mlp_bf,
            8192, 3072, 768);
        mfma_gemm<0, float><<<dim3(6, 64), 256, 0, stream>>>(
            mlp_bf, wo2_t + (long)l * 768 * 3072, bo2 + l * 768, t,
            8192, 768, 3072);
        add_ln_kernel<<<8192, 256, 0, stream>>>(h, t, ln2_s + l * 768, ln2_b + l * 768, h_bf);
    }

    // ---- head: pool -> LN -> MLP -> final ----
    pool_split<<<192, 256, 0, stream>>>(h_bf, poolw_t, pool_b, pooled);
    ln_z_kernel<<<8, 256, 0, stream>>>(pooled, hln_s, hln_b, z_bf);
    mlp_split<<<128, 256, 0, stream>>>(z_bf, w1_t, hb1, z1);
    head_final_kernel<<<1, 256, 0, stream>>>(z1, hw2, hb2, (float*)d_out);
}

// Round 7
// 1195.110 us; speedup vs baseline: 6.3171x; 1.0249x over previous
//
#include <hip/hip_runtime.h>
#include <hip/hip_bf16.h>
#include <math.h>

// B=8, S=1024, D=768, H=12, DH=64, L=3, I=3072, W1S=128, nc=8, MLP=512, NCLS=3

typedef __attribute__((ext_vector_type(8))) short short8;   // 8 bf16 (4 VGPRs)
typedef __attribute__((ext_vector_type(4))) short short4v;  // 4 bf16 (8 B)
typedef __attribute__((ext_vector_type(4))) float floatx4;  // MFMA C/D

__device__ __forceinline__ float gelu_exact(float x) {
    return 0.5f * x * (1.f + erff(x * 0.70710678118654752440f));
}

__device__ __forceinline__ short bfs(float x) {
    __hip_bfloat16 h = __float2bfloat16(x);
    short s;
    __builtin_memcpy(&s, &h, 2);
    return s;
}

__device__ __forceinline__ float bf2f(short s) {
    unsigned u = ((unsigned)(unsigned short)s) << 16;
    float f;
    __builtin_memcpy(&f, &u, 4);
    return f;
}

#define GLOAD_LDS16(g, l) __builtin_amdgcn_global_load_lds( \
    (const __attribute__((address_space(1))) void*)(g),     \
    (__attribute__((address_space(3))) void*)(l), 16, 0, 0)

// ---------------------------------------------------------------------------
// Weight convert+transpose: W[K,N] fp32 -> Wt[N,K] bf16. blockIdx.z = layer.
// ---------------------------------------------------------------------------
__global__ __launch_bounds__(256) void transpose_bf16(
    const float* __restrict__ W, __hip_bfloat16* __restrict__ Wt,
    int K, int N, long inLS, long outLS)
{
    __shared__ float tile[32][33];
    int l = blockIdx.z;
    const float* Wl = W + (long)l * inLS;
    __hip_bfloat16* Wtl = Wt + (long)l * outLS;
    int lx = threadIdx.x & 31, ly = threadIdx.x >> 5;
    int kb = blockIdx.y * 32, nb = blockIdx.x * 32;
    #pragma unroll
    for (int r = 0; r < 32; r += 8)
        tile[ly + r][lx] = Wl[(long)(kb + ly + r) * N + nb + lx];
    __syncthreads();
    #pragma unroll
    for (int r = 0; r < 32; r += 8)
        Wtl[(long)(nb + ly + r) * K + kb + lx] = __float2bfloat16(tile[lx][ly + r]);
}

__global__ void pack_qkv_bias(const float* __restrict__ bq,
                              const float* __restrict__ bk,
                              const float* __restrict__ bv,
                              float* __restrict__ out)
{
    int l = blockIdx.x, tid = threadIdx.x;   // 768 threads
    out[l * 2304 + tid]        = bq[l * 768 + tid];
    out[l * 2304 + 768 + tid]  = bk[l * 768 + tid];
    out[l * 2304 + 1536 + tid] = bv[l * 768 + tid];
}

// ---------------------------------------------------------------------------
// Patchify gather: x (8,3,64,32,32) fp32 -> xr_bf [8192 tokens][192] bf16.
// ---------------------------------------------------------------------------
__global__ __launch_bounds__(192) void gather_x(
    const float* __restrict__ x, __hip_bfloat16* __restrict__ xr)
{
    int tok = blockIdx.x;           // 0..8191
    int b = tok >> 10, s = tok & 1023;
    int tci = s >> 6, sci = (s >> 3) & 7, scj = s & 7;
    int f = threadIdx.x;            // 0..191
    int ch  = f % 3;
    int crc = f / 3;
    int cr1 = crc >> 4, cr2 = (crc >> 2) & 3, cr3 = crc & 3;
    float v = x[(((b * 3 + ch) * 64) + cr1 * 16 + tci) * 1024 +
                (cr2 * 8 + sci) * 32 + cr3 * 8 + scj];
    xr[(long)tok * 192 + f] = __float2bfloat16(v);
}

// ---------------------------------------------------------------------------
// bf16 MFMA GEMM: C[M,N](bf16) = A[M,K](bf16) @ Bt[N,K](bf16)^T + bias.
// 128x128 tile, BK=32, 4 waves. M must be 8192 (64 row-tiles): 1-D grid,
// by = L & 63 so same-A blocks share an XCD (L2 reuse); bx = L >> 6.
// LDS K-chunk XOR swizzle kills the 8-way bank conflict (R6: 4.7M cycles).
// Epilogue: LDS transpose -> coalesced 16-B/lane bf16 stores (R6 wrote 32-B
// segments -> 2.2x HBM write amplification).
// ---------------------------------------------------------------------------
template<int ACT>
__global__ __launch_bounds__(256) void mfma_gemm(
    const __hip_bfloat16* __restrict__ A, const __hip_bfloat16* __restrict__ Bt,
    const float* __restrict__ bias, __hip_bfloat16* __restrict__ C,
    int M, int N, int K)
{
    __shared__ short lds_raw[8704];            // As(4096) + Bs(4096) / Ebuf(8704)
    __hip_bfloat16* As = (__hip_bfloat16*)lds_raw;
    __hip_bfloat16* Bs = As + 4096;
    int tid  = threadIdx.x;
    int wave = tid >> 6, lane = tid & 63;
    int L = blockIdx.x;
    long m0 = (long)(L & 63) * 128, n0 = (long)(L >> 6) * 128;
    int wr = wave >> 1, wc = wave & 1;
    floatx4 acc[4][4] = {};

    int srow = (wave * 128 + lane) >> 2;
    int sch  = (lane & 3) ^ ((lane >> 3) & 3);      // source-side XOR swizzle
    const __hip_bfloat16* Ag = A  + (m0 + srow) * K + sch * 8;
    const __hip_bfloat16* Bg = Bt + (n0 + srow) * K + sch * 8;
    __hip_bfloat16* AsW = &As[wave * 128 * 8];
    __hip_bfloat16* BsW = &Bs[wave * 128 * 8];
    int lm = lane & 15, lg = lane >> 4;
    int lk8 = ((lg ^ ((lm >> 1) & 3))) * 8;         // read-side swizzle

    for (int k0 = 0; k0 < K; k0 += 32) {
        GLOAD_LDS16(Ag + k0,          AsW);
        GLOAD_LDS16(Ag + 16 * K + k0, AsW + 64 * 8);
        GLOAD_LDS16(Bg + k0,          BsW);
        GLOAD_LDS16(Bg + 16 * K + k0, BsW + 64 * 8);
        __syncthreads();
        short8 af[4], bf[4];
        #pragma unroll
        for (int mi = 0; mi < 4; mi++)
            af[mi] = *(const short8*)&As[(wr * 64 + mi * 16 + lm) * 32 + lk8];
        #pragma unroll
        for (int ni = 0; ni < 4; ni++)
            bf[ni] = *(const short8*)&Bs[(wc * 64 + ni * 16 + lm) * 32 + lk8];
        #pragma unroll
        for (int mi = 0; mi < 4; mi++)
            #pragma unroll
            for (int ni = 0; ni < 4; ni++)
                acc[mi][ni] = __builtin_amdgcn_mfma_f32_16x16x32_bf16(
                    af[mi], bf[ni], acc[mi][ni], 0, 0, 0);
        __syncthreads();
    }

    // ---- epilogue: bias(+gelu), LDS transpose, coalesced bf16 stores ----
    float bvv[4];
    #pragma unroll
    for (int ni = 0; ni < 4; ni++)
        bvv[ni] = bias[n0 + wc * 64 + ni * 16 + lm];
    int erow = tid >> 4;            // 0..15
    int ecol = (tid & 15) * 8;      // 0..120
    #pragma unroll
    for (int p = 0; p < 2; p++) {
        if (wr == p) {
            #pragma unroll
            for (int mi = 0; mi < 4; mi++)
                #pragma unroll
                for (int ni = 0; ni < 4; ni++)
                    #pragma unroll
                    for (int j = 0; j < 4; j++) {
                        float o = acc[mi][ni][j] + bvv[ni];
                        if (ACT == 1) o = gelu_exact(o);
                        lds_raw[(mi * 16 + lg * 4 + j) * 136 +
                                wc * 64 + ni * 16 + lm] = bfs(o);
                    }
        }
        __syncthreads();
        #pragma unroll
        for (int rr = 0; rr < 4; rr++) {
            int r = erow + rr * 16;
            short8 v = *(const short8*)&lds_raw[r * 136 + ecol];
            *(short8*)&C[(m0 + p * 64 + r) * N + n0 + ecol] = v;
        }
        __syncthreads();
    }
}

// ---------------------------------------------------------------------------
// h = LayerNorm(t_bf + pos_emb[s] + tok_emb); writes fp32 h + bf16 mirror.
// ---------------------------------------------------------------------------
__global__ __launch_bounds__(256) void pos_ln_kernel(
    const __hip_bfloat16* __restrict__ t, const float* __restrict__ pos_emb,
    const float* __restrict__ tok_emb, const float* __restrict__ ln_s,
    const float* __restrict__ ln_b, float* __restrict__ h,
    __hip_bfloat16* __restrict__ hbf)
{
    int tok = blockIdx.x;
    int s = tok & 1023;
    int tid = threadIdx.x;
    __shared__ float red[8];
    const __hip_bfloat16* trow = &t[(long)tok * 768];
    int d0 = tid, d1 = tid + 256, d2 = tid + 512;
    float a0 = __bfloat162float(trow[d0]) + pos_emb[s * 768 + d0] + tok_emb[d0];
    float a1 = __bfloat162float(trow[d1]) + pos_emb[s * 768 + d1] + tok_emb[d1];
    float a2 = __bfloat162float(trow[d2]) + pos_emb[s * 768 + d2] + tok_emb[d2];
    float sum = a0 + a1 + a2;
    float sumsq = a0 * a0 + a1 * a1 + a2 * a2;
    #pragma unroll
    for (int off = 32; off; off >>= 1) {
        sum   += __shfl_down(sum, off, 64);
        sumsq += __shfl_down(sumsq, off, 64);
    }
    if ((tid & 63) == 0) { red[tid >> 6] = sum; red[4 + (tid >> 6)] = sumsq; }
    __syncthreads();
    sum   = red[0] + red[1] + red[2] + red[3];
    sumsq = red[4] + red[5] + red[6] + red[7];
    float mean = sum * (1.f / 768.f);
    float var  = sumsq * (1.f / 768.f) - mean * mean;
    float rs   = rsqrtf(var + 1e-12f);
    float* hrow = &h[(long)tok * 768];
    __hip_bfloat16* brow = &hbf[(long)tok * 768];
    float o0 = (a0 - mean) * rs * ln_s[d0] + ln_b[d0];
    float o1 = (a1 - mean) * rs * ln_s[d1] + ln_b[d1];
    float o2 = (a2 - mean) * rs * ln_s[d2] + ln_b[d2];
    hrow[d0] = o0; hrow[d1] = o1; hrow[d2] = o2;
    brow[d0] = __float2bfloat16(o0);
    brow[d1] = __float2bfloat16(o1);
    brow[d2] = __float2bfloat16(o2);
}

// ---------------------------------------------------------------------------
// MFMA band attention; QKV is bf16 [8192, 2304] (q|k|v packed per token).
// ---------------------------------------------------------------------------
__global__ __launch_bounds__(256) void attn_kernel(
    const __hip_bfloat16* __restrict__ QKV, __hip_bfloat16* __restrict__ Ob)
{
    __shared__ __hip_bfloat16 KV[128 * 72];       // Ks[128][72]  /  Vt[64][136]
    __shared__ __hip_bfloat16 Pl[4][32 * 136];    // per-wave P[query][key]
    __shared__ float alpha_s[4][32];
    __shared__ float l_s[4][32];

    int blk = blockIdx.x;
    int ci = blk & 7, hh = (blk >> 3) % 12, b = blk / 96;
    int tid = threadIdx.x, w = tid >> 6, lane = tid & 63;
    int lm = lane & 15, lg = lane >> 4;
    __hip_bfloat16* Pw = &Pl[w][0];

    short8 qf[2][2];
    #pragma unroll
    for (int nt = 0; nt < 2; nt++) {
        int q = ci * 128 + w * 32 + nt * 16 + lm;
        const __hip_bfloat16* qp = &QKV[((long)(b * 1024 + q)) * 2304 + hh * 64];
        #pragma unroll
        for (int ks = 0; ks < 2; ks++)
            qf[nt][ks] = *(const short8*)(qp + ks * 32 + lg * 8);
    }

    floatx4 accO[2][4] = {};
    float m_run[2] = {-1e30f, -1e30f};
    float l_run[2] = {0.f, 0.f};

    for (int tt = 0; tt < 3; tt++) {
        __syncthreads();
        #pragma unroll
        for (int i = 0; i < 4; i++) {
            int e = tid + i * 256;          // 0..1023
            int jj = e >> 3, dd = (e & 7) * 8;
            int kpos = ci * 128 + tt * 128 + jj - 128;
            short8 kv = {};
            if (kpos >= 0 && kpos < 1024)
                kv = *(const short8*)&QKV[((long)(b * 1024 + kpos)) * 2304 + 768 + hh * 64 + dd];
            *(short8*)&KV[jj * 72 + dd] = kv;
        }
        __syncthreads();

        floatx4 accS[8][2] = {};
        #pragma unroll
        for (int ks = 0; ks < 2; ks++)
            #pragma unroll
            for (int mt = 0; mt < 8; mt++) {
                short8 kf = *(const short8*)&KV[(mt * 16 + lm) * 72 + ks * 32 + lg * 8];
                accS[mt][0] = __builtin_amdgcn_mfma_f32_16x16x32_bf16(kf, qf[0][ks], accS[mt][0], 0, 0, 0);
                accS[mt][1] = __builtin_amdgcn_mfma_f32_16x16x32_bf16(kf, qf[1][ks], accS[mt][1], 0, 0, 0);
            }

        float tmax[2] = {-1e30f, -1e30f};
        #pragma unroll
        for (int nt = 0; nt < 2; nt++) {
            int r = w * 32 + nt * 16 + lm;
            #pragma unroll
            for (int mt = 0; mt < 8; mt++)
                #pragma unroll
                for (int j = 0; j < 4; j++) {
                    int jrel = tt * 128 + mt * 16 + lg * 4 + j;
                    int kpos = ci * 128 + jrel - 128;
                    bool valid = (jrel >= r) && (jrel <= r + 256) &&
                                 (kpos >= 0) && (kpos < 1024);
                    float s = valid ? accS[mt][nt][j] * 0.125f : -1e9f;
                    accS[mt][nt][j] = s;
                    tmax[nt] = fmaxf(tmax[nt], s);
                }
            tmax[nt] = fmaxf(tmax[nt], __shfl_xor(tmax[nt], 16));
            tmax[nt] = fmaxf(tmax[nt], __shfl_xor(tmax[nt], 32));
        }

        float al[2];
        #pragma unroll
        for (int nt = 0; nt < 2; nt++) {
            float mnew = fmaxf(m_run[nt], tmax[nt]);
            al[nt] = __expf(m_run[nt] - mnew);
            m_run[nt] = mnew;
            float ts = 0.f;
            #pragma unroll
            for (int mt = 0; mt < 8; mt++) {
                short4v pp;
                #pragma unroll
                for (int j = 0; j < 4; j++) {
                    float p = __expf(accS[mt][nt][j] - mnew);
                    ts += p;
                    pp[j] = bfs(p);
                }
                *(short4v*)&Pw[(nt * 16 + lm) * 136 + mt * 16 + lg * 4] = pp;
            }
            ts += __shfl_xor(ts, 16);
            ts += __shfl_xor(ts, 32);
            l_run[nt] = l_run[nt] * al[nt] + ts;
        }
        if (lg < 2) alpha_s[w][lg * 16 + lm] = al[lg];

        __syncthreads();
        #pragma unroll
        for (int i = 0; i < 4; i++) {
            int e = tid + i * 256;          // 0..1023
            int jj = e >> 3, dd = (e & 7) * 8;
            int kpos = ci * 128 + tt * 128 + jj - 128;
            short8 vv = {};
            if (kpos >= 0 && kpos < 1024)
                vv = *(const short8*)&QKV[((long)(b * 1024 + kpos)) * 2304 + 1536 + hh * 64 + dd];
            short* kvs = (short*)KV;
            #pragma unroll
            for (int m2 = 0; m2 < 8; m2++)
                kvs[(dd + m2) * 136 + jj] = vv[m2];
        }
        __syncthreads();

        #pragma unroll
        for (int mo = 0; mo < 2; mo++)
            #pragma unroll
            for (int j = 0; j < 4; j++) {
                float a = alpha_s[w][mo * 16 + lg * 4 + j];
                #pragma unroll
                for (int nd = 0; nd < 4; nd++)
                    accO[mo][nd][j] *= a;
            }

        #pragma unroll
        for (int kk = 0; kk < 4; kk++) {
            short8 pf[2], vf[4];
            #pragma unroll
            for (int mo = 0; mo < 2; mo++)
                pf[mo] = *(const short8*)&Pw[(mo * 16 + lm) * 136 + kk * 32 + lg * 8];
            #pragma unroll
            for (int nd = 0; nd < 4; nd++)
                vf[nd] = *(const short8*)&KV[(nd * 16 + lm) * 136 + kk * 32 + lg * 8];
            #pragma unroll
            for (int mo = 0; mo < 2; mo++)
                #pragma unroll
                for (int nd = 0; nd < 4; nd++)
                    accO[mo][nd] = __builtin_amdgcn_mfma_f32_16x16x32_bf16(
                        pf[mo], vf[nd], accO[mo][nd], 0, 0, 0);
        }
    }

    if (lg < 2) l_s[w][lg * 16 + lm] = l_run[lg];
    #pragma unroll
    for (int mo = 0; mo < 2; mo++)
        #pragma unroll
        for (int j = 0; j < 4; j++) {
            int qr = mo * 16 + lg * 4 + j;       // within-wave row, 0..31
            float rl = 1.f / l_s[w][qr];
            int q  = w * 32 + qr;
            long base = ((long)(b * 1024 + ci * 128 + q)) * 768 + hh * 64;
            #pragma unroll
            for (int nd = 0; nd < 4; nd++)
                Ob[base + nd * 16 + lm] = __float2bfloat16(accO[mo][nd][j] * rl);
        }
}

// ---------------------------------------------------------------------------
// h = LayerNorm(h + t_bf) in place; also writes bf16 mirror.
// ---------------------------------------------------------------------------
__global__ __launch_bounds__(256) void add_ln_kernel(
    float* __restrict__ h, const __hip_bfloat16* __restrict__ t,
    const float* __restrict__ ln_s, const float* __restrict__ ln_b,
    __hip_bfloat16* __restrict__ hbf)
{
    int tok = blockIdx.x;
    int tid = threadIdx.x;
    __shared__ float red[8];
    float* hrow = &h[(long)tok * 768];
    const __hip_bfloat16* trow = &t[(long)tok * 768];
    int d0 = tid, d1 = tid + 256, d2 = tid + 512;
    float a0 = hrow[d0] + __bfloat162float(trow[d0]);
    float a1 = hrow[d1] + __bfloat162float(trow[d1]);
    float a2 = hrow[d2] + __bfloat162float(trow[d2]);
    float sum = a0 + a1 + a2;
    float sumsq = a0 * a0 + a1 * a1 + a2 * a2;
    #pragma unroll
    for (int off = 32; off; off >>= 1) {
        sum   += __shfl_down(sum, off, 64);
        sumsq += __shfl_down(sumsq, off, 64);
    }
    if ((tid & 63) == 0) { red[tid >> 6] = sum; red[4 + (tid >> 6)] = sumsq; }
    __syncthreads();
    sum   = red[0] + red[1] + red[2] + red[3];
    sumsq = red[4] + red[5] + red[6] + red[7];
    float mean = sum * (1.f / 768.f);
    float var  = sumsq * (1.f / 768.f) - mean * mean;
    float rs   = rsqrtf(var + 1e-12f);
    __hip_bfloat16* brow = &hbf[(long)tok * 768];
    float o0 = (a0 - mean) * rs * ln_s[d0] + ln_b[d0];
    float o1 = (a1 - mean) * rs * ln_s[d1] + ln_b[d1];
    float o2 = (a2 - mean) * rs * ln_s[d2] + ln_b[d2];
    hrow[d0] = o0; hrow[d1] = o1; hrow[d2] = o2;
    brow[d0] = __float2bfloat16(o0);
    brow[d1] = __float2bfloat16(o1);
    brow[d2] = __float2bfloat16(o2);
}

// ---------------------------------------------------------------------------
// Head stage 1: pooled[b,d] = tanh(h_bf[b,0,:] . pool_wt[d,:] + pool_b[d]).
// ---------------------------------------------------------------------------
__global__ __launch_bounds__(256) void pool_split(
    const __hip_bfloat16* __restrict__ hbf, const __hip_bfloat16* __restrict__ pool_wt,
    const float* __restrict__ pool_b, float* __restrict__ pooled)
{
    int g = blockIdx.x * 256 + threadIdx.x;
    int out = g >> 3, t8 = g & 7;
    int b = out / 768, d = out - b * 768;
    const __hip_bfloat16* hr = hbf + (long)b * 1024 * 768;   // token 0 of batch b
    const __hip_bfloat16* wr = pool_wt + (long)d * 768;
    float acc = 0.f;
    #pragma unroll
    for (int kk = 0; kk < 96; kk += 8) {
        int k = t8 * 96 + kk;
        short8 hv = *(const short8*)&hr[k];
        short8 wv = *(const short8*)&wr[k];
        #pragma unroll
        for (int j = 0; j < 8; j++) acc += bf2f(hv[j]) * bf2f(wv[j]);
    }
    acc += __shfl_down(acc, 4, 64);
    acc += __shfl_down(acc, 2, 64);
    acc += __shfl_down(acc, 1, 64);
    if (t8 == 0) pooled[out] = tanhf(acc + pool_b[d]);
}

// ---------------------------------------------------------------------------
// Head stage 2: z_bf[b] = bf16(LN(pooled[b])). 8 blocks x 256 thr.
// ---------------------------------------------------------------------------
__global__ __launch_bounds__(256) void ln_z_kernel(
    const float* __restrict__ pooled, const float* __restrict__ hln_s,
    const float* __restrict__ hln_b, __hip_bfloat16* __restrict__ zbf)
{
    int b = blockIdx.x, tid = threadIdx.x;
    __shared__ float red[8];
    const float* pr = &pooled[b * 768];
    float p0 = pr[tid], p1 = pr[tid + 256], p2 = pr[tid + 512];
    float sum = p0 + p1 + p2;
    float sumsq = p0 * p0 + p1 * p1 + p2 * p2;
    #pragma unroll
    for (int off = 32; off; off >>= 1) {
        sum   += __shfl_down(sum, off, 64);
        sumsq += __shfl_down(sumsq, off, 64);
    }
    if ((tid & 63) == 0) { red[tid >> 6] = sum; red[4 + (tid >> 6)] = sumsq; }
    __syncthreads();
    sum   = red[0] + red[1] + red[2] + red[3];
    sumsq = red[4] + red[5] + red[6] + red[7];
    float mean = sum * (1.f / 768.f);
    float var  = sumsq * (1.f / 768.f) - mean * mean;
    float rs   = rsqrtf(var + 1e-12f);
    zbf[b * 768 + tid]       = __float2bfloat16((p0 - mean) * rs * hln_s[tid]       + hln_b[tid]);
    zbf[b * 768 + tid + 256] = __float2bfloat16((p1 - mean) * rs * hln_s[tid + 256] + hln_b[tid + 256]);
    zbf[b * 768 + tid + 512] = __float2bfloat16((p2 - mean) * rs * hln_s[tid + 512] + hln_b[tid + 512]);
}

// ---------------------------------------------------------------------------
// Head stage 3: z1[b,d] = gelu(z_bf[b] . w1t[d,:] + b1[d]).
// ---------------------------------------------------------------------------
__global__ __launch_bounds__(256) void mlp_split(
    const __hip_bfloat16* __restrict__ zbf, const __hip_bfloat16* __restrict__ w1t,
    const float* __restrict__ b1, float* __restrict__ z1)
{
    int g = blockIdx.x * 256 + threadIdx.x;
    int out = g >> 3, t8 = g & 7;
    int b = out >> 9, d = out & 511;
    const __hip_bfloat16* zr = zbf + b * 768;
    const __hip_bfloat16* wr = w1t + (long)d * 768;
    float acc = 0.f;
    #pragma unroll
    for (int kk = 0; kk < 96; kk += 8) {
        int k = t8 * 96 + kk;
        short8 zv = *(const short8*)&zr[k];
        short8 wv = *(const short8*)&wr[k];
        #pragma unroll
        for (int j = 0; j < 8; j++) acc += bf2f(zv[j]) * bf2f(wv[j]);
    }
    acc += __shfl_down(acc, 4, 64);
    acc += __shfl_down(acc, 2, 64);
    acc += __shfl_down(acc, 1, 64);
    if (t8 == 0) z1[out] = gelu_exact(acc + b1[d]);
}

// ---------------------------------------------------------------------------
// Head stage 4: out[b,o] = z1[b] @ w2[:,o] + b2[o]. 1 block, 256 threads.
// ---------------------------------------------------------------------------
__global__ __launch_bounds__(256) void head_final_kernel(
    const float* __restrict__ z1, const float* __restrict__ w2,
    const float* __restrict__ b2, float* __restrict__ out)
{
    int tid = threadIdx.x;
    int g = tid >> 3, t8 = tid & 7;
    if (g < 24) {
        int b = g / 3, o = g % 3;
        float acc = 0.f;
        for (int k = t8; k < 512; k += 8)
            acc += z1[b * 512 + k] * w2[k * 3 + o];
        acc += __shfl_down(acc, 4, 64);
        acc += __shfl_down(acc, 2, 64);
        acc += __shfl_down(acc, 1, 64);
        if (t8 == 0) out[b * 3 + o] = acc + b2[o];
    }
}

// ---------------------------------------------------------------------------
extern "C" void kernel_launch(void* const* d_in, const int* in_sizes, int n_in,
                              void* d_out, int out_size, void* d_ws, size_t ws_size,
                              hipStream_t stream) {
    const float* x       = (const float*)d_in[0];
    const float* proj_w  = (const float*)d_in[2];
    const float* proj_b  = (const float*)d_in[3];
    const float* pos_emb = (const float*)d_in[4];
    const float* tok_emb = (const float*)d_in[5];
    const float* eln_s   = (const float*)d_in[6];
    const float* eln_b   = (const float*)d_in[7];
    const float* wq      = (const float*)d_in[8];
    const float* bq      = (const float*)d_in[9];
    const float* wk      = (const float*)d_in[10];
    const float* bk      = (const float*)d_in[11];
    const float* wv      = (const float*)d_in[12];
    const float* bv      = (const float*)d_in[13];
    const float* wo      = (const float*)d_in[14];
    const float* bo      = (const float*)d_in[15];
    const float* ln1_s   = (const float*)d_in[16];
    const float* ln1_b   = (const float*)d_in[17];
    const float* wi      = (const float*)d_in[18];
    const float* bi      = (const float*)d_in[19];
    const float* wo2     = (const float*)d_in[20];
    const float* bo2     = (const float*)d_in[21];
    const float* ln2_s   = (const float*)d_in[22];
    const float* ln2_b   = (const float*)d_in[23];
    const float* pool_w  = (const float*)d_in[24];
    const float* pool_b  = (const float*)d_in[25];
    const float* hln_s   = (const float*)d_in[26];
    const float* hln_b   = (const float*)d_in[27];
    const float* hw1     = (const float*)d_in[28];
    const float* hb1     = (const float*)d_in[29];
    const float* hw2     = (const float*)d_in[30];
    const float* hb2     = (const float*)d_in[31];

    char* wp = (char*)d_ws;
    auto alloc = [&](size_t bytes) {
        char* p = wp; wp += (bytes + 255) & ~(size_t)255; return p;
    };
    float*          h       = (float*)alloc(8192ll * 768 * 4);
    __hip_bfloat16* qkv_bf  = (__hip_bfloat16*)alloc(8192ll * 2304 * 2);
    __hip_bfloat16* t_bf    = (__hip_bfloat16*)alloc(8192ll * 768 * 2);
    __hip_bfloat16* mlp_bf  = (__hip_bfloat16*)alloc(8192ll * 3072 * 2);
    __hip_bfloat16* h_bf    = (__hip_bfloat16*)alloc(8192ll * 768 * 2);
    __hip_bfloat16* a_bf    = (__hip_bfloat16*)alloc(8192ll * 768 * 2);
    __hip_bfloat16* qkvw_t  = (__hip_bfloat16*)alloc(3ll * 2304 * 768 * 2);
    __hip_bfloat16* wo_t    = (__hip_bfloat16*)alloc(3ll * 768 * 768 * 2);
    __hip_bfloat16* wi_t    = (__hip_bfloat16*)alloc(3ll * 3072 * 768 * 2);
    __hip_bfloat16* wo2_t   = (__hip_bfloat16*)alloc(3ll * 768 * 3072 * 2);
    float*          qkv_b   = (float*)alloc(3ll * 2304 * 4);
    __hip_bfloat16* xr_bf   = (__hip_bfloat16*)alloc(8192ll * 192 * 2);
    __hip_bfloat16* projw_t = (__hip_bfloat16*)alloc(768ll * 192 * 2);
    __hip_bfloat16* poolw_t = (__hip_bfloat16*)alloc(768ll * 768 * 2);
    __hip_bfloat16* w1_t    = (__hip_bfloat16*)alloc(512ll * 768 * 2);
    float*          pooled  = (float*)alloc(8ll * 768 * 4);
    __hip_bfloat16* z_bf    = (__hip_bfloat16*)alloc(8ll * 768 * 2);
    float*          z1      = (float*)alloc(8ll * 512 * 4);

    // ---- weight conversion (every call; graph-safe) ----
    transpose_bf16<<<dim3(24, 24, 3), 256, 0, stream>>>(wq, qkvw_t,               768, 768,  768ll * 768,  2304ll * 768);
    transpose_bf16<<<dim3(24, 24, 3), 256, 0, stream>>>(wk, qkvw_t + 768 * 768,   768, 768,  768ll * 768,  2304ll * 768);
    transpose_bf16<<<dim3(24, 24, 3), 256, 0, stream>>>(wv, qkvw_t + 1536 * 768,  768, 768,  768ll * 768,  2304ll * 768);
    transpose_bf16<<<dim3(24, 24, 3), 256, 0, stream>>>(wo, wo_t,                 768, 768,  768ll * 768,  768ll * 768);
    transpose_bf16<<<dim3(96, 24, 3), 256, 0, stream>>>(wi, wi_t,                 768, 3072, 768ll * 3072, 3072ll * 768);
    transpose_bf16<<<dim3(24, 96, 3), 256, 0, stream>>>(wo2, wo2_t,               3072, 768, 3072ll * 768, 768ll * 3072);
    transpose_bf16<<<dim3(24, 6, 1),  256, 0, stream>>>(proj_w, projw_t,          192, 768,  0, 0);
    transpose_bf16<<<dim3(24, 24, 1), 256, 0, stream>>>(pool_w, poolw_t,          768, 768,  0, 0);
    transpose_bf16<<<dim3(16, 24, 1), 256, 0, stream>>>(hw1, w1_t,                768, 512,  0, 0);
    pack_qkv_bias<<<3, 768, 0, stream>>>(bq, bk, bv, qkv_b);

    // ---- embed as MFMA GEMM ----
    gather_x<<<8192, 192, 0, stream>>>(x, xr_bf);
    mfma_gemm<0><<<6 * 64, 256, 0, stream>>>(
        xr_bf, projw_t, proj_b, t_bf, 8192, 768, 192);
    pos_ln_kernel<<<8192, 256, 0, stream>>>(t_bf, pos_emb, tok_emb, eln_s, eln_b, h, h_bf);

    for (int l = 0; l < 3; l++) {
        mfma_gemm<0><<<18 * 64, 256, 0, stream>>>(
            h_bf, qkvw_t + (long)l * 2304 * 768, qkv_b + l * 2304, qkv_bf,
            8192, 2304, 768);
        attn_kernel<<<768, 256, 0, stream>>>(qkv_bf, a_bf);
        mfma_gemm<0><<<6 * 64, 256, 0, stream>>>(
            a_bf, wo_t + (long)l * 768 * 768, bo + l * 768, t_bf,
            8192, 768, 768);
        add_ln_kernel<<<8192, 256, 0, stream>>>(h, t_bf, ln1_s + l * 768, ln1_b + l * 768, h_bf);
        mfma_gemm<1><<<24 * 64, 256, 0, stream>>>(
            h_bf, wi_t + (long)l * 3072 * 768, bi + l * 3072, mlp_bf,
            8192, 3072, 768);
        mfma_gemm<0><<<6 * 64, 256, 0, stream>>>(
            mlp_bf, wo2_t + (long)l * 768 * 3072, bo2 + l * 768, t_bf,
            8192, 768, 3072);
        add_ln_kernel<<<8192, 256, 0, stream>>>(h, t_bf, ln2_s + l * 768, ln2_b + l * 768, h_bf);
    }

    // ---- head: pool -> LN -> MLP -> final ----
    pool_split<<<192, 256, 0, stream>>>(h_bf, poolw_t, pool_b, pooled);
    ln_z_kernel<<<8, 256, 0, stream>>>(pooled, hln_s, hln_b, z_bf);
    mlp_split<<<128, 256, 0, stream>>>(z_bf, w1_t, hb1, z1);
    head_final_kernel<<<1, 256, 0, stream>>>(z1, hw2, hb2, (float*)d_out);
}

// Round 8
// 1090.610 us; speedup vs baseline: 6.9224x; 1.0958x over previous
//
#include <hip/hip_runtime.h>
#include <hip/hip_bf16.h>
#include <math.h>

// B=8, S=1024, D=768, H=12, DH=64, L=3, I=3072, W1S=128, nc=8, MLP=512, NCLS=3

typedef __attribute__((ext_vector_type(8))) short short8;   // 8 bf16 (4 VGPRs)
typedef __attribute__((ext_vector_type(4))) short short4v;  // 4 bf16 (8 B)
typedef __attribute__((ext_vector_type(4))) float floatx4;  // MFMA C/D

// Exact-accuracy gelu via A&S 7.1.26 rational erf (|err|<=1.5e-7), ~15 VALU
// ops vs libm erff's ~50 branchy ones (R7: VALUBusy 45% on the gelu GEMM).
__device__ __forceinline__ float gelu_exact(float x) {
    float ax = fabsf(x) * 0.70710678118654752440f;
    float t  = 1.f / (1.f + 0.3275911f * ax);
    float y  = t * (0.254829592f + t * (-0.284496736f + t * (1.421413741f +
               t * (-1.453152027f + t * 1.061405429f))));
    float erfv = copysignf(1.f - y * __expf(-ax * ax), x);
    return 0.5f * x * (1.f + erfv);
}

__device__ __forceinline__ short bfs(float x) {
    __hip_bfloat16 h = __float2bfloat16(x);
    short s;
    __builtin_memcpy(&s, &h, 2);
    return s;
}

__device__ __forceinline__ float bf2f(short s) {
    unsigned u = ((unsigned)(unsigned short)s) << 16;
    float f;
    __builtin_memcpy(&f, &u, 4);
    return f;
}

#define GLOAD_LDS16(g, l) __builtin_amdgcn_global_load_lds( \
    (const __attribute__((address_space(1))) void*)(g),     \
    (__attribute__((address_space(3))) void*)(l), 16, 0, 0)

// ---------------------------------------------------------------------------
// Weight convert+transpose: W[K,N] fp32 -> Wt[N,K] bf16. blockIdx.z = layer.
// ---------------------------------------------------------------------------
__global__ __launch_bounds__(256) void transpose_bf16(
    const float* __restrict__ W, __hip_bfloat16* __restrict__ Wt,
    int K, int N, long inLS, long outLS)
{
    __shared__ float tile[32][33];
    int l = blockIdx.z;
    const float* Wl = W + (long)l * inLS;
    __hip_bfloat16* Wtl = Wt + (long)l * outLS;
    int lx = threadIdx.x & 31, ly = threadIdx.x >> 5;
    int kb = blockIdx.y * 32, nb = blockIdx.x * 32;
    #pragma unroll
    for (int r = 0; r < 32; r += 8)
        tile[ly + r][lx] = Wl[(long)(kb + ly + r) * N + nb + lx];
    __syncthreads();
    #pragma unroll
    for (int r = 0; r < 32; r += 8)
        Wtl[(long)(nb + ly + r) * K + kb + lx] = __float2bfloat16(tile[lx][ly + r]);
}

__global__ void pack_qkv_bias(const float* __restrict__ bq,
                              const float* __restrict__ bk,
                              const float* __restrict__ bv,
                              float* __restrict__ out)
{
    int l = blockIdx.x, tid = threadIdx.x;   // 768 threads
    out[l * 2304 + tid]        = bq[l * 768 + tid];
    out[l * 2304 + 768 + tid]  = bk[l * 768 + tid];
    out[l * 2304 + 1536 + tid] = bv[l * 768 + tid];
}

// ---------------------------------------------------------------------------
// Patchify gather: x (8,3,64,32,32) fp32 -> xr_bf [8192 tokens][192] bf16.
// ---------------------------------------------------------------------------
__global__ __launch_bounds__(192) void gather_x(
    const float* __restrict__ x, __hip_bfloat16* __restrict__ xr)
{
    int tok = blockIdx.x;           // 0..8191
    int b = tok >> 10, s = tok & 1023;
    int tci = s >> 6, sci = (s >> 3) & 7, scj = s & 7;
    int f = threadIdx.x;            // 0..191
    int ch  = f % 3;
    int crc = f / 3;
    int cr1 = crc >> 4, cr2 = (crc >> 2) & 3, cr3 = crc & 3;
    float v = x[(((b * 3 + ch) * 64) + cr1 * 16 + tci) * 1024 +
                (cr2 * 8 + sci) * 32 + cr3 * 8 + scj];
    xr[(long)tok * 192 + f] = __float2bfloat16(v);
}

// ---------------------------------------------------------------------------
// bf16 MFMA GEMM: C[M,N](bf16) = A[M,K](bf16) @ Bt[N,K](bf16)^T + bias.
// 128x128 tile, BK=32, 4 waves, DOUBLE-BUFFERED LDS: loads for tile k+1
// issue right after the barrier, so the barrier's vmcnt(0) drain waits on
// loads that had a full compute phase to land (R7: single-buffer paid the
// drain every iter -> MfmaUtil stuck at 18%).
// 1-D grid, by = L & 63 (same-A blocks share an XCD); bx = L >> 6.
// XOR-swizzled LDS K-chunks (bank conflicts); LDS-transpose epilogue
// (coalesced 16-B bf16 stores).
// ---------------------------------------------------------------------------
template<int ACT>
__global__ __launch_bounds__(256) void mfma_gemm(
    const __hip_bfloat16* __restrict__ A, const __hip_bfloat16* __restrict__ Bt,
    const float* __restrict__ bias, __hip_bfloat16* __restrict__ C,
    int M, int N, int K)
{
    __shared__ short lds_raw[16384];           // As[2][4096] | Bs[2][4096]; epi reuses
    __hip_bfloat16* As = (__hip_bfloat16*)lds_raw;
    __hip_bfloat16* Bs = As + 8192;
    int tid  = threadIdx.x;
    int wave = tid >> 6, lane = tid & 63;
    int L = blockIdx.x;
    long m0 = (long)(L & 63) * 128, n0 = (long)(L >> 6) * 128;
    int wr = wave >> 1, wc = wave & 1;
    floatx4 acc[4][4] = {};

    int srow = (wave * 128 + lane) >> 2;
    int sch  = (lane & 3) ^ ((lane >> 3) & 3);      // source-side XOR swizzle
    const __hip_bfloat16* Ag = A  + (m0 + srow) * K + sch * 8;
    const __hip_bfloat16* Bg = Bt + (n0 + srow) * K + sch * 8;
    int lm = lane & 15, lg = lane >> 4;
    int lk8 = ((lg ^ ((lm >> 1) & 3))) * 8;         // read-side swizzle

    auto stage = [&](int buf, int k0) {
        __hip_bfloat16* a = As + buf * 4096 + wave * 1024;
        __hip_bfloat16* b = Bs + buf * 4096 + wave * 1024;
        GLOAD_LDS16(Ag + k0,          a);
        GLOAD_LDS16(Ag + 16 * K + k0, a + 512);
        GLOAD_LDS16(Bg + k0,          b);
        GLOAD_LDS16(Bg + 16 * K + k0, b + 512);
    };

    stage(0, 0);
    int buf = 0;
    for (int k0 = 0; k0 < K; k0 += 32, buf ^= 1) {
        __syncthreads();                 // buf's loads landed; prev reads done
        if (k0 + 32 < K) stage(buf ^ 1, k0 + 32);
        const __hip_bfloat16* Ab = As + buf * 4096;
        const __hip_bfloat16* Bb = Bs + buf * 4096;
        short8 af[4], bf4[4];
        #pragma unroll
        for (int mi = 0; mi < 4; mi++)
            af[mi] = *(const short8*)&Ab[(wr * 64 + mi * 16 + lm) * 32 + lk8];
        #pragma unroll
        for (int ni = 0; ni < 4; ni++)
            bf4[ni] = *(const short8*)&Bb[(wc * 64 + ni * 16 + lm) * 32 + lk8];
        #pragma unroll
        for (int mi = 0; mi < 4; mi++)
            #pragma unroll
            for (int ni = 0; ni < 4; ni++)
                acc[mi][ni] = __builtin_amdgcn_mfma_f32_16x16x32_bf16(
                    af[mi], bf4[ni], acc[mi][ni], 0, 0, 0);
    }
    __syncthreads();

    // ---- epilogue: bias(+gelu), LDS transpose, coalesced bf16 stores ----
    float bvv[4];
    #pragma unroll
    for (int ni = 0; ni < 4; ni++)
        bvv[ni] = bias[n0 + wc * 64 + ni * 16 + lm];
    int erow = tid >> 4;            // 0..15
    int ecol = (tid & 15) * 8;      // 0..120
    #pragma unroll
    for (int p = 0; p < 2; p++) {
        if (wr == p) {
            #pragma unroll
            for (int mi = 0; mi < 4; mi++)
                #pragma unroll
                for (int ni = 0; ni < 4; ni++)
                    #pragma unroll
                    for (int j = 0; j < 4; j++) {
                        float o = acc[mi][ni][j] + bvv[ni];
                        if (ACT == 1) o = gelu_exact(o);
                        lds_raw[(mi * 16 + lg * 4 + j) * 136 +
                                wc * 64 + ni * 16 + lm] = bfs(o);
                    }
        }
        __syncthreads();
        #pragma unroll
        for (int rr = 0; rr < 4; rr++) {
            int r = erow + rr * 16;
            short8 v = *(const short8*)&lds_raw[r * 136 + ecol];
            *(short8*)&C[(m0 + p * 64 + r) * N + n0 + ecol] = v;
        }
        __syncthreads();
    }
}

// ---------------------------------------------------------------------------
// h = LayerNorm(t_bf + pos_emb[s] + tok_emb); fp32 h + bf16 mirror.
// 192 threads, float4/short4 per lane (16-B coalescing).
// ---------------------------------------------------------------------------
__global__ __launch_bounds__(192) void pos_ln_kernel(
    const __hip_bfloat16* __restrict__ t, const float* __restrict__ pos_emb,
    const float* __restrict__ tok_emb, const float* __restrict__ ln_s,
    const float* __restrict__ ln_b, float* __restrict__ h,
    __hip_bfloat16* __restrict__ hbf)
{
    int tok = blockIdx.x;
    int s = tok & 1023;
    int tid = threadIdx.x;        // 0..191
    int d = tid * 4;
    __shared__ float red[6];
    short4v tv = *(const short4v*)&t[(long)tok * 768 + d];
    float4 pv = *(const float4*)&pos_emb[s * 768 + d];
    float4 kv = *(const float4*)&tok_emb[d];
    float a[4] = { bf2f(tv[0]) + pv.x + kv.x, bf2f(tv[1]) + pv.y + kv.y,
                   bf2f(tv[2]) + pv.z + kv.z, bf2f(tv[3]) + pv.w + kv.w };
    float sum = a[0] + a[1] + a[2] + a[3];
    float sumsq = a[0]*a[0] + a[1]*a[1] + a[2]*a[2] + a[3]*a[3];
    #pragma unroll
    for (int off = 32; off; off >>= 1) {
        sum   += __shfl_down(sum, off, 64);
        sumsq += __shfl_down(sumsq, off, 64);
    }
    if ((tid & 63) == 0) { red[tid >> 6] = sum; red[3 + (tid >> 6)] = sumsq; }
    __syncthreads();
    sum   = red[0] + red[1] + red[2];
    sumsq = red[3] + red[4] + red[5];
    float mean = sum * (1.f / 768.f);
    float var  = sumsq * (1.f / 768.f) - mean * mean;
    float rs   = rsqrtf(var + 1e-12f);
    float4 sv = *(const float4*)&ln_s[d];
    float4 bv = *(const float4*)&ln_b[d];
    float4 o;
    o.x = (a[0] - mean) * rs * sv.x + bv.x;
    o.y = (a[1] - mean) * rs * sv.y + bv.y;
    o.z = (a[2] - mean) * rs * sv.z + bv.z;
    o.w = (a[3] - mean) * rs * sv.w + bv.w;
    *(float4*)&h[(long)tok * 768 + d] = o;
    short4v ob = { bfs(o.x), bfs(o.y), bfs(o.z), bfs(o.w) };
    *(short4v*)&hbf[(long)tok * 768 + d] = ob;
}

// ---------------------------------------------------------------------------
// MFMA band attention; QKV is bf16 [8192, 2304] (q|k|v packed per token).
// ---------------------------------------------------------------------------
__global__ __launch_bounds__(256) void attn_kernel(
    const __hip_bfloat16* __restrict__ QKV, __hip_bfloat16* __restrict__ Ob)
{
    __shared__ __hip_bfloat16 KV[128 * 72];       // Ks[128][72]  /  Vt[64][136]
    __shared__ __hip_bfloat16 Pl[4][32 * 136];    // per-wave P[query][key]
    __shared__ float alpha_s[4][32];
    __shared__ float l_s[4][32];

    int blk = blockIdx.x;
    int ci = blk & 7, hh = (blk >> 3) % 12, b = blk / 96;
    int tid = threadIdx.x, w = tid >> 6, lane = tid & 63;
    int lm = lane & 15, lg = lane >> 4;
    __hip_bfloat16* Pw = &Pl[w][0];

    short8 qf[2][2];
    #pragma unroll
    for (int nt = 0; nt < 2; nt++) {
        int q = ci * 128 + w * 32 + nt * 16 + lm;
        const __hip_bfloat16* qp = &QKV[((long)(b * 1024 + q)) * 2304 + hh * 64];
        #pragma unroll
        for (int ks = 0; ks < 2; ks++)
            qf[nt][ks] = *(const short8*)(qp + ks * 32 + lg * 8);
    }

    floatx4 accO[2][4] = {};
    float m_run[2] = {-1e30f, -1e30f};
    float l_run[2] = {0.f, 0.f};

    for (int tt = 0; tt < 3; tt++) {
        __syncthreads();
        #pragma unroll
        for (int i = 0; i < 4; i++) {
            int e = tid + i * 256;          // 0..1023
            int jj = e >> 3, dd = (e & 7) * 8;
            int kpos = ci * 128 + tt * 128 + jj - 128;
            short8 kv = {};
            if (kpos >= 0 && kpos < 1024)
                kv = *(const short8*)&QKV[((long)(b * 1024 + kpos)) * 2304 + 768 + hh * 64 + dd];
            *(short8*)&KV[jj * 72 + dd] = kv;
        }
        __syncthreads();

        floatx4 accS[8][2] = {};
        #pragma unroll
        for (int ks = 0; ks < 2; ks++)
            #pragma unroll
            for (int mt = 0; mt < 8; mt++) {
                short8 kf = *(const short8*)&KV[(mt * 16 + lm) * 72 + ks * 32 + lg * 8];
                accS[mt][0] = __builtin_amdgcn_mfma_f32_16x16x32_bf16(kf, qf[0][ks], accS[mt][0], 0, 0, 0);
                accS[mt][1] = __builtin_amdgcn_mfma_f32_16x16x32_bf16(kf, qf[1][ks], accS[mt][1], 0, 0, 0);
            }

        float tmax[2] = {-1e30f, -1e30f};
        #pragma unroll
        for (int nt = 0; nt < 2; nt++) {
            int r = w * 32 + nt * 16 + lm;
            #pragma unroll
            for (int mt = 0; mt < 8; mt++)
                #pragma unroll
                for (int j = 0; j < 4; j++) {
                    int jrel = tt * 128 + mt * 16 + lg * 4 + j;
                    int kpos = ci * 128 + jrel - 128;
                    bool valid = (jrel >= r) && (jrel <= r + 256) &&
                                 (kpos >= 0) && (kpos < 1024);
                    float s = valid ? accS[mt][nt][j] * 0.125f : -1e9f;
                    accS[mt][nt][j] = s;
                    tmax[nt] = fmaxf(tmax[nt], s);
                }
            tmax[nt] = fmaxf(tmax[nt], __shfl_xor(tmax[nt], 16));
            tmax[nt] = fmaxf(tmax[nt], __shfl_xor(tmax[nt], 32));
        }

        float al[2];
        #pragma unroll
        for (int nt = 0; nt < 2; nt++) {
            float mnew = fmaxf(m_run[nt], tmax[nt]);
            al[nt] = __expf(m_run[nt] - mnew);
            m_run[nt] = mnew;
            float ts = 0.f;
            #pragma unroll
            for (int mt = 0; mt < 8; mt++) {
                short4v pp;
                #pragma unroll
                for (int j = 0; j < 4; j++) {
                    float p = __expf(accS[mt][nt][j] - mnew);
                    ts += p;
                    pp[j] = bfs(p);
                }
                *(short4v*)&Pw[(nt * 16 + lm) * 136 + mt * 16 + lg * 4] = pp;
            }
            ts += __shfl_xor(ts, 16);
            ts += __shfl_xor(ts, 32);
            l_run[nt] = l_run[nt] * al[nt] + ts;
        }
        if (lg < 2) alpha_s[w][lg * 16 + lm] = al[lg];

        __syncthreads();
        #pragma unroll
        for (int i = 0; i < 4; i++) {
            int e = tid + i * 256;          // 0..1023
            int jj = e >> 3, dd = (e & 7) * 8;
            int kpos = ci * 128 + tt * 128 + jj - 128;
            short8 vv = {};
            if (kpos >= 0 && kpos < 1024)
                vv = *(const short8*)&QKV[((long)(b * 1024 + kpos)) * 2304 + 1536 + hh * 64 + dd];
            short* kvs = (short*)KV;
            #pragma unroll
            for (int m2 = 0; m2 < 8; m2++)
                kvs[(dd + m2) * 136 + jj] = vv[m2];
        }
        __syncthreads();

        #pragma unroll
        for (int mo = 0; mo < 2; mo++)
            #pragma unroll
            for (int j = 0; j < 4; j++) {
                float a = alpha_s[w][mo * 16 + lg * 4 + j];
                #pragma unroll
                for (int nd = 0; nd < 4; nd++)
                    accO[mo][nd][j] *= a;
            }

        #pragma unroll
        for (int kk = 0; kk < 4; kk++) {
            short8 pf[2], vf[4];
            #pragma unroll
            for (int mo = 0; mo < 2; mo++)
                pf[mo] = *(const short8*)&Pw[(mo * 16 + lm) * 136 + kk * 32 + lg * 8];
            #pragma unroll
            for (int nd = 0; nd < 4; nd++)
                vf[nd] = *(const short8*)&KV[(nd * 16 + lm) * 136 + kk * 32 + lg * 8];
            #pragma unroll
            for (int mo = 0; mo < 2; mo++)
                #pragma unroll
                for (int nd = 0; nd < 4; nd++)
                    accO[mo][nd] = __builtin_amdgcn_mfma_f32_16x16x32_bf16(
                        pf[mo], vf[nd], accO[mo][nd], 0, 0, 0);
        }
    }

    if (lg < 2) l_s[w][lg * 16 + lm] = l_run[lg];
    #pragma unroll
    for (int mo = 0; mo < 2; mo++)
        #pragma unroll
        for (int j = 0; j < 4; j++) {
            int qr = mo * 16 + lg * 4 + j;       // within-wave row, 0..31
            float rl = 1.f / l_s[w][qr];
            int q  = w * 32 + qr;
            long base = ((long)(b * 1024 + ci * 128 + q)) * 768 + hh * 64;
            #pragma unroll
            for (int nd = 0; nd < 4; nd++)
                Ob[base + nd * 16 + lm] = __float2bfloat16(accO[mo][nd][j] * rl);
        }
}

// ---------------------------------------------------------------------------
// h = LayerNorm(h + t_bf) in place; bf16 mirror. 192 thr, 16-B vector access.
// ---------------------------------------------------------------------------
__global__ __launch_bounds__(192) void add_ln_kernel(
    float* __restrict__ h, const __hip_bfloat16* __restrict__ t,
    const float* __restrict__ ln_s, const float* __restrict__ ln_b,
    __hip_bfloat16* __restrict__ hbf)
{
    int tok = blockIdx.x;
    int tid = threadIdx.x;        // 0..191
    int d = tid * 4;
    __shared__ float red[6];
    float* hrow = &h[(long)tok * 768];
    float4 hv = *(const float4*)&hrow[d];
    short4v tv = *(const short4v*)&t[(long)tok * 768 + d];
    float a[4] = { hv.x + bf2f(tv[0]), hv.y + bf2f(tv[1]),
                   hv.z + bf2f(tv[2]), hv.w + bf2f(tv[3]) };
    float sum = a[0] + a[1] + a[2] + a[3];
    float sumsq = a[0]*a[0] + a[1]*a[1] + a[2]*a[2] + a[3]*a[3];
    #pragma unroll
    for (int off = 32; off; off >>= 1) {
        sum   += __shfl_down(sum, off, 64);
        sumsq += __shfl_down(sumsq, off, 64);
    }
    if ((tid & 63) == 0) { red[tid >> 6] = sum; red[3 + (tid >> 6)] = sumsq; }
    __syncthreads();
    sum   = red[0] + red[1] + red[2];
    sumsq = red[3] + red[4] + red[5];
    float mean = sum * (1.f / 768.f);
    float var  = sumsq * (1.f / 768.f) - mean * mean;
    float rs   = rsqrtf(var + 1e-12f);
    float4 sv = *(const float4*)&ln_s[d];
    float4 bv = *(const float4*)&ln_b[d];
    float4 o;
    o.x = (a[0] - mean) * rs * sv.x + bv.x;
    o.y = (a[1] - mean) * rs * sv.y + bv.y;
    o.z = (a[2] - mean) * rs * sv.z + bv.z;
    o.w = (a[3] - mean) * rs * sv.w + bv.w;
    *(float4*)&hrow[d] = o;
    short4v ob = { bfs(o.x), bfs(o.y), bfs(o.z), bfs(o.w) };
    *(short4v*)&hbf[(long)tok * 768 + d] = ob;
}

// ---------------------------------------------------------------------------
// Head stage 1: pooled[b,d] = tanh(h_bf[b,0,:] . pool_wt[d,:] + pool_b[d]).
// ---------------------------------------------------------------------------
__global__ __launch_bounds__(256) void pool_split(
    const __hip_bfloat16* __restrict__ hbf, const __hip_bfloat16* __restrict__ pool_wt,
    const float* __restrict__ pool_b, float* __restrict__ pooled)
{
    int g = blockIdx.x * 256 + threadIdx.x;
    int out = g >> 3, t8 = g & 7;
    int b = out / 768, d = out - b * 768;
    const __hip_bfloat16* hr = hbf + (long)b * 1024 * 768;   // token 0 of batch b
    const __hip_bfloat16* wr = pool_wt + (long)d * 768;
    float acc = 0.f;
    #pragma unroll
    for (int kk = 0; kk < 96; kk += 8) {
        int k = t8 * 96 + kk;
        short8 hv = *(const short8*)&hr[k];
        short8 wv = *(const short8*)&wr[k];
        #pragma unroll
        for (int j = 0; j < 8; j++) acc += bf2f(hv[j]) * bf2f(wv[j]);
    }
    acc += __shfl_down(acc, 4, 64);
    acc += __shfl_down(acc, 2, 64);
    acc += __shfl_down(acc, 1, 64);
    if (t8 == 0) pooled[out] = tanhf(acc + pool_b[d]);
}

// ---------------------------------------------------------------------------
// Head stage 2: z_bf[b] = bf16(LN(pooled[b])). 8 blocks x 256 thr.
// ---------------------------------------------------------------------------
__global__ __launch_bounds__(256) void ln_z_kernel(
    const float* __restrict__ pooled, const float* __restrict__ hln_s,
    const float* __restrict__ hln_b, __hip_bfloat16* __restrict__ zbf)
{
    int b = blockIdx.x, tid = threadIdx.x;
    __shared__ float red[8];
    const float* pr = &pooled[b * 768];
    float p0 = pr[tid], p1 = pr[tid + 256], p2 = pr[tid + 512];
    float sum = p0 + p1 + p2;
    float sumsq = p0 * p0 + p1 * p1 + p2 * p2;
    #pragma unroll
    for (int off = 32; off; off >>= 1) {
        sum   += __shfl_down(sum, off, 64);
        sumsq += __shfl_down(sumsq, off, 64);
    }
    if ((tid & 63) == 0) { red[tid >> 6] = sum; red[4 + (tid >> 6)] = sumsq; }
    __syncthreads();
    sum   = red[0] + red[1] + red[2] + red[3];
    sumsq = red[4] + red[5] + red[6] + red[7];
    float mean = sum * (1.f / 768.f);
    float var  = sumsq * (1.f / 768.f) - mean * mean;
    float rs   = rsqrtf(var + 1e-12f);
    zbf[b * 768 + tid]       = __float2bfloat16((p0 - mean) * rs * hln_s[tid]       + hln_b[tid]);
    zbf[b * 768 + tid + 256] = __float2bfloat16((p1 - mean) * rs * hln_s[tid + 256] + hln_b[tid + 256]);
    zbf[b * 768 + tid + 512] = __float2bfloat16((p2 - mean) * rs * hln_s[tid + 512] + hln_b[tid + 512]);
}

// ---------------------------------------------------------------------------
// Head stage 3: z1[b,d] = gelu(z_bf[b] . w1t[d,:] + b1[d]).
// ---------------------------------------------------------------------------
__global__ __launch_bounds__(256) void mlp_split(
    const __hip_bfloat16* __restrict__ zbf, const __hip_bfloat16* __restrict__ w1t,
    const float* __restrict__ b1, float* __restrict__ z1)
{
    int g = blockIdx.x * 256 + threadIdx.x;
    int out = g >> 3, t8 = g & 7;
    int b = out >> 9, d = out & 511;
    const __hip_bfloat16* zr = zbf + b * 768;
    const __hip_bfloat16* wr = w1t + (long)d * 768;
    float acc = 0.f;
    #pragma unroll
    for (int kk = 0; kk < 96; kk += 8) {
        int k = t8 * 96 + kk;
        short8 zv = *(const short8*)&zr[k];
        short8 wv = *(const short8*)&wr[k];
        #pragma unroll
        for (int j = 0; j < 8; j++) acc += bf2f(zv[j]) * bf2f(wv[j]);
    }
    acc += __shfl_down(acc, 4, 64);
    acc += __shfl_down(acc, 2, 64);
    acc += __shfl_down(acc, 1, 64);
    if (t8 == 0) z1[out] = gelu_exact(acc + b1[d]);
}

// ---------------------------------------------------------------------------
// Head stage 4: out[b,o] = z1[b] @ w2[:,o] + b2[o]. 1 block, 256 threads.
// ---------------------------------------------------------------------------
__global__ __launch_bounds__(256) void head_final_kernel(
    const float* __restrict__ z1, const float* __restrict__ w2,
    const float* __restrict__ b2, float* __restrict__ out)
{
    int tid = threadIdx.x;
    int g = tid >> 3, t8 = tid & 7;
    if (g < 24) {
        int b = g / 3, o = g % 3;
        float acc = 0.f;
        for (int k = t8; k < 512; k += 8)
            acc += z1[b * 512 + k] * w2[k * 3 + o];
        acc += __shfl_down(acc, 4, 64);
        acc += __shfl_down(acc, 2, 64);
        acc += __shfl_down(acc, 1, 64);
        if (t8 == 0) out[b * 3 + o] = acc + b2[o];
    }
}

// ---------------------------------------------------------------------------
extern "C" void kernel_launch(void* const* d_in, const int* in_sizes, int n_in,
                              void* d_out, int out_size, void* d_ws, size_t ws_size,
                              hipStream_t stream) {
    const float* x       = (const float*)d_in[0];
    const float* proj_w  = (const float*)d_in[2];
    const float* proj_b  = (const float*)d_in[3];
    const float* pos_emb = (const float*)d_in[4];
    const float* tok_emb = (const float*)d_in[5];
    const float* eln_s   = (const float*)d_in[6];
    const float* eln_b   = (const float*)d_in[7];
    const float* wq      = (const float*)d_in[8];
    const float* bq      = (const float*)d_in[9];
    const float* wk      = (const float*)d_in[10];
    const float* bk      = (const float*)d_in[11];
    const float* wv      = (const float*)d_in[12];
    const float* bv      = (const float*)d_in[13];
    const float* wo      = (const float*)d_in[14];
    const float* bo      = (const float*)d_in[15];
    const float* ln1_s   = (const float*)d_in[16];
    const float* ln1_b   = (const float*)d_in[17];
    const float* wi      = (const float*)d_in[18];
    const float* bi      = (const float*)d_in[19];
    const float* wo2     = (const float*)d_in[20];
    const float* bo2     = (const float*)d_in[21];
    const float* ln2_s   = (const float*)d_in[22];
    const float* ln2_b   = (const float*)d_in[23];
    const float* pool_w  = (const float*)d_in[24];
    const float* pool_b  = (const float*)d_in[25];
    const float* hln_s   = (const float*)d_in[26];
    const float* hln_b   = (const float*)d_in[27];
    const float* hw1     = (const float*)d_in[28];
    const float* hb1     = (const float*)d_in[29];
    const float* hw2     = (const float*)d_in[30];
    const float* hb2     = (const float*)d_in[31];

    char* wp = (char*)d_ws;
    auto alloc = [&](size_t bytes) {
        char* p = wp; wp += (bytes + 255) & ~(size_t)255; return p;
    };
    float*          h       = (float*)alloc(8192ll * 768 * 4);
    __hip_bfloat16* qkv_bf  = (__hip_bfloat16*)alloc(8192ll * 2304 * 2);
    __hip_bfloat16* t_bf    = (__hip_bfloat16*)alloc(8192ll * 768 * 2);
    __hip_bfloat16* mlp_bf  = (__hip_bfloat16*)alloc(8192ll * 3072 * 2);
    __hip_bfloat16* h_bf    = (__hip_bfloat16*)alloc(8192ll * 768 * 2);
    __hip_bfloat16* a_bf    = (__hip_bfloat16*)alloc(8192ll * 768 * 2);
    __hip_bfloat16* qkvw_t  = (__hip_bfloat16*)alloc(3ll * 2304 * 768 * 2);
    __hip_bfloat16* wo_t    = (__hip_bfloat16*)alloc(3ll * 768 * 768 * 2);
    __hip_bfloat16* wi_t    = (__hip_bfloat16*)alloc(3ll * 3072 * 768 * 2);
    __hip_bfloat16* wo2_t   = (__hip_bfloat16*)alloc(3ll * 768 * 3072 * 2);
    float*          qkv_b   = (float*)alloc(3ll * 2304 * 4);
    __hip_bfloat16* xr_bf   = (__hip_bfloat16*)alloc(8192ll * 192 * 2);
    __hip_bfloat16* projw_t = (__hip_bfloat16*)alloc(768ll * 192 * 2);
    __hip_bfloat16* poolw_t = (__hip_bfloat16*)alloc(768ll * 768 * 2);
    __hip_bfloat16* w1_t    = (__hip_bfloat16*)alloc(512ll * 768 * 2);
    float*          pooled  = (float*)alloc(8ll * 768 * 4);
    __hip_bfloat16* z_bf    = (__hip_bfloat16*)alloc(8ll * 768 * 2);
    float*          z1      = (float*)alloc(8ll * 512 * 4);

    // ---- weight conversion (every call; graph-safe) ----
    transpose_bf16<<<dim3(24, 24, 3), 256, 0, stream>>>(wq, qkvw_t,               768, 768,  768ll * 768,  2304ll * 768);
    transpose_bf16<<<dim3(24, 24, 3), 256, 0, stream>>>(wk, qkvw_t + 768 * 768,   768, 768,  768ll * 768,  2304ll * 768);
    transpose_bf16<<<dim3(24, 24, 3), 256, 0, stream>>>(wv, qkvw_t + 1536 * 768,  768, 768,  768ll * 768,  2304ll * 768);
    transpose_bf16<<<dim3(24, 24, 3), 256, 0, stream>>>(wo, wo_t,                 768, 768,  768ll * 768,  768ll * 768);
    transpose_bf16<<<dim3(96, 24, 3), 256, 0, stream>>>(wi, wi_t,                 768, 3072, 768ll * 3072, 3072ll * 768);
    transpose_bf16<<<dim3(24, 96, 3), 256, 0, stream>>>(wo2, wo2_t,               3072, 768, 3072ll * 768, 768ll * 3072);
    transpose_bf16<<<dim3(24, 6, 1),  256, 0, stream>>>(proj_w, projw_t,          192, 768,  0, 0);
    transpose_bf16<<<dim3(24, 24, 1), 256, 0, stream>>>(pool_w, poolw_t,          768, 768,  0, 0);
    transpose_bf16<<<dim3(16, 24, 1), 256, 0, stream>>>(hw1, w1_t,                768, 512,  0, 0);
    pack_qkv_bias<<<3, 768, 0, stream>>>(bq, bk, bv, qkv_b);

    // ---- embed as MFMA GEMM ----
    gather_x<<<8192, 192, 0, stream>>>(x, xr_bf);
    mfma_gemm<0><<<6 * 64, 256, 0, stream>>>(
        xr_bf, projw_t, proj_b, t_bf, 8192, 768, 192);
    pos_ln_kernel<<<8192, 192, 0, stream>>>(t_bf, pos_emb, tok_emb, eln_s, eln_b, h, h_bf);

    for (int l = 0; l < 3; l++) {
        mfma_gemm<0><<<18 * 64, 256, 0, stream>>>(
            h_bf, qkvw_t + (long)l * 2304 * 768, qkv_b + l * 2304, qkv_bf,
            8192, 2304, 768);
        attn_kernel<<<768, 256, 0, stream>>>(qkv_bf, a_bf);
        mfma_gemm<0><<<6 * 64, 256, 0, stream>>>(
            a_bf, wo_t + (long)l * 768 * 768, bo + l * 768, t_bf,
            8192, 768, 768);
        add_ln_kernel<<<8192, 192, 0, stream>>>(h, t_bf, ln1_s + l * 768, ln1_b + l * 768, h_bf);
        mfma_gemm<1><<<24 * 64, 256, 0, stream>>>(
            h_bf, wi_t + (long)l * 3072 * 768, bi + l * 3072, mlp_bf,
            8192, 3072, 768);
        mfma_gemm<0><<<6 * 64, 256, 0, stream>>>(
            mlp_bf, wo2_t + (long)l * 768 * 3072, bo2 + l * 768, t_bf,
            8192, 768, 3072);
        add_ln_kernel<<<8192, 192, 0, stream>>>(h, t_bf, ln2_s + l * 768, ln2_b + l * 768, h_bf);
    }

    // ---- head: pool -> LN -> MLP -> final ----
    pool_split<<<192, 256, 0, stream>>>(h_bf, poolw_t, pool_b, pooled);
    ln_z_kernel<<<8, 256, 0, stream>>>(pooled, hln_s, hln_b, z_bf);
    mlp_split<<<128, 256, 0, stream>>>(z_bf, w1_t, hb1, z1);
    head_final_kernel<<<1, 256, 0, stream>>>(z1, hw2, hb2, (float*)d_out);
}